// Round 2
// baseline (304.229 us; speedup 1.0000x reference)
//
#include <hip/hip_runtime.h>
#include <hip/hip_bf16.h>
#include <math.h>

#define BB  2
#define TT  2048
#define DDE 1024
#define NHH 16
#define HDD 64

typedef __bf16 bf16_t;
typedef __attribute__((ext_vector_type(8))) __bf16 bf16x8;
typedef __attribute__((ext_vector_type(4))) __bf16 bf16x4;
typedef __attribute__((ext_vector_type(4))) float  f32x4;

#define MFMA(a, b, c) __builtin_amdgcn_mfma_f32_16x16x32_bf16((a), (b), (c), 0, 0, 0)

__device__ inline unsigned short bf2us(bf16_t x) {
    union { bf16_t h; unsigned short u; } c; c.h = x; return c.u;
}

// pack 2 f32 -> 1 u32 of 2 bf16 (RNE), no builtin on gfx950
__device__ inline unsigned int cvtpk(float a, float b) {
    unsigned int r;
    asm("v_cvt_pk_bf16_f32 %0, %1, %2" : "=v"(r) : "v"(a), "v"(b));
    return r;
}

__device__ inline void gll16(const bf16_t* g, unsigned short* l) {
    __builtin_amdgcn_global_load_lds(
        (const __attribute__((address_space(1))) void*)g,
        (__attribute__((address_space(3))) void*)l, 16, 0, 0);
}

// Stage [ROWS x 64] bf16 tile (row stride gstride elems) into LDS via
// global_load_lds, chunk-swizzled: LDS elem [r][ (c ^ (r&7))*8 + j ].
template<int ROWS>
__device__ inline void stage_tile(const bf16_t* g0, size_t gstride,
                                  unsigned short* lds, int wave, int lane)
{
    const int r8 = lane >> 3;
    const int ck = (lane & 7) ^ r8;
    constexpr int RW = ROWS / 4;
    const bf16_t* g = g0 + (size_t)(wave * RW + r8) * gstride + ck * 8;
    unsigned short* l = lds + wave * RW * 64 + lane * 8;
    #pragma unroll
    for (int i = 0; i < RW / 8; ++i)
        gll16(g + (size_t)(i * 8) * gstride, l + i * 512);
}

// split-s work decomposition: 40 blocks cover 16 q-tiles x ceil(tiles/8) chunks
__device__ inline void split_decode(int wid, int& qt, int& ch) {
    const int g = (wid >= 24) ? 3 : (wid >= 12) ? 2 : (wid >= 4) ? 1 : 0;
    const int loc = wid - 2 * g * (g + 1);
    qt = 4 * g + loc / (g + 1);
    ch = loc % (g + 1);
}

// ---------------------------------------------------------------------------
// fused fp32->bf16 conversion of x, w_attn, w_k2, w_proj into the contiguous
// ws region starting at xb.  Segment boundaries are multiples of 1024 elems.
// ---------------------------------------------------------------------------
__global__ __launch_bounds__(256) void cvt_all(
    const float* __restrict__ x, const float* __restrict__ wa,
    const float* __restrict__ wk, const float* __restrict__ wp,
    bf16_t* __restrict__ out)
{
    const size_t NX  = (size_t)BB*TT*DDE;
    const size_t NWA = (size_t)2*DDE*DDE;
    const size_t NW  = (size_t)DDE*DDE;
    const size_t e = ((size_t)blockIdx.x * 256 + threadIdx.x) * 4;
    const float* src;
    if (e < NX)                 src = x  + e;
    else if (e < NX + NWA)      src = wa + (e - NX);
    else if (e < NX + NWA + NW) src = wk + (e - NX - NWA);
    else                        src = wp + (e - NX - NWA - NW);
    float4 v = *(const float4*)src;
    bf16x4 o;
    o[0] = (bf16_t)v.x; o[1] = (bf16_t)v.y;
    o[2] = (bf16_t)v.z; o[3] = (bf16_t)v.w;
    *(bf16x4*)(out + e) = o;
}

// ---------------------------------------------------------------------------
// Per-head 64x64 transpose: dst[bh][d][t] = src[b][t][h*64+d].
// ---------------------------------------------------------------------------
__global__ __launch_bounds__(256) void transpose_head(
    const bf16_t* __restrict__ src, bf16_t* __restrict__ dst)
{
    const int t0 = blockIdx.x * 64, h = blockIdx.y, b = blockIdx.z;
    const int tid = threadIdx.x;
    __shared__ __align__(16) bf16_t tile[64 * 64];

    #pragma unroll
    for (int it = 0; it < 2; ++it) {
        const int t = it * 32 + (tid >> 3);
        const int cw = tid & 7;
        const int slot = (cw + (t >> 3)) & 7;
        bf16x8 v = *(const bf16x8*)(src + (size_t)(b*TT + t0 + t)*DDE + h*HDD + cw*8);
        *(bf16x8*)(tile + t*64 + slot*8) = v;
    }
    __syncthreads();
    const int bh = b * NHH + h;
    #pragma unroll
    for (int it = 0; it < 2; ++it) {
        const int d = it * 32 + (tid >> 3);
        const int co = tid & 7;
        const int slot = ((d >> 3) + co) & 7;
        bf16x8 o;
        #pragma unroll
        for (int j = 0; j < 8; ++j)
            o[j] = tile[(co*8 + j)*64 + slot*8 + (d & 7)];
        *(bf16x8*)(dst + (size_t)(bh*64 + d)*TT + t0 + co*8) = o;
    }
}

// ---------------------------------------------------------------------------
// Fused normalize + E-transpose:
//   n[t] = yo[t] / lsum[t]  (AR output);  yarb[t] = bf16(n[t])
//   etg[bh][d][t] = x[t][d] - n[t-1][d]  (0 at t==0)
// Row t0-1 normalization recomputed locally (no cross-block dependency).
// ---------------------------------------------------------------------------
__global__ __launch_bounds__(256) void norm_build_etg(
    const float* __restrict__ yo, const float* __restrict__ ls,
    const bf16_t* __restrict__ xb, bf16_t* __restrict__ yarb,
    bf16_t* __restrict__ etg)
{
    const int t0 = blockIdx.x * 64, h = blockIdx.y, b = blockIdx.z;
    const int tid = threadIdx.x;
    const int bh = b * NHH + h;
    __shared__ __align__(16) bf16_t tile[64 * 64];

    #pragma unroll
    for (int it = 0; it < 2; ++it) {
        const int t = it * 32 + (tid >> 3);
        const int cw = tid & 7;
        const int slot = (cw + (t >> 3)) & 7;
        const int tg = t0 + t;
        // n[tg] -> yarb
        const float inv = 1.f / ls[(size_t)bh*TT + tg];
        const float* yp = yo + (size_t)(b*TT + tg)*DDE + h*HDD + cw*8;
        float4 y0 = *(const float4*)yp;
        float4 y1 = *(const float4*)(yp + 4);
        bf16x8 nb;
        nb[0] = (bf16_t)(y0.x*inv); nb[1] = (bf16_t)(y0.y*inv);
        nb[2] = (bf16_t)(y0.z*inv); nb[3] = (bf16_t)(y0.w*inv);
        nb[4] = (bf16_t)(y1.x*inv); nb[5] = (bf16_t)(y1.y*inv);
        nb[6] = (bf16_t)(y1.z*inv); nb[7] = (bf16_t)(y1.w*inv);
        *(bf16x8*)(yarb + (size_t)(b*TT + tg)*DDE + h*HDD + cw*8) = nb;
        // e[tg] = x[tg] - n[tg-1]
        bf16x8 ev;
        if (tg == 0) {
            #pragma unroll
            for (int u = 0; u < 8; ++u) ev[u] = (bf16_t)0.f;
        } else {
            const float invp = 1.f / ls[(size_t)bh*TT + tg - 1];
            const float* ypp = yo + (size_t)(b*TT + tg - 1)*DDE + h*HDD + cw*8;
            float4 p0 = *(const float4*)ypp;
            float4 p1 = *(const float4*)(ypp + 4);
            bf16x8 xv = *(const bf16x8*)(xb + (size_t)(b*TT + tg)*DDE + h*HDD + cw*8);
            ev[0] = (bf16_t)((float)xv[0] - p0.x*invp);
            ev[1] = (bf16_t)((float)xv[1] - p0.y*invp);
            ev[2] = (bf16_t)((float)xv[2] - p0.z*invp);
            ev[3] = (bf16_t)((float)xv[3] - p0.w*invp);
            ev[4] = (bf16_t)((float)xv[4] - p1.x*invp);
            ev[5] = (bf16_t)((float)xv[5] - p1.y*invp);
            ev[6] = (bf16_t)((float)xv[6] - p1.z*invp);
            ev[7] = (bf16_t)((float)xv[7] - p1.w*invp);
        }
        *(bf16x8*)(tile + t*64 + slot*8) = ev;
    }
    __syncthreads();
    #pragma unroll
    for (int it = 0; it < 2; ++it) {
        const int d = it * 32 + (tid >> 3);
        const int co = tid & 7;
        const int slot = ((d >> 3) + co) & 7;
        bf16x8 o;
        #pragma unroll
        for (int j = 0; j < 8; ++j)
            o[j] = tile[(co*8 + j)*64 + slot*8 + (d & 7)];
        *(bf16x8*)(etg + (size_t)(bh*64 + d)*TT + t0 + co*8) = o;
    }
}

// ---------------------------------------------------------------------------
// Fused QKV GEMM, BK=64 swizzled staging, 2-phase double-buffered pipeline:
// issue next K-step's global_load_lds BEFORE computing current, one barrier
// per step (prefetch flight hides under ds_read+MFMA).  Region by column tile:
//   [0,1024):  q -> qkb = q*0.125*log2(e) (exp2 domain), qab = leaky(q*0.125)
//   [1024,2048): k -> qkb raw
//   [2048,3072): k2 -> kcs[t+1] = sigmoid(k2*0.0025)-0.5 (shifted, row0=0)
// ---------------------------------------------------------------------------
__global__ __launch_bounds__(256) void gemm_qkk2(
    const bf16_t* __restrict__ A, const bf16_t* __restrict__ wab,
    const bf16_t* __restrict__ wkb, const float* __restrict__ b_attn,
    const float* __restrict__ b_k2, bf16_t* __restrict__ qkb,
    bf16_t* __restrict__ qab, bf16_t* __restrict__ kcs)
{
    __shared__ __align__(16) unsigned short As[2][128 * 64];
    __shared__ __align__(16) unsigned short Bs[2][128 * 64];
    const int tid  = threadIdx.x;
    const int wave = tid >> 6, lane = tid & 63;
    const int l15  = lane & 15, quad = lane >> 4;
    const int bm = blockIdx.y * 128, bn = blockIdx.x * 128;
    const int wm = (wave & 1) * 64, wn = (wave >> 1) * 64;
    const int region = bn >> 10;
    const int K = DDE;

    const bf16_t* W = (region < 2) ? wab + (size_t)bn * K
                                   : wkb + (size_t)(bn - 2048) * K;
    const float* bp = (region < 2) ? b_attn + bn : b_k2 + (bn - 2048);
    const bf16_t* Ab = A + (size_t)bm * K;

    f32x4 acc[4][4];
    #pragma unroll
    for (int i = 0; i < 4; ++i)
        #pragma unroll
        for (int j = 0; j < 4; ++j) acc[i][j] = (f32x4)0.f;

    // prologue: stage K-step 0
    stage_tile<128>(Ab, K, As[0], wave, lane);
    stage_tile<128>(W,  K, Bs[0], wave, lane);
    __syncthreads();

    int cur = 0;
    for (int k0 = 0; k0 < K; k0 += 64) {
        // issue next K-step's staging before compute (2-phase pipeline)
        if (k0 + 64 < K) {
            stage_tile<128>(Ab + k0 + 64, K, As[cur ^ 1], wave, lane);
            stage_tile<128>(W  + k0 + 64, K, Bs[cur ^ 1], wave, lane);
        }
        const unsigned short* Ac = As[cur];
        const unsigned short* Bc = Bs[cur];
        bf16x8 af[4][2], bfr[4][2];
        #pragma unroll
        for (int mt = 0; mt < 4; ++mt)
            #pragma unroll
            for (int kh = 0; kh < 2; ++kh)
                af[mt][kh] = *(const bf16x8*)(Ac + (wm + mt*16 + l15)*64
                                              + (((kh*4 + quad) ^ (l15 & 7))*8));
        #pragma unroll
        for (int nt = 0; nt < 4; ++nt)
            #pragma unroll
            for (int kh = 0; kh < 2; ++kh)
                bfr[nt][kh] = *(const bf16x8*)(Bc + (wn + nt*16 + l15)*64
                                               + (((kh*4 + quad) ^ (l15 & 7))*8));
        #pragma unroll
        for (int mt = 0; mt < 4; ++mt)
            #pragma unroll
            for (int nt = 0; nt < 4; ++nt) {
                acc[mt][nt] = MFMA(af[mt][0], bfr[nt][0], acc[mt][nt]);
                acc[mt][nt] = MFMA(af[mt][1], bfr[nt][1], acc[mt][nt]);
            }
        // barrier drains this step's prefetch (vmcnt) and all lgkm reads,
        // so buf[cur^1] is ready and buf[cur] is safe to overwrite next iter.
        __syncthreads();
        cur ^= 1;
    }

    #pragma unroll
    for (int nt = 0; nt < 4; ++nt) {
        const int cl = wn + nt*16 + l15;
        const float bj = bp[cl];
        const int cg = bn + cl;
        #pragma unroll
        for (int mt = 0; mt < 4; ++mt)
            #pragma unroll
            for (int r = 0; r < 4; ++r) {
                const int row = bm + wm + mt*16 + quad*4 + r;
                const float v = acc[mt][nt][r] + bj;
                if (region == 0) {
                    qkb[(size_t)row * (2*DDE) + cg] = (bf16_t)(v * 0.180336880f);
                    const float z = v * 0.125f;
                    qab[(size_t)row * DDE + cg] = (bf16_t)((v > 0.f) ? 0.02f*z : z);
                } else if (region == 1) {
                    qkb[(size_t)row * (2*DDE) + cg] = (bf16_t)v;
                } else {
                    const int c2 = cg - 2048;
                    const float kc = 1.f/(1.f + __expf(-v*0.0025f)) - 0.5f;
                    if (((row + 1) & (TT - 1)) != 0)
                        kcs[(size_t)(row + 1) * DDE + c2] = (bf16_t)kc;
                    if ((row & (TT - 1)) == 0)
                        kcs[(size_t)row * DDE + c2] = (bf16_t)0.f;
                }
            }
    }
}

// ---------------------------------------------------------------------------
// proj GEMM, BK=64, 2-phase double-buffered pipeline (fp32 out):
// C = A W^T + 2*bias
// ---------------------------------------------------------------------------
__global__ __launch_bounds__(256) void gemm_proj(
    const bf16_t* __restrict__ A, const bf16_t* __restrict__ W,
    const float* __restrict__ bias, float* __restrict__ C,
    int M, int N, int K, float bmul)
{
    __shared__ __align__(16) unsigned short As[2][128 * 64];
    __shared__ __align__(16) unsigned short Bs[2][128 * 64];
    const int tid  = threadIdx.x;
    const int wave = tid >> 6, lane = tid & 63;
    const int l15  = lane & 15, quad = lane >> 4;
    const int bm = blockIdx.y * 128, bn = blockIdx.x * 128;
    const int wm = (wave & 1) * 64, wn = (wave >> 1) * 64;

    const bf16_t* Ab = A + (size_t)bm * K;
    const bf16_t* Wb = W + (size_t)bn * K;

    f32x4 acc[4][4];
    #pragma unroll
    for (int i = 0; i < 4; ++i)
        #pragma unroll
        for (int j = 0; j < 4; ++j) acc[i][j] = (f32x4)0.f;

    stage_tile<128>(Ab, K, As[0], wave, lane);
    stage_tile<128>(Wb, K, Bs[0], wave, lane);
    __syncthreads();

    int cur = 0;
    for (int k0 = 0; k0 < K; k0 += 64) {
        if (k0 + 64 < K) {
            stage_tile<128>(Ab + k0 + 64, K, As[cur ^ 1], wave, lane);
            stage_tile<128>(Wb + k0 + 64, K, Bs[cur ^ 1], wave, lane);
        }
        const unsigned short* Ac = As[cur];
        const unsigned short* Bc = Bs[cur];
        bf16x8 af[4][2], bfr[4][2];
        #pragma unroll
        for (int mt = 0; mt < 4; ++mt)
            #pragma unroll
            for (int kh = 0; kh < 2; ++kh)
                af[mt][kh] = *(const bf16x8*)(Ac + (wm + mt*16 + l15)*64
                                              + (((kh*4 + quad) ^ (l15 & 7))*8));
        #pragma unroll
        for (int nt = 0; nt < 4; ++nt)
            #pragma unroll
            for (int kh = 0; kh < 2; ++kh)
                bfr[nt][kh] = *(const bf16x8*)(Bc + (wn + nt*16 + l15)*64
                                               + (((kh*4 + quad) ^ (l15 & 7))*8));
        #pragma unroll
        for (int mt = 0; mt < 4; ++mt)
            #pragma unroll
            for (int nt = 0; nt < 4; ++nt) {
                acc[mt][nt] = MFMA(af[mt][0], bfr[nt][0], acc[mt][nt]);
                acc[mt][nt] = MFMA(af[mt][1], bfr[nt][1], acc[mt][nt]);
            }
        __syncthreads();
        cur ^= 1;
    }

    #pragma unroll
    for (int nt = 0; nt < 4; ++nt) {
        const int col = bn + wn + nt*16 + l15;
        const float bj = bias[col] * bmul;
        #pragma unroll
        for (int mt = 0; mt < 4; ++mt)
            #pragma unroll
            for (int r = 0; r < 4; ++r) {
                const int row = bm + wm + mt*16 + quad*4 + r;
                C[(size_t)row * N + col] = acc[mt][nt][r] + bj;
            }
    }
}

// ---------------------------------------------------------------------------
// AR: fixed-max flash attention, split-s, double-buffered K/V staging,
// swapped QK^T (S^T layout) + in-register P repack (cvt_pk + ds_bpermute).
// Partials via fp32 atomics.
// ---------------------------------------------------------------------------
__global__ __launch_bounds__(256) void attn_ar_mfma(
    const bf16_t* __restrict__ qkb, const bf16_t* __restrict__ vtg,
    float* __restrict__ yo, float* __restrict__ lsum)
{
    int qt, ch;
    split_decode(39 - (int)blockIdx.x, qt, ch);
    const int h = blockIdx.y, b = blockIdx.z;
    const int tid = threadIdx.x, wave = tid >> 6, lane = tid & 63;
    const int l15 = lane & 15, quad = lane >> 4;
    const int q0 = qt * 128;
    const int bh = b * NHH + h;

    __shared__ __align__(16) unsigned short Qs[128 * 64];
    __shared__ __align__(16) unsigned short Ks[2][64 * 64];
    __shared__ __align__(16) unsigned short Vs[2][64 * 64];

    const int kt0 = ch * 8;
    const int kt1 = min(kt0 + 8, 2*qt + 2);
    const int nit = kt1 - kt0;

    const bf16_t* kg = qkb + (size_t)(b*TT + kt0*64)*(2*DDE) + DDE + h*HDD;
    const bf16_t* vg = vtg + (size_t)(bh*64)*TT + kt0*64;

    // prologue: Q + first K/V tile
    stage_tile<128>(qkb + (size_t)(b*TT + q0) * (2*DDE) + h*HDD, 2*DDE, Qs, wave, lane);
    stage_tile<64>(kg, 2*DDE, Ks[0], wave, lane);
    stage_tile<64>(vg, TT, Vs[0], wave, lane);
    __syncthreads();

    bf16x8 qf[2][2];
    #pragma unroll
    for (int mt = 0; mt < 2; ++mt)
        #pragma unroll
        for (int kc = 0; kc < 2; ++kc)
            qf[mt][kc] = *(const bf16x8*)(Qs + (wave*32 + mt*16 + l15)*64
                                          + ((kc*4 + quad) ^ (l15 & 7))*8);

    f32x4 o[2][4];
    float lrow[2];
    #pragma unroll
    for (int mt = 0; mt < 2; ++mt) {
        #pragma unroll
        for (int nt = 0; nt < 4; ++nt) o[mt][nt] = (f32x4)0.f;
        lrow[mt] = 0.f;
    }

    const int qw0 = q0 + wave * 32;
    // bpermute byte indices for cross-quad P repack
    const int idxA = ((((2*quad    ) & 3) << 4) + l15) << 2;
    const int idxB = ((((2*quad + 1) & 3) << 4) + l15) << 2;
    bool did = false;

    for (int it = 0; it < nit; ++it) {
        // issue next tile's staging before compute (2-phase pipeline)
        if (it + 1 < nit) {
            stage_tile<64>(kg + (size_t)(it+1)*64*(2*DDE), 2*DDE, Ks[(it+1)&1], wave, lane);
            stage_tile<64>(vg + (it+1)*64, TT, Vs[(it+1)&1], wave, lane);
        }
        const int s0 = (kt0 + it) * 64;
        if (s0 <= qw0 + 31) {
            did = true;
            const unsigned short* Kc = Ks[it & 1];
            const unsigned short* Vc = Vs[it & 1];

            // swapped QK: sv holds S^T — key = nt*16+quad*4+r, query = l15
            f32x4 sv[2][4];
            __builtin_amdgcn_s_setprio(1);
            #pragma unroll
            for (int nt = 0; nt < 4; ++nt) {
                const unsigned short* kr = Kc + (nt*16 + l15)*64;
                bf16x8 kb0 = *(const bf16x8*)(kr + ((quad    ) ^ (l15 & 7))*8);
                bf16x8 kb1 = *(const bf16x8*)(kr + ((quad + 4) ^ (l15 & 7))*8);
                #pragma unroll
                for (int mt = 0; mt < 2; ++mt) {
                    f32x4 z = (f32x4)0.f;
                    z = MFMA(kb0, qf[mt][0], z);
                    z = MFMA(kb1, qf[mt][1], z);
                    sv[mt][nt] = z;
                }
            }
            __builtin_amdgcn_s_setprio(0);

            const bool domask = (s0 + 63 > qw0);
            bf16x8 pa[2][2];
            #pragma unroll
            for (int mt = 0; mt < 2; ++mt) {
                const int qg = qw0 + mt*16 + l15;
                unsigned int pk[4][2];
                float lr = 0.f;
                #pragma unroll
                for (int nt = 0; nt < 4; ++nt) {
                    float pv[4];
                    #pragma unroll
                    for (int r = 0; r < 4; ++r) {
                        float p = exp2f(sv[mt][nt][r]);
                        if (domask) {
                            const int sg = s0 + nt*16 + quad*4 + r;
                            if (sg > qg) p = 0.f;
                        }
                        lr += p;
                        pv[r] = p;
                    }
                    pk[nt][0] = cvtpk(pv[0], pv[1]);
                    pk[nt][1] = cvtpk(pv[2], pv[3]);
                }
                lrow[mt] += lr;
                // repack S^T (C-layout) -> PV A-fragment:
                // word(sc,jp): key pair sc*32+quad*8+2jp from src lane
                // ((2q+(jp>>1))&3)*16+l15, source word pk[2sc+(q>>1)][jp&1]
                #pragma unroll
                for (int sc = 0; sc < 2; ++sc) {
                    union { unsigned int u[4]; bf16x8 v; } pu;
                    #pragma unroll
                    for (int jp = 0; jp < 4; ++jp) {
                        const int idx = (jp & 2) ? idxB : idxA;
                        const int lo = __builtin_amdgcn_ds_bpermute(idx, (int)pk[2*sc  ][jp & 1]);
                        const int hi = __builtin_amdgcn_ds_bpermute(idx, (int)pk[2*sc+1][jp & 1]);
                        pu.u[jp] = (quad & 2) ? (unsigned)hi : (unsigned)lo;
                    }
                    pa[mt][sc] = pu.v;
                }
            }

            __builtin_amdgcn_s_setprio(1);
            #pragma unroll
            for (int nt = 0; nt < 4; ++nt) {
                const unsigned short* vr = Vc + (nt*16 + l15)*64;
                bf16x8 vb0 = *(const bf16x8*)(vr + ((quad    ) ^ (l15 & 7))*8);
                bf16x8 vb1 = *(const bf16x8*)(vr + ((quad + 4) ^ (l15 & 7))*8);
                #pragma unroll
                for (int mt = 0; mt < 2; ++mt) {
                    o[mt][nt] = MFMA(pa[mt][0], vb0, o[mt][nt]);
                    o[mt][nt] = MFMA(pa[mt][1], vb1, o[mt][nt]);
                }
            }
            __builtin_amdgcn_s_setprio(0);
        }
        __syncthreads();
    }

    if (did) {
        #pragma unroll
        for (int mt = 0; mt < 2; ++mt) {
            float lv = lrow[mt];
            lv += __shfl_xor(lv, 16);
            lv += __shfl_xor(lv, 32);
            if (lane < 16)
                atomicAdd(lsum + (size_t)bh*TT + qw0 + mt*16 + l15, lv);
        }
        #pragma unroll
        for (int mt = 0; mt < 2; ++mt)
            #pragma unroll
            for (int nt = 0; nt < 4; ++nt)
                #pragma unroll
                for (int r = 0; r < 4; ++r) {
                    const int row = qw0 + mt*16 + quad*4 + r;
                    const int col = h*HDD + nt*16 + l15;
                    atomicAdd(yo + (size_t)(b*TT + row)*DDE + col, o[mt][nt][r]);
                }
    }
}

// ---------------------------------------------------------------------------
// MA: linear causal attention, split-s, same dbuf + swapped-S^T structure.
// ---------------------------------------------------------------------------
__global__ __launch_bounds__(256) void attn_ma_mfma(
    const bf16_t* __restrict__ qab, const bf16_t* __restrict__ kcs,
    const bf16_t* __restrict__ etg, float* __restrict__ ma)
{
    int qt, ch;
    split_decode(39 - (int)blockIdx.x, qt, ch);
    const int h = blockIdx.y, b = blockIdx.z;
    const int tid = threadIdx.x, wave = tid >> 6, lane = tid & 63;
    const int l15 = lane & 15, quad = lane >> 4;
    const int q0 = qt * 128;
    const int bh = b * NHH + h;

    __shared__ __align__(16) unsigned short Qs[128 * 64];
    __shared__ __align__(16) unsigned short Ks[2][64 * 64];
    __shared__ __align__(16) unsigned short Es[2][64 * 64];
    __shared__ float Rl[128];

    const int kt0 = ch * 8;
    const int kt1 = min(kt0 + 8, 2*qt + 2);
    const int nit = kt1 - kt0;

    const bf16_t* kg = kcs + (size_t)(b*TT + kt0*64)*DDE + h*HDD;
    const bf16_t* eg = etg + (size_t)(bh*64)*TT + kt0*64;

    stage_tile<128>(qab + (size_t)(b*TT + q0)*DDE + h*HDD, DDE, Qs, wave, lane);
    stage_tile<64>(kg, DDE, Ks[0], wave, lane);
    stage_tile<64>(eg, TT, Es[0], wave, lane);
    __syncthreads();
    if (tid < 128) {
        float s = 0.f;
        #pragma unroll
        for (int c = 0; c < 8; ++c) {
            bf16x8 v = *(const bf16x8*)(Qs + tid*64 + c*8);
            #pragma unroll
            for (int u = 0; u < 8; ++u) s += (float)v[u];
        }
        Rl[tid] = s;
    }
    __syncthreads();

    bf16x8 qf[2][2];
    float Rr[2];
    #pragma unroll
    for (int mt = 0; mt < 2; ++mt) {
        #pragma unroll
        for (int kc = 0; kc < 2; ++kc)
            qf[mt][kc] = *(const bf16x8*)(Qs + (wave*32 + mt*16 + l15)*64
                                          + ((kc*4 + quad) ^ (l15 & 7))*8);
        Rr[mt] = 0.5f * Rl[wave*32 + mt*16 + l15];
    }

    f32x4 o[2][4];
    #pragma unroll
    for (int mt = 0; mt < 2; ++mt)
        #pragma unroll
        for (int nt = 0; nt < 4; ++nt) o[mt][nt] = (f32x4)0.f;

    const int qw0 = q0 + wave * 32;
    const int idxA = ((((2*quad    ) & 3) << 4) + l15) << 2;
    const int idxB = ((((2*quad + 1) & 3) << 4) + l15) << 2;
    bool did = false;

    for (int it = 0; it < nit; ++it) {
        if (it + 1 < nit) {
            stage_tile<64>(kg + (size_t)(it+1)*64*DDE, DDE, Ks[(it+1)&1], wave, lane);
            stage_tile<64>(eg + (it+1)*64, TT, Es[(it+1)&1], wave, lane);
        }
        const int kt = kt0 + it;
        const int s0 = kt * 64;
        if (s0 <= qw0 + 31) {
            did = true;
            const unsigned short* Kc = Ks[it & 1];
            const unsigned short* Ec = Es[it & 1];

            f32x4 sv[2][4];
            __builtin_amdgcn_s_setprio(1);
            #pragma unroll
            for (int nt = 0; nt < 4; ++nt) {
                const unsigned short* kr = Kc + (nt*16 + l15)*64;
                bf16x8 kb0 = *(const bf16x8*)(kr + ((quad    ) ^ (l15 & 7))*8);
                bf16x8 kb1 = *(const bf16x8*)(kr + ((quad + 4) ^ (l15 & 7))*8);
                #pragma unroll
                for (int mt = 0; mt < 2; ++mt) {
                    f32x4 z = (f32x4)0.f;
                    z = MFMA(kb0, qf[mt][0], z);
                    z = MFMA(kb1, qf[mt][1], z);
                    sv[mt][nt] = z;
                }
            }
            __builtin_amdgcn_s_setprio(0);

            const bool domask = (s0 + 63 > qw0);
            const bool m0 = (kt == 0);
            bf16x8 pa[2][2];
            #pragma unroll
            for (int mt = 0; mt < 2; ++mt) {
                const int qg = qw0 + mt*16 + l15;
                unsigned int pk[4][2];
                #pragma unroll
                for (int nt = 0; nt < 4; ++nt) {
                    float pv[4];
                    #pragma unroll
                    for (int r = 0; r < 4; ++r) {
                        const int sg = s0 + nt*16 + quad*4 + r;
                        float p = sv[mt][nt][r] + Rr[mt];
                        if (m0 && sg == 0) p = 0.f;
                        if (domask && sg > qg) p = 0.f;
                        pv[r] = p;
                    }
                    pk[nt][0] = cvtpk(pv[0], pv[1]);
                    pk[nt][1] = cvtpk(pv[2], pv[3]);
                }
                #pragma unroll
                for (int sc = 0; sc < 2; ++sc) {
                    union { unsigned int u[4]; bf16x8 v; } pu;
                    #pragma unroll
                    for (int jp = 0; jp < 4; ++jp) {
                        const int idx = (jp & 2) ? idxB : idxA;
                        const int lo = __builtin_amdgcn_ds_bpermute(idx, (int)pk[2*sc  ][jp & 1]);
                        const int hi = __builtin_amdgcn_ds_bpermute(idx, (int)pk[2*sc+1][jp & 1]);
                        pu.u[jp] = (quad & 2) ? (unsigned)hi : (unsigned)lo;
                    }
                    pa[mt][sc] = pu.v;
                }
            }

            __builtin_amdgcn_s_setprio(1);
            #pragma unroll
            for (int nt = 0; nt < 4; ++nt) {
                const unsigned short* er = Ec + (nt*16 + l15)*64;
                bf16x8 eb0 = *(const bf16x8*)(er + ((quad    ) ^ (l15 & 7))*8);
                bf16x8 eb1 = *(const bf16x8*)(er + ((quad + 4) ^ (l15 & 7))*8);
                #pragma unroll
                for (int mt = 0; mt < 2; ++mt) {
                    o[mt][nt] = MFMA(pa[mt][0], eb0, o[mt][nt]);
                    o[mt][nt] = MFMA(pa[mt][1], eb1, o[mt][nt]);
                }
            }
            __builtin_amdgcn_s_setprio(0);
        }
        __syncthreads();
    }

    if (did) {
        #pragma unroll
        for (int mt = 0; mt < 2; ++mt)
            #pragma unroll
            for (int nt = 0; nt < 4; ++nt)
                #pragma unroll
                for (int r = 0; r < 4; ++r) {
                    const int row = qw0 + mt*16 + quad*4 + r;
                    const int col = h*HDD + nt*16 + l15;
                    atomicAdd(ma + (size_t)(b*TT + row)*DDE + col, o[mt][nt][r]);
                }
    }
}

// ---------------------------------------------------------------------------
// ysumb = bf16( yarb + ma )
// ---------------------------------------------------------------------------
__global__ __launch_bounds__(256) void combine(
    const bf16_t* __restrict__ yarb, const float* __restrict__ ma,
    bf16_t* __restrict__ ysumb)
{
    const size_t e = ((size_t)blockIdx.x * 256 + threadIdx.x) * 4;
    bf16x4 a = *(const bf16x4*)(yarb + e);
    float4 m = *(const float4*)(ma + e);
    bf16x4 o;
    o[0] = (bf16_t)((float)a[0] + m.x);
    o[1] = (bf16_t)((float)a[1] + m.y);
    o[2] = (bf16_t)((float)a[2] + m.z);
    o[3] = (bf16_t)((float)a[3] + m.w);
    *(bf16x4*)(ysumb + e) = o;
}

// ---------------------------------------------------------------------------
extern "C" void kernel_launch(void* const* d_in, const int* in_sizes, int n_in,
                              void* d_out, int out_size, void* d_ws, size_t ws_size,
                              hipStream_t stream)
{
    const float* x      = (const float*)d_in[0];
    const float* w_attn = (const float*)d_in[1];
    const float* b_attn = (const float*)d_in[2];
    const float* w_k2   = (const float*)d_in[3];
    const float* b_k2   = (const float*)d_in[4];
    const float* w_proj = (const float*)d_in[5];
    const float* b_proj = (const float*)d_in[6];

    const size_t NX  = (size_t)BB*TT*DDE;
    const size_t NWA = (size_t)2*DDE*DDE;
    const size_t NW  = (size_t)DDE*DDE;
    const size_t NQK = (size_t)BB*TT*2*DDE;

    bf16_t* xb   = (bf16_t*)d_ws;
    bf16_t* wab  = xb   + NX;
    bf16_t* wkb  = wab  + NWA;
    bf16_t* wpb  = wkb  + NW;
    bf16_t* qkb  = wpb  + NW;      // aliased by maf (f32) after attn_ar
    bf16_t* qab  = qkb  + NQK;
    bf16_t* kcs  = qab  + NX;
    bf16_t* vtg  = kcs  + NX;      // aliased by etg after attn_ar
    float*  yo   = (float*)(vtg + NX);  // aliased by ysumb after norm_build
    bf16_t* yarb = (bf16_t*)(yo + NX);
    float*  lsum = (float*)wab;    // aliases wab after gemm_qkk2
    float*  maf  = (float*)qkb;
    bf16_t* etg  = vtg;
    bf16_t* ysumb= (bf16_t*)yo;

    hipMemsetAsync(yo, 0, NX * sizeof(float), stream);

    const size_t NCVT = NX + NWA + NW + NW;
    cvt_all<<<NCVT / 1024, 256, 0, stream>>>(x, w_attn, w_k2, w_proj, xb);

    transpose_head<<<dim3(TT/64, NHH, BB), 256, 0, stream>>>(xb, vtg);

    const int M = BB * TT;
    gemm_qkk2<<<dim3(24, M/128), 256, 0, stream>>>(xb, wab, wkb, b_attn, b_k2,
                                                    qkb, qab, kcs);
    hipMemsetAsync(lsum, 0, (size_t)BB*NHH*TT * sizeof(float), stream);

    attn_ar_mfma<<<dim3(40, NHH, BB), 256, 0, stream>>>(qkb, vtg, yo, lsum);
    norm_build_etg<<<dim3(TT/64, NHH, BB), 256, 0, stream>>>(yo, lsum, xb, yarb, etg);

    hipMemsetAsync(maf, 0, NX * sizeof(float), stream);
    attn_ma_mfma<<<dim3(40, NHH, BB), 256, 0, stream>>>(qab, kcs, etg, maf);

    combine<<<NX / 1024, 256, 0, stream>>>(yarb, maf, ysumb);
    gemm_proj<<<dim3(DDE/128, M/128), 256, 0, stream>>>(ysumb, wpb, b_proj,
                                                        (float*)d_out, M, DDE, DDE, 2.f);
}

// Round 3
// 298.573 us; speedup vs baseline: 1.0189x; 1.0189x over previous
//
#include <hip/hip_runtime.h>
#include <hip/hip_bf16.h>
#include <math.h>

#define BB  2
#define TT  2048
#define DDE 1024
#define NHH 16
#define HDD 64

typedef __bf16 bf16_t;
typedef __attribute__((ext_vector_type(8))) __bf16 bf16x8;
typedef __attribute__((ext_vector_type(4))) __bf16 bf16x4;
typedef __attribute__((ext_vector_type(4))) float  f32x4;

#define MFMA(a, b, c) __builtin_amdgcn_mfma_f32_16x16x32_bf16((a), (b), (c), 0, 0, 0)

// counted waits: loads for the NEXT tile stay in flight across barriers (T4)
#define WAIT_VM8()   asm volatile("s_waitcnt vmcnt(8)" ::: "memory")
#define WAIT_VM4()   asm volatile("s_waitcnt vmcnt(4)" ::: "memory")
#define WAIT_VM0()   asm volatile("s_waitcnt vmcnt(0)" ::: "memory")
#define WAIT_LGKM0() asm volatile("s_waitcnt lgkmcnt(0)" ::: "memory")

// raw workgroup barrier (no vmcnt drain), fenced against compiler reordering
__device__ inline void wg_barrier() {
    __builtin_amdgcn_sched_barrier(0);
    __builtin_amdgcn_s_barrier();
    __builtin_amdgcn_sched_barrier(0);
}

__device__ inline unsigned short bf2us(bf16_t x) {
    union { bf16_t h; unsigned short u; } c; c.h = x; return c.u;
}

// pack 2 f32 -> 1 u32 of 2 bf16 (RNE), no builtin on gfx950
__device__ inline unsigned int cvtpk(float a, float b) {
    unsigned int r;
    asm("v_cvt_pk_bf16_f32 %0, %1, %2" : "=v"(r) : "v"(a), "v"(b));
    return r;
}

__device__ inline void gll16(const bf16_t* g, unsigned short* l) {
    __builtin_amdgcn_global_load_lds(
        (const __attribute__((address_space(1))) void*)g,
        (__attribute__((address_space(3))) void*)l, 16, 0, 0);
}

// Stage [ROWS x 64] bf16 tile (row stride gstride elems) into LDS via
// global_load_lds, chunk-swizzled: LDS elem [r][ (c ^ (r&7))*8 + j ].
// Per-wave gll16 count: ROWS/32  (128 -> 4, 64 -> 2).
template<int ROWS>
__device__ inline void stage_tile(const bf16_t* g0, size_t gstride,
                                  unsigned short* lds, int wave, int lane)
{
    const int r8 = lane >> 3;
    const int ck = (lane & 7) ^ r8;
    constexpr int RW = ROWS / 4;
    const bf16_t* g = g0 + (size_t)(wave * RW + r8) * gstride + ck * 8;
    unsigned short* l = lds + wave * RW * 64 + lane * 8;
    #pragma unroll
    for (int i = 0; i < RW / 8; ++i)
        gll16(g + (size_t)(i * 8) * gstride, l + i * 512);
}

// split-s work decomposition: 40 blocks cover 16 q-tiles x ceil(tiles/8) chunks
__device__ inline void split_decode(int wid, int& qt, int& ch) {
    const int g = (wid >= 24) ? 3 : (wid >= 12) ? 2 : (wid >= 4) ? 1 : 0;
    const int loc = wid - 2 * g * (g + 1);
    qt = 4 * g + loc / (g + 1);
    ch = loc % (g + 1);
}

// ---------------------------------------------------------------------------
// fused fp32->bf16 conversion of x, w_attn, w_k2, w_proj into the contiguous
// ws region starting at xb.  Segment boundaries are multiples of 1024 elems.
// ---------------------------------------------------------------------------
__global__ __launch_bounds__(256) void cvt_all(
    const float* __restrict__ x, const float* __restrict__ wa,
    const float* __restrict__ wk, const float* __restrict__ wp,
    bf16_t* __restrict__ out)
{
    const size_t NX  = (size_t)BB*TT*DDE;
    const size_t NWA = (size_t)2*DDE*DDE;
    const size_t NW  = (size_t)DDE*DDE;
    const size_t e = ((size_t)blockIdx.x * 256 + threadIdx.x) * 4;
    const float* src;
    if (e < NX)                 src = x  + e;
    else if (e < NX + NWA)      src = wa + (e - NX);
    else if (e < NX + NWA + NW) src = wk + (e - NX - NWA);
    else                        src = wp + (e - NX - NWA - NW);
    float4 v = *(const float4*)src;
    bf16x4 o;
    o[0] = (bf16_t)v.x; o[1] = (bf16_t)v.y;
    o[2] = (bf16_t)v.z; o[3] = (bf16_t)v.w;
    *(bf16x4*)(out + e) = o;
}

// ---------------------------------------------------------------------------
// Per-head 64x64 transpose: dst[bh][d][t] = src[b][t][h*64+d].
// ---------------------------------------------------------------------------
__global__ __launch_bounds__(256) void transpose_head(
    const bf16_t* __restrict__ src, bf16_t* __restrict__ dst)
{
    const int t0 = blockIdx.x * 64, h = blockIdx.y, b = blockIdx.z;
    const int tid = threadIdx.x;
    __shared__ __align__(16) bf16_t tile[64 * 64];

    #pragma unroll
    for (int it = 0; it < 2; ++it) {
        const int t = it * 32 + (tid >> 3);
        const int cw = tid & 7;
        const int slot = (cw + (t >> 3)) & 7;
        bf16x8 v = *(const bf16x8*)(src + (size_t)(b*TT + t0 + t)*DDE + h*HDD + cw*8);
        *(bf16x8*)(tile + t*64 + slot*8) = v;
    }
    __syncthreads();
    const int bh = b * NHH + h;
    #pragma unroll
    for (int it = 0; it < 2; ++it) {
        const int d = it * 32 + (tid >> 3);
        const int co = tid & 7;
        const int slot = ((d >> 3) + co) & 7;
        bf16x8 o;
        #pragma unroll
        for (int j = 0; j < 8; ++j)
            o[j] = tile[(co*8 + j)*64 + slot*8 + (d & 7)];
        *(bf16x8*)(dst + (size_t)(bh*64 + d)*TT + t0 + co*8) = o;
    }
}

// ---------------------------------------------------------------------------
// Fused normalize + E-transpose:
//   n[t] = yo[t] / lsum[t]  (AR output);  yarb[t] = bf16(n[t])
//   etg[bh][d][t] = x[t][d] - n[t-1][d]  (0 at t==0)
// ---------------------------------------------------------------------------
__global__ __launch_bounds__(256) void norm_build_etg(
    const float* __restrict__ yo, const float* __restrict__ ls,
    const bf16_t* __restrict__ xb, bf16_t* __restrict__ yarb,
    bf16_t* __restrict__ etg)
{
    const int t0 = blockIdx.x * 64, h = blockIdx.y, b = blockIdx.z;
    const int tid = threadIdx.x;
    const int bh = b * NHH + h;
    __shared__ __align__(16) bf16_t tile[64 * 64];

    #pragma unroll
    for (int it = 0; it < 2; ++it) {
        const int t = it * 32 + (tid >> 3);
        const int cw = tid & 7;
        const int slot = (cw + (t >> 3)) & 7;
        const int tg = t0 + t;
        const float inv = 1.f / ls[(size_t)bh*TT + tg];
        const float* yp = yo + (size_t)(b*TT + tg)*DDE + h*HDD + cw*8;
        float4 y0 = *(const float4*)yp;
        float4 y1 = *(const float4*)(yp + 4);
        bf16x8 nb;
        nb[0] = (bf16_t)(y0.x*inv); nb[1] = (bf16_t)(y0.y*inv);
        nb[2] = (bf16_t)(y0.z*inv); nb[3] = (bf16_t)(y0.w*inv);
        nb[4] = (bf16_t)(y1.x*inv); nb[5] = (bf16_t)(y1.y*inv);
        nb[6] = (bf16_t)(y1.z*inv); nb[7] = (bf16_t)(y1.w*inv);
        *(bf16x8*)(yarb + (size_t)(b*TT + tg)*DDE + h*HDD + cw*8) = nb;
        bf16x8 ev;
        if (tg == 0) {
            #pragma unroll
            for (int u = 0; u < 8; ++u) ev[u] = (bf16_t)0.f;
        } else {
            const float invp = 1.f / ls[(size_t)bh*TT + tg - 1];
            const float* ypp = yo + (size_t)(b*TT + tg - 1)*DDE + h*HDD + cw*8;
            float4 p0 = *(const float4*)ypp;
            float4 p1 = *(const float4*)(ypp + 4);
            bf16x8 xv = *(const bf16x8*)(xb + (size_t)(b*TT + tg)*DDE + h*HDD + cw*8);
            ev[0] = (bf16_t)((float)xv[0] - p0.x*invp);
            ev[1] = (bf16_t)((float)xv[1] - p0.y*invp);
            ev[2] = (bf16_t)((float)xv[2] - p0.z*invp);
            ev[3] = (bf16_t)((float)xv[3] - p0.w*invp);
            ev[4] = (bf16_t)((float)xv[4] - p1.x*invp);
            ev[5] = (bf16_t)((float)xv[5] - p1.y*invp);
            ev[6] = (bf16_t)((float)xv[6] - p1.z*invp);
            ev[7] = (bf16_t)((float)xv[7] - p1.w*invp);
        }
        *(bf16x8*)(tile + t*64 + slot*8) = ev;
    }
    __syncthreads();
    #pragma unroll
    for (int it = 0; it < 2; ++it) {
        const int d = it * 32 + (tid >> 3);
        const int co = tid & 7;
        const int slot = ((d >> 3) + co) & 7;
        bf16x8 o;
        #pragma unroll
        for (int j = 0; j < 8; ++j)
            o[j] = tile[(co*8 + j)*64 + slot*8 + (d & 7)];
        *(bf16x8*)(etg + (size_t)(bh*64 + d)*TT + t0 + co*8) = o;
    }
}

// ---------------------------------------------------------------------------
// Fused QKV GEMM, BK=64, counted-vmcnt double-buffered pipeline:
// next tile's global_load_lds stays in flight ACROSS the barrier (vmcnt(8),
// never 0 in steady state).  Region by column tile:
//   [0,1024):  q -> qkb = q*0.125*log2(e) (exp2 domain), qab = leaky(q*0.125)
//   [1024,2048): k -> qkb raw
//   [2048,3072): k2 -> kcs[t+1] = sigmoid(k2*0.0025)-0.5 (shifted, row0=0)
// ---------------------------------------------------------------------------
__global__ __launch_bounds__(256) void gemm_qkk2(
    const bf16_t* __restrict__ A, const bf16_t* __restrict__ wab,
    const bf16_t* __restrict__ wkb, const float* __restrict__ b_attn,
    const float* __restrict__ b_k2, bf16_t* __restrict__ qkb,
    bf16_t* __restrict__ qab, bf16_t* __restrict__ kcs)
{
    __shared__ __align__(16) unsigned short As[2][128 * 64];
    __shared__ __align__(16) unsigned short Bs[2][128 * 64];
    const int tid  = threadIdx.x;
    const int wave = tid >> 6, lane = tid & 63;
    const int l15  = lane & 15, quad = lane >> 4;
    const int bm = blockIdx.y * 128, bn = blockIdx.x * 128;
    const int wm = (wave & 1) * 64, wn = (wave >> 1) * 64;
    const int region = bn >> 10;
    const int K = DDE;
    constexpr int NST = DDE / 64;   // 16 K-steps

    const bf16_t* W = (region < 2) ? wab + (size_t)bn * K
                                   : wkb + (size_t)(bn - 2048) * K;
    const float* bp = (region < 2) ? b_attn + bn : b_k2 + (bn - 2048);
    const bf16_t* Ab = A + (size_t)bm * K;

    f32x4 acc[4][4];
    #pragma unroll
    for (int i = 0; i < 4; ++i)
        #pragma unroll
        for (int j = 0; j < 4; ++j) acc[i][j] = (f32x4)0.f;

    // prologue: stage K-steps 0 and 1 (8 gll16/wave each)
    stage_tile<128>(Ab, K, As[0], wave, lane);
    stage_tile<128>(W,  K, Bs[0], wave, lane);
    stage_tile<128>(Ab + 64, K, As[1], wave, lane);
    stage_tile<128>(W  + 64, K, Bs[1], wave, lane);

    for (int t = 0; t < NST; ++t) {
        // wait tile t landed; tile t+1's 8 loads stay in flight
        if (t + 1 < NST) WAIT_VM8(); else WAIT_VM0();
        wg_barrier();
        const unsigned short* Ac = As[t & 1];
        const unsigned short* Bc = Bs[t & 1];
        bf16x8 af[4][2], bfr[4][2];
        #pragma unroll
        for (int mt = 0; mt < 4; ++mt)
            #pragma unroll
            for (int kh = 0; kh < 2; ++kh)
                af[mt][kh] = *(const bf16x8*)(Ac + (wm + mt*16 + l15)*64
                                              + (((kh*4 + quad) ^ (l15 & 7))*8));
        #pragma unroll
        for (int nt = 0; nt < 4; ++nt)
            #pragma unroll
            for (int kh = 0; kh < 2; ++kh)
                bfr[nt][kh] = *(const bf16x8*)(Bc + (wn + nt*16 + l15)*64
                                               + (((kh*4 + quad) ^ (l15 & 7))*8));
        __builtin_amdgcn_s_setprio(1);
        #pragma unroll
        for (int mt = 0; mt < 4; ++mt)
            #pragma unroll
            for (int nt = 0; nt < 4; ++nt) {
                acc[mt][nt] = MFMA(af[mt][0], bfr[nt][0], acc[mt][nt]);
                acc[mt][nt] = MFMA(af[mt][1], bfr[nt][1], acc[mt][nt]);
            }
        __builtin_amdgcn_s_setprio(0);
        // all waves done reading buf[t&1] before restaging into it
        WAIT_LGKM0();
        wg_barrier();
        if (t + 2 < NST) {
            stage_tile<128>(Ab + (t+2)*64, K, As[t & 1], wave, lane);
            stage_tile<128>(W  + (t+2)*64, K, Bs[t & 1], wave, lane);
        }
    }

    #pragma unroll
    for (int nt = 0; nt < 4; ++nt) {
        const int cl = wn + nt*16 + l15;
        const float bj = bp[cl];
        const int cg = bn + cl;
        #pragma unroll
        for (int mt = 0; mt < 4; ++mt)
            #pragma unroll
            for (int r = 0; r < 4; ++r) {
                const int row = bm + wm + mt*16 + quad*4 + r;
                const float v = acc[mt][nt][r] + bj;
                if (region == 0) {
                    qkb[(size_t)row * (2*DDE) + cg] = (bf16_t)(v * 0.180336880f);
                    const float z = v * 0.125f;
                    qab[(size_t)row * DDE + cg] = (bf16_t)((v > 0.f) ? 0.02f*z : z);
                } else if (region == 1) {
                    qkb[(size_t)row * (2*DDE) + cg] = (bf16_t)v;
                } else {
                    const int c2 = cg - 2048;
                    const float kc = 1.f/(1.f + __expf(-v*0.0025f)) - 0.5f;
                    if (((row + 1) & (TT - 1)) != 0)
                        kcs[(size_t)(row + 1) * DDE + c2] = (bf16_t)kc;
                    if ((row & (TT - 1)) == 0)
                        kcs[(size_t)row * DDE + c2] = (bf16_t)0.f;
                }
            }
    }
}

// ---------------------------------------------------------------------------
// proj GEMM, BK=64, counted-vmcnt double-buffered pipeline (fp32 out):
// C = A W^T + 2*bias
// ---------------------------------------------------------------------------
__global__ __launch_bounds__(256) void gemm_proj(
    const bf16_t* __restrict__ A, const bf16_t* __restrict__ W,
    const float* __restrict__ bias, float* __restrict__ C,
    int M, int N, int K, float bmul)
{
    __shared__ __align__(16) unsigned short As[2][128 * 64];
    __shared__ __align__(16) unsigned short Bs[2][128 * 64];
    const int tid  = threadIdx.x;
    const int wave = tid >> 6, lane = tid & 63;
    const int l15  = lane & 15, quad = lane >> 4;
    const int bm = blockIdx.y * 128, bn = blockIdx.x * 128;
    const int wm = (wave & 1) * 64, wn = (wave >> 1) * 64;

    const bf16_t* Ab = A + (size_t)bm * K;
    const bf16_t* Wb = W + (size_t)bn * K;
    const int NST = K / 64;

    f32x4 acc[4][4];
    #pragma unroll
    for (int i = 0; i < 4; ++i)
        #pragma unroll
        for (int j = 0; j < 4; ++j) acc[i][j] = (f32x4)0.f;

    stage_tile<128>(Ab, K, As[0], wave, lane);
    stage_tile<128>(Wb, K, Bs[0], wave, lane);
    stage_tile<128>(Ab + 64, K, As[1], wave, lane);
    stage_tile<128>(Wb + 64, K, Bs[1], wave, lane);

    for (int t = 0; t < NST; ++t) {
        if (t + 1 < NST) WAIT_VM8(); else WAIT_VM0();
        wg_barrier();
        const unsigned short* Ac = As[t & 1];
        const unsigned short* Bc = Bs[t & 1];
        bf16x8 af[4][2], bfr[4][2];
        #pragma unroll
        for (int mt = 0; mt < 4; ++mt)
            #pragma unroll
            for (int kh = 0; kh < 2; ++kh)
                af[mt][kh] = *(const bf16x8*)(Ac + (wm + mt*16 + l15)*64
                                              + (((kh*4 + quad) ^ (l15 & 7))*8));
        #pragma unroll
        for (int nt = 0; nt < 4; ++nt)
            #pragma unroll
            for (int kh = 0; kh < 2; ++kh)
                bfr[nt][kh] = *(const bf16x8*)(Bc + (wn + nt*16 + l15)*64
                                               + (((kh*4 + quad) ^ (l15 & 7))*8));
        __builtin_amdgcn_s_setprio(1);
        #pragma unroll
        for (int mt = 0; mt < 4; ++mt)
            #pragma unroll
            for (int nt = 0; nt < 4; ++nt) {
                acc[mt][nt] = MFMA(af[mt][0], bfr[nt][0], acc[mt][nt]);
                acc[mt][nt] = MFMA(af[mt][1], bfr[nt][1], acc[mt][nt]);
            }
        __builtin_amdgcn_s_setprio(0);
        WAIT_LGKM0();
        wg_barrier();
        if (t + 2 < NST) {
            stage_tile<128>(Ab + (t+2)*64, K, As[t & 1], wave, lane);
            stage_tile<128>(Wb + (t+2)*64, K, Bs[t & 1], wave, lane);
        }
    }

    #pragma unroll
    for (int nt = 0; nt < 4; ++nt) {
        const int col = bn + wn + nt*16 + l15;
        const float bj = bias[col] * bmul;
        #pragma unroll
        for (int mt = 0; mt < 4; ++mt)
            #pragma unroll
            for (int r = 0; r < 4; ++r) {
                const int row = bm + wm + mt*16 + quad*4 + r;
                C[(size_t)row * N + col] = acc[mt][nt][r] + bj;
            }
    }
}

// ---------------------------------------------------------------------------
// AR: fixed-max flash attention, split-s, counted-vmcnt double-buffered K/V,
// swapped QK^T (S^T layout) + in-register P repack (cvt_pk + ds_bpermute).
// Partials via fp32 atomics.
// ---------------------------------------------------------------------------
__global__ __launch_bounds__(256) void attn_ar_mfma(
    const bf16_t* __restrict__ qkb, const bf16_t* __restrict__ vtg,
    float* __restrict__ yo, float* __restrict__ lsum)
{
    int qt, ch;
    split_decode(39 - (int)blockIdx.x, qt, ch);
    const int h = blockIdx.y, b = blockIdx.z;
    const int tid = threadIdx.x, wave = tid >> 6, lane = tid & 63;
    const int l15 = lane & 15, quad = lane >> 4;
    const int q0 = qt * 128;
    const int bh = b * NHH + h;

    __shared__ __align__(16) unsigned short Qs[128 * 64];
    __shared__ __align__(16) unsigned short Ks[2][64 * 64];
    __shared__ __align__(16) unsigned short Vs[2][64 * 64];

    const int kt0 = ch * 8;
    const int kt1 = min(kt0 + 8, 2*qt + 2);
    const int nit = kt1 - kt0;

    const bf16_t* kg = qkb + (size_t)(b*TT + kt0*64)*(2*DDE) + DDE + h*HDD;
    const bf16_t* vg = vtg + (size_t)(bh*64)*TT + kt0*64;

    // prologue: Q (4 loads/wave) + tiles 0,1 (4 loads/wave each)
    stage_tile<128>(qkb + (size_t)(b*TT + q0) * (2*DDE) + h*HDD, 2*DDE, Qs, wave, lane);
    stage_tile<64>(kg, 2*DDE, Ks[0], wave, lane);
    stage_tile<64>(vg, TT, Vs[0], wave, lane);
    if (nit > 1) {
        stage_tile<64>(kg + (size_t)64*(2*DDE), 2*DDE, Ks[1], wave, lane);
        stage_tile<64>(vg + 64, TT, Vs[1], wave, lane);
        WAIT_VM4();            // Q + tile0 done, tile1 in flight
    } else {
        WAIT_VM0();
    }
    wg_barrier();

    bf16x8 qf[2][2];
    #pragma unroll
    for (int mt = 0; mt < 2; ++mt)
        #pragma unroll
        for (int kc = 0; kc < 2; ++kc)
            qf[mt][kc] = *(const bf16x8*)(Qs + (wave*32 + mt*16 + l15)*64
                                          + ((kc*4 + quad) ^ (l15 & 7))*8);

    f32x4 o[2][4];
    float lrow[2];
    #pragma unroll
    for (int mt = 0; mt < 2; ++mt) {
        #pragma unroll
        for (int nt = 0; nt < 4; ++nt) o[mt][nt] = (f32x4)0.f;
        lrow[mt] = 0.f;
    }

    const int qw0 = q0 + wave * 32;
    // bpermute byte indices for cross-quad P repack
    const int idxA = ((((2*quad    ) & 3) << 4) + l15) << 2;
    const int idxB = ((((2*quad + 1) & 3) << 4) + l15) << 2;
    bool did = false;

    for (int it = 0; it < nit; ++it) {
        if (it > 0) {
            if (it + 1 < nit) WAIT_VM4(); else WAIT_VM0();
            wg_barrier();
        }
        const int s0 = (kt0 + it) * 64;
        if (s0 <= qw0 + 31) {
            did = true;
            const unsigned short* Kc = Ks[it & 1];
            const unsigned short* Vc = Vs[it & 1];

            // swapped QK: sv holds S^T — key = nt*16+quad*4+r, query = l15
            f32x4 sv[2][4];
            __builtin_amdgcn_s_setprio(1);
            #pragma unroll
            for (int nt = 0; nt < 4; ++nt) {
                const unsigned short* kr = Kc + (nt*16 + l15)*64;
                bf16x8 kb0 = *(const bf16x8*)(kr + ((quad    ) ^ (l15 & 7))*8);
                bf16x8 kb1 = *(const bf16x8*)(kr + ((quad + 4) ^ (l15 & 7))*8);
                #pragma unroll
                for (int mt = 0; mt < 2; ++mt) {
                    f32x4 z = (f32x4)0.f;
                    z = MFMA(kb0, qf[mt][0], z);
                    z = MFMA(kb1, qf[mt][1], z);
                    sv[mt][nt] = z;
                }
            }
            __builtin_amdgcn_s_setprio(0);

            const bool domask = (s0 + 63 > qw0);
            bf16x8 pa[2][2];
            #pragma unroll
            for (int mt = 0; mt < 2; ++mt) {
                const int qg = qw0 + mt*16 + l15;
                unsigned int pk[4][2];
                float lr = 0.f;
                #pragma unroll
                for (int nt = 0; nt < 4; ++nt) {
                    float pv[4];
                    #pragma unroll
                    for (int r = 0; r < 4; ++r) {
                        float p = exp2f(sv[mt][nt][r]);
                        if (domask) {
                            const int sg = s0 + nt*16 + quad*4 + r;
                            if (sg > qg) p = 0.f;
                        }
                        lr += p;
                        pv[r] = p;
                    }
                    pk[nt][0] = cvtpk(pv[0], pv[1]);
                    pk[nt][1] = cvtpk(pv[2], pv[3]);
                }
                lrow[mt] += lr;
                // repack S^T (C-layout) -> PV A-fragment
                #pragma unroll
                for (int sc = 0; sc < 2; ++sc) {
                    union { unsigned int u[4]; bf16x8 v; } pu;
                    #pragma unroll
                    for (int jp = 0; jp < 4; ++jp) {
                        const int idx = (jp & 2) ? idxB : idxA;
                        const int lo = __builtin_amdgcn_ds_bpermute(idx, (int)pk[2*sc  ][jp & 1]);
                        const int hi = __builtin_amdgcn_ds_bpermute(idx, (int)pk[2*sc+1][jp & 1]);
                        pu.u[jp] = (quad & 2) ? (unsigned)hi : (unsigned)lo;
                    }
                    pa[mt][sc] = pu.v;
                }
            }

            __builtin_amdgcn_s_setprio(1);
            #pragma unroll
            for (int nt = 0; nt < 4; ++nt) {
                const unsigned short* vr = Vc + (nt*16 + l15)*64;
                bf16x8 vb0 = *(const bf16x8*)(vr + ((quad    ) ^ (l15 & 7))*8);
                bf16x8 vb1 = *(const bf16x8*)(vr + ((quad + 4) ^ (l15 & 7))*8);
                #pragma unroll
                for (int mt = 0; mt < 2; ++mt) {
                    o[mt][nt] = MFMA(pa[mt][0], vb0, o[mt][nt]);
                    o[mt][nt] = MFMA(pa[mt][1], vb1, o[mt][nt]);
                }
            }
            __builtin_amdgcn_s_setprio(0);
        }
        WAIT_LGKM0();
        wg_barrier();
        if (it + 2 < nit) {
            stage_tile<64>(kg + (size_t)(it+2)*64*(2*DDE), 2*DDE, Ks[it & 1], wave, lane);
            stage_tile<64>(vg + (it+2)*64, TT, Vs[it & 1], wave, lane);
        }
    }

    if (did) {
        #pragma unroll
        for (int mt = 0; mt < 2; ++mt) {
            float lv = lrow[mt];
            lv += __shfl_xor(lv, 16);
            lv += __shfl_xor(lv, 32);
            if (lane < 16)
                atomicAdd(lsum + (size_t)bh*TT + qw0 + mt*16 + l15, lv);
        }
        #pragma unroll
        for (int mt = 0; mt < 2; ++mt)
            #pragma unroll
            for (int nt = 0; nt < 4; ++nt)
                #pragma unroll
                for (int r = 0; r < 4; ++r) {
                    const int row = qw0 + mt*16 + quad*4 + r;
                    const int col = h*HDD + nt*16 + l15;
                    atomicAdd(yo + (size_t)(b*TT + row)*DDE + col, o[mt][nt][r]);
                }
    }
}

// ---------------------------------------------------------------------------
// MA: linear causal attention, split-s, counted-vmcnt dbuf, swapped-S^T.
// ---------------------------------------------------------------------------
__global__ __launch_bounds__(256) void attn_ma_mfma(
    const bf16_t* __restrict__ qab, const bf16_t* __restrict__ kcs,
    const bf16_t* __restrict__ etg, float* __restrict__ ma)
{
    int qt, ch;
    split_decode(39 - (int)blockIdx.x, qt, ch);
    const int h = blockIdx.y, b = blockIdx.z;
    const int tid = threadIdx.x, wave = tid >> 6, lane = tid & 63;
    const int l15 = lane & 15, quad = lane >> 4;
    const int q0 = qt * 128;
    const int bh = b * NHH + h;

    __shared__ __align__(16) unsigned short Qs[128 * 64];
    __shared__ __align__(16) unsigned short Ks[2][64 * 64];
    __shared__ __align__(16) unsigned short Es[2][64 * 64];
    __shared__ float Rl[128];

    const int kt0 = ch * 8;
    const int kt1 = min(kt0 + 8, 2*qt + 2);
    const int nit = kt1 - kt0;

    const bf16_t* kg = kcs + (size_t)(b*TT + kt0*64)*DDE + h*HDD;
    const bf16_t* eg = etg + (size_t)(bh*64)*TT + kt0*64;

    stage_tile<128>(qab + (size_t)(b*TT + q0)*DDE + h*HDD, DDE, Qs, wave, lane);
    stage_tile<64>(kg, DDE, Ks[0], wave, lane);
    stage_tile<64>(eg, TT, Es[0], wave, lane);
    if (nit > 1) {
        stage_tile<64>(kg + (size_t)64*DDE, DDE, Ks[1], wave, lane);
        stage_tile<64>(eg + 64, TT, Es[1], wave, lane);
        WAIT_VM4();
    } else {
        WAIT_VM0();
    }
    wg_barrier();

    if (tid < 128) {
        float s = 0.f;
        #pragma unroll
        for (int c = 0; c < 8; ++c) {
            bf16x8 v = *(const bf16x8*)(Qs + tid*64 + c*8);
            #pragma unroll
            for (int u = 0; u < 8; ++u) s += (float)v[u];
        }
        Rl[tid] = s;
    }
    WAIT_LGKM0();
    wg_barrier();

    bf16x8 qf[2][2];
    float Rr[2];
    #pragma unroll
    for (int mt = 0; mt < 2; ++mt) {
        #pragma unroll
        for (int kc = 0; kc < 2; ++kc)
            qf[mt][kc] = *(const bf16x8*)(Qs + (wave*32 + mt*16 + l15)*64
                                          + ((kc*4 + quad) ^ (l15 & 7))*8);
        Rr[mt] = 0.5f * Rl[wave*32 + mt*16 + l15];
    }

    f32x4 o[2][4];
    #pragma unroll
    for (int mt = 0; mt < 2; ++mt)
        #pragma unroll
        for (int nt = 0; nt < 4; ++nt) o[mt][nt] = (f32x4)0.f;

    const int qw0 = q0 + wave * 32;
    const int idxA = ((((2*quad    ) & 3) << 4) + l15) << 2;
    const int idxB = ((((2*quad + 1) & 3) << 4) + l15) << 2;
    bool did = false;

    for (int it = 0; it < nit; ++it) {
        if (it > 0) {
            if (it + 1 < nit) WAIT_VM4(); else WAIT_VM0();
            wg_barrier();
        }
        const int kt = kt0 + it;
        const int s0 = kt * 64;
        if (s0 <= qw0 + 31) {
            did = true;
            const unsigned short* Kc = Ks[it & 1];
            const unsigned short* Ec = Es[it & 1];

            f32x4 sv[2][4];
            __builtin_amdgcn_s_setprio(1);
            #pragma unroll
            for (int nt = 0; nt < 4; ++nt) {
                const unsigned short* kr = Kc + (nt*16 + l15)*64;
                bf16x8 kb0 = *(const bf16x8*)(kr + ((quad    ) ^ (l15 & 7))*8);
                bf16x8 kb1 = *(const bf16x8*)(kr + ((quad + 4) ^ (l15 & 7))*8);
                #pragma unroll
                for (int mt = 0; mt < 2; ++mt) {
                    f32x4 z = (f32x4)0.f;
                    z = MFMA(kb0, qf[mt][0], z);
                    z = MFMA(kb1, qf[mt][1], z);
                    sv[mt][nt] = z;
                }
            }
            __builtin_amdgcn_s_setprio(0);

            const bool domask = (s0 + 63 > qw0);
            const bool m0 = (kt == 0);
            bf16x8 pa[2][2];
            #pragma unroll
            for (int mt = 0; mt < 2; ++mt) {
                const int qg = qw0 + mt*16 + l15;
                unsigned int pk[4][2];
                #pragma unroll
                for (int nt = 0; nt < 4; ++nt) {
                    float pv[4];
                    #pragma unroll
                    for (int r = 0; r < 4; ++r) {
                        const int sg = s0 + nt*16 + quad*4 + r;
                        float p = sv[mt][nt][r] + Rr[mt];
                        if (m0 && sg == 0) p = 0.f;
                        if (domask && sg > qg) p = 0.f;
                        pv[r] = p;
                    }
                    pk[nt][0] = cvtpk(pv[0], pv[1]);
                    pk[nt][1] = cvtpk(pv[2], pv[3]);
                }
                #pragma unroll
                for (int sc = 0; sc < 2; ++sc) {
                    union { unsigned int u[4]; bf16x8 v; } pu;
                    #pragma unroll
                    for (int jp = 0; jp < 4; ++jp) {
                        const int idx = (jp & 2) ? idxB : idxA;
                        const int lo = __builtin_amdgcn_ds_bpermute(idx, (int)pk[2*sc  ][jp & 1]);
                        const int hi = __builtin_amdgcn_ds_bpermute(idx, (int)pk[2*sc+1][jp & 1]);
                        pu.u[jp] = (quad & 2) ? (unsigned)hi : (unsigned)lo;
                    }
                    pa[mt][sc] = pu.v;
                }
            }

            __builtin_amdgcn_s_setprio(1);
            #pragma unroll
            for (int nt = 0; nt < 4; ++nt) {
                const unsigned short* er = Ec + (nt*16 + l15)*64;
                bf16x8 eb0 = *(const bf16x8*)(er + ((quad    ) ^ (l15 & 7))*8);
                bf16x8 eb1 = *(const bf16x8*)(er + ((quad + 4) ^ (l15 & 7))*8);
                #pragma unroll
                for (int mt = 0; mt < 2; ++mt) {
                    o[mt][nt] = MFMA(pa[mt][0], eb0, o[mt][nt]);
                    o[mt][nt] = MFMA(pa[mt][1], eb1, o[mt][nt]);
                }
            }
            __builtin_amdgcn_s_setprio(0);
        }
        WAIT_LGKM0();
        wg_barrier();
        if (it + 2 < nit) {
            stage_tile<64>(kg + (size_t)(it+2)*64*DDE, DDE, Ks[it & 1], wave, lane);
            stage_tile<64>(eg + (it+2)*64, TT, Es[it & 1], wave, lane);
        }
    }

    if (did) {
        #pragma unroll
        for (int mt = 0; mt < 2; ++mt)
            #pragma unroll
            for (int nt = 0; nt < 4; ++nt)
                #pragma unroll
                for (int r = 0; r < 4; ++r) {
                    const int row = qw0 + mt*16 + quad*4 + r;
                    const int col = h*HDD + nt*16 + l15;
                    atomicAdd(ma + (size_t)(b*TT + row)*DDE + col, o[mt][nt][r]);
                }
    }
}

// ---------------------------------------------------------------------------
// ysumb = bf16( yarb + ma )
// ---------------------------------------------------------------------------
__global__ __launch_bounds__(256) void combine(
    const bf16_t* __restrict__ yarb, const float* __restrict__ ma,
    bf16_t* __restrict__ ysumb)
{
    const size_t e = ((size_t)blockIdx.x * 256 + threadIdx.x) * 4;
    bf16x4 a = *(const bf16x4*)(yarb + e);
    float4 m = *(const float4*)(ma + e);
    bf16x4 o;
    o[0] = (bf16_t)((float)a[0] + m.x);
    o[1] = (bf16_t)((float)a[1] + m.y);
    o[2] = (bf16_t)((float)a[2] + m.z);
    o[3] = (bf16_t)((float)a[3] + m.w);
    *(bf16x4*)(ysumb + e) = o;
}

// ---------------------------------------------------------------------------
extern "C" void kernel_launch(void* const* d_in, const int* in_sizes, int n_in,
                              void* d_out, int out_size, void* d_ws, size_t ws_size,
                              hipStream_t stream)
{
    const float* x      = (const float*)d_in[0];
    const float* w_attn = (const float*)d_in[1];
    const float* b_attn = (const float*)d_in[2];
    const float* w_k2   = (const float*)d_in[3];
    const float* b_k2   = (const float*)d_in[4];
    const float* w_proj = (const float*)d_in[5];
    const float* b_proj = (const float*)d_in[6];

    const size_t NX  = (size_t)BB*TT*DDE;
    const size_t NWA = (size_t)2*DDE*DDE;
    const size_t NW  = (size_t)DDE*DDE;
    const size_t NQK = (size_t)BB*TT*2*DDE;

    bf16_t* xb   = (bf16_t*)d_ws;
    bf16_t* wab  = xb   + NX;
    bf16_t* wkb  = wab  + NWA;
    bf16_t* wpb  = wkb  + NW;
    bf16_t* qkb  = wpb  + NW;      // aliased by maf (f32) after attn_ar
    bf16_t* qab  = qkb  + NQK;
    bf16_t* kcs  = qab  + NX;
    bf16_t* vtg  = kcs  + NX;      // aliased by etg after attn_ar
    float*  yo   = (float*)(vtg + NX);  // aliased by ysumb after norm_build
    bf16_t* yarb = (bf16_t*)(yo + NX);
    float*  lsum = (float*)wab;    // aliases wab after gemm_qkk2
    float*  maf  = (float*)qkb;
    bf16_t* etg  = vtg;
    bf16_t* ysumb= (bf16_t*)yo;

    hipMemsetAsync(yo, 0, NX * sizeof(float), stream);

    const size_t NCVT = NX + NWA + NW + NW;
    cvt_all<<<NCVT / 1024, 256, 0, stream>>>(x, w_attn, w_k2, w_proj, xb);

    transpose_head<<<dim3(TT/64, NHH, BB), 256, 0, stream>>>(xb, vtg);

    const int M = BB * TT;
    gemm_qkk2<<<dim3(24, M/128), 256, 0, stream>>>(xb, wab, wkb, b_attn, b_k2,
                                                    qkb, qab, kcs);
    hipMemsetAsync(lsum, 0, (size_t)BB*NHH*TT * sizeof(float), stream);

    attn_ar_mfma<<<dim3(40, NHH, BB), 256, 0, stream>>>(qkb, vtg, yo, lsum);
    norm_build_etg<<<dim3(TT/64, NHH, BB), 256, 0, stream>>>(yo, lsum, xb, yarb, etg);

    hipMemsetAsync(maf, 0, NX * sizeof(float), stream);
    attn_ma_mfma<<<dim3(40, NHH, BB), 256, 0, stream>>>(qab, kcs, etg, maf);

    combine<<<NX / 1024, 256, 0, stream>>>(yarb, maf, ysumb);
    gemm_proj<<<dim3(DDE/128, M/128), 256, 0, stream>>>(ysumb, wpb, b_proj,
                                                        (float*)d_out, M, DDE, DDE, 2.f);
}

// Round 4
// 292.246 us; speedup vs baseline: 1.0410x; 1.0216x over previous
//
#include <hip/hip_runtime.h>
#include <hip/hip_bf16.h>
#include <math.h>

#define BB  2
#define TT  2048
#define DDE 1024
#define NHH 16
#define HDD 64

typedef __bf16 bf16_t;
typedef __attribute__((ext_vector_type(8))) __bf16 bf16x8;
typedef __attribute__((ext_vector_type(4))) __bf16 bf16x4;
typedef __attribute__((ext_vector_type(4))) float  f32x4;

#define MFMA(a, b, c) __builtin_amdgcn_mfma_f32_16x16x32_bf16((a), (b), (c), 0, 0, 0)

// counted waits: loads for the NEXT tile stay in flight across barriers (T4)
#define WAIT_VM8()   asm volatile("s_waitcnt vmcnt(8)" ::: "memory")
#define WAIT_VM4()   asm volatile("s_waitcnt vmcnt(4)" ::: "memory")
#define WAIT_VM0()   asm volatile("s_waitcnt vmcnt(0)" ::: "memory")
#define WAIT_LGKM0() asm volatile("s_waitcnt lgkmcnt(0)" ::: "memory")

// raw workgroup barrier (no vmcnt drain), fenced against compiler reordering
__device__ inline void wg_barrier() {
    __builtin_amdgcn_sched_barrier(0);
    __builtin_amdgcn_s_barrier();
    __builtin_amdgcn_sched_barrier(0);
}

// pack 2 f32 -> 1 u32 of 2 bf16 (RNE), no builtin on gfx950
__device__ inline unsigned int cvtpk(float a, float b) {
    unsigned int r;
    asm("v_cvt_pk_bf16_f32 %0, %1, %2" : "=v"(r) : "v"(a), "v"(b));
    return r;
}

__device__ inline void gll16(const bf16_t* g, unsigned short* l) {
    __builtin_amdgcn_global_load_lds(
        (const __attribute__((address_space(1))) void*)g,
        (__attribute__((address_space(3))) void*)l, 16, 0, 0);
}

// Stage [ROWS x 64] bf16 tile (row stride gstride elems) into LDS via
// global_load_lds, chunk-swizzled: LDS elem [r][ (c ^ (r&7))*8 + j ].
// Per-wave gll16 count: ROWS/32  (128 -> 4, 64 -> 2).
template<int ROWS>
__device__ inline void stage_tile(const bf16_t* g0, size_t gstride,
                                  unsigned short* lds, int wave, int lane)
{
    const int r8 = lane >> 3;
    const int ck = (lane & 7) ^ r8;
    constexpr int RW = ROWS / 4;
    const bf16_t* g = g0 + (size_t)(wave * RW + r8) * gstride + ck * 8;
    unsigned short* l = lds + wave * RW * 64 + lane * 8;
    #pragma unroll
    for (int i = 0; i < RW / 8; ++i)
        gll16(g + (size_t)(i * 8) * gstride, l + i * 512);
}

// ---------------------------------------------------------------------------
// fused fp32->bf16 conversion of x, w_attn, w_k2, w_proj into the contiguous
// ws region starting at xb.  Segment boundaries are multiples of 1024 elems.
// ---------------------------------------------------------------------------
__global__ __launch_bounds__(256) void cvt_all(
    const float* __restrict__ x, const float* __restrict__ wa,
    const float* __restrict__ wk, const float* __restrict__ wp,
    bf16_t* __restrict__ out)
{
    const size_t NX  = (size_t)BB*TT*DDE;
    const size_t NWA = (size_t)2*DDE*DDE;
    const size_t NW  = (size_t)DDE*DDE;
    const size_t e = ((size_t)blockIdx.x * 256 + threadIdx.x) * 4;
    const float* src;
    if (e < NX)                 src = x  + e;
    else if (e < NX + NWA)      src = wa + (e - NX);
    else if (e < NX + NWA + NW) src = wk + (e - NX - NWA);
    else                        src = wp + (e - NX - NWA - NW);
    float4 v = *(const float4*)src;
    bf16x4 o;
    o[0] = (bf16_t)v.x; o[1] = (bf16_t)v.y;
    o[2] = (bf16_t)v.z; o[3] = (bf16_t)v.w;
    *(bf16x4*)(out + e) = o;
}

// ---------------------------------------------------------------------------
// Per-head 64x64 transpose: dst[bh][d][t] = src[b][t][h*64+d].
// ---------------------------------------------------------------------------
__global__ __launch_bounds__(256) void transpose_head(
    const bf16_t* __restrict__ src, bf16_t* __restrict__ dst)
{
    const int t0 = blockIdx.x * 64, h = blockIdx.y, b = blockIdx.z;
    const int tid = threadIdx.x;
    __shared__ __align__(16) bf16_t tile[64 * 64];

    #pragma unroll
    for (int it = 0; it < 2; ++it) {
        const int t = it * 32 + (tid >> 3);
        const int cw = tid & 7;
        const int slot = (cw + (t >> 3)) & 7;
        bf16x8 v = *(const bf16x8*)(src + (size_t)(b*TT + t0 + t)*DDE + h*HDD + cw*8);
        *(bf16x8*)(tile + t*64 + slot*8) = v;
    }
    __syncthreads();
    const int bh = b * NHH + h;
    #pragma unroll
    for (int it = 0; it < 2; ++it) {
        const int d = it * 32 + (tid >> 3);
        const int co = tid & 7;
        const int slot = ((d >> 3) + co) & 7;
        bf16x8 o;
        #pragma unroll
        for (int j = 0; j < 8; ++j)
            o[j] = tile[(co*8 + j)*64 + slot*8 + (d & 7)];
        *(bf16x8*)(dst + (size_t)(bh*64 + d)*TT + t0 + co*8) = o;
    }
}

// ---------------------------------------------------------------------------
// E-transpose: etg[bh][d][t] = x[t][d] - n[t-1][d]  (0 at t==0),
// where n = yarb (normalized AR output, written by attn_ar).
// ---------------------------------------------------------------------------
__global__ __launch_bounds__(256) void build_etg(
    const bf16_t* __restrict__ yarb, const bf16_t* __restrict__ xb,
    bf16_t* __restrict__ etg)
{
    const int t0 = blockIdx.x * 64, h = blockIdx.y, b = blockIdx.z;
    const int tid = threadIdx.x;
    const int bh = b * NHH + h;
    __shared__ __align__(16) bf16_t tile[64 * 64];

    #pragma unroll
    for (int it = 0; it < 2; ++it) {
        const int t = it * 32 + (tid >> 3);
        const int cw = tid & 7;
        const int slot = (cw + (t >> 3)) & 7;
        const int tg = t0 + t;
        bf16x8 ev;
        if (tg == 0) {
            #pragma unroll
            for (int u = 0; u < 8; ++u) ev[u] = (bf16_t)0.f;
        } else {
            bf16x8 xv = *(const bf16x8*)(xb   + (size_t)(b*TT + tg)*DDE + h*HDD + cw*8);
            bf16x8 nv = *(const bf16x8*)(yarb + (size_t)(b*TT + tg - 1)*DDE + h*HDD + cw*8);
            #pragma unroll
            for (int u = 0; u < 8; ++u)
                ev[u] = (bf16_t)((float)xv[u] - (float)nv[u]);
        }
        *(bf16x8*)(tile + t*64 + slot*8) = ev;
    }
    __syncthreads();
    #pragma unroll
    for (int it = 0; it < 2; ++it) {
        const int d = it * 32 + (tid >> 3);
        const int co = tid & 7;
        const int slot = ((d >> 3) + co) & 7;
        bf16x8 o;
        #pragma unroll
        for (int j = 0; j < 8; ++j)
            o[j] = tile[(co*8 + j)*64 + slot*8 + (d & 7)];
        *(bf16x8*)(etg + (size_t)(bh*64 + d)*TT + t0 + co*8) = o;
    }
}

// ---------------------------------------------------------------------------
// Fused QKV GEMM, BK=64, counted-vmcnt dbuf pipeline + XCD-aware swizzle.
// Region by column tile:
//   [0,1024):  q -> qkb = q*0.125*log2(e) (exp2 domain), qab = leaky(q*0.125)
//   [1024,2048): k -> qkb raw
//   [2048,3072): k2 -> kcs[t+1] = sigmoid(k2*0.0025)-0.5 (shifted, row0=0)
// ---------------------------------------------------------------------------
__global__ __launch_bounds__(256) void gemm_qkk2(
    const bf16_t* __restrict__ A, const bf16_t* __restrict__ wab,
    const bf16_t* __restrict__ wkb, const float* __restrict__ b_attn,
    const float* __restrict__ b_k2, bf16_t* __restrict__ qkb,
    bf16_t* __restrict__ qab, bf16_t* __restrict__ kcs)
{
    __shared__ __align__(16) unsigned short As[2][128 * 64];
    __shared__ __align__(16) unsigned short Bs[2][128 * 64];
    const int tid  = threadIdx.x;
    const int wave = tid >> 6, lane = tid & 63;
    const int l15  = lane & 15, quad = lane >> 4;
    // XCD swizzle (bijective: 768 = 8*96): each XCD gets 4 contiguous M-rows
    // across all 24 N-tiles -> A-panels L2-resident per XCD.
    const int lid = (int)blockIdx.y * 24 + (int)blockIdx.x;
    const int s   = (lid & 7) * 96 + (lid >> 3);
    const int bm = (s / 24) * 128, bn = (s % 24) * 128;
    const int wm = (wave & 1) * 64, wn = (wave >> 1) * 64;
    const int region = bn >> 10;
    const int K = DDE;
    constexpr int NST = DDE / 64;   // 16 K-steps

    const bf16_t* W = (region < 2) ? wab + (size_t)bn * K
                                   : wkb + (size_t)(bn - 2048) * K;
    const float* bp = (region < 2) ? b_attn + bn : b_k2 + (bn - 2048);
    const bf16_t* Ab = A + (size_t)bm * K;

    f32x4 acc[4][4];
    #pragma unroll
    for (int i = 0; i < 4; ++i)
        #pragma unroll
        for (int j = 0; j < 4; ++j) acc[i][j] = (f32x4)0.f;

    // prologue: stage K-steps 0 and 1 (8 gll16/wave each)
    stage_tile<128>(Ab, K, As[0], wave, lane);
    stage_tile<128>(W,  K, Bs[0], wave, lane);
    stage_tile<128>(Ab + 64, K, As[1], wave, lane);
    stage_tile<128>(W  + 64, K, Bs[1], wave, lane);

    for (int t = 0; t < NST; ++t) {
        // wait tile t landed; tile t+1's 8 loads stay in flight
        if (t + 1 < NST) WAIT_VM8(); else WAIT_VM0();
        wg_barrier();
        const unsigned short* Ac = As[t & 1];
        const unsigned short* Bc = Bs[t & 1];
        bf16x8 af[4][2], bfr[4][2];
        #pragma unroll
        for (int mt = 0; mt < 4; ++mt)
            #pragma unroll
            for (int kh = 0; kh < 2; ++kh)
                af[mt][kh] = *(const bf16x8*)(Ac + (wm + mt*16 + l15)*64
                                              + (((kh*4 + quad) ^ (l15 & 7))*8));
        #pragma unroll
        for (int nt = 0; nt < 4; ++nt)
            #pragma unroll
            for (int kh = 0; kh < 2; ++kh)
                bfr[nt][kh] = *(const bf16x8*)(Bc + (wn + nt*16 + l15)*64
                                               + (((kh*4 + quad) ^ (l15 & 7))*8));
        __builtin_amdgcn_s_setprio(1);
        #pragma unroll
        for (int mt = 0; mt < 4; ++mt)
            #pragma unroll
            for (int nt = 0; nt < 4; ++nt) {
                acc[mt][nt] = MFMA(af[mt][0], bfr[nt][0], acc[mt][nt]);
                acc[mt][nt] = MFMA(af[mt][1], bfr[nt][1], acc[mt][nt]);
            }
        __builtin_amdgcn_s_setprio(0);
        // all waves done reading buf[t&1] before restaging into it
        WAIT_LGKM0();
        wg_barrier();
        if (t + 2 < NST) {
            stage_tile<128>(Ab + (t+2)*64, K, As[t & 1], wave, lane);
            stage_tile<128>(W  + (t+2)*64, K, Bs[t & 1], wave, lane);
        }
    }

    #pragma unroll
    for (int nt = 0; nt < 4; ++nt) {
        const int cl = wn + nt*16 + l15;
        const float bj = bp[cl];
        const int cg = bn + cl;
        #pragma unroll
        for (int mt = 0; mt < 4; ++mt)
            #pragma unroll
            for (int r = 0; r < 4; ++r) {
                const int row = bm + wm + mt*16 + quad*4 + r;
                const float v = acc[mt][nt][r] + bj;
                if (region == 0) {
                    qkb[(size_t)row * (2*DDE) + cg] = (bf16_t)(v * 0.180336880f);
                    const float z = v * 0.125f;
                    qab[(size_t)row * DDE + cg] = (bf16_t)((v > 0.f) ? 0.02f*z : z);
                } else if (region == 1) {
                    qkb[(size_t)row * (2*DDE) + cg] = (bf16_t)v;
                } else {
                    const int c2 = cg - 2048;
                    const float kc = 1.f/(1.f + __expf(-v*0.0025f)) - 0.5f;
                    if (((row + 1) & (TT - 1)) != 0)
                        kcs[(size_t)(row + 1) * DDE + c2] = (bf16_t)kc;
                    if ((row & (TT - 1)) == 0)
                        kcs[(size_t)row * DDE + c2] = (bf16_t)0.f;
                }
            }
    }
}

// ---------------------------------------------------------------------------
// proj GEMM, BK=64, counted-vmcnt dbuf pipeline + XCD swizzle (fp32 out):
// C = A W^T + 2*bias
// ---------------------------------------------------------------------------
__global__ __launch_bounds__(256) void gemm_proj(
    const bf16_t* __restrict__ A, const bf16_t* __restrict__ W,
    const float* __restrict__ bias, float* __restrict__ C,
    int M, int N, int K, float bmul)
{
    __shared__ __align__(16) unsigned short As[2][128 * 64];
    __shared__ __align__(16) unsigned short Bs[2][128 * 64];
    const int tid  = threadIdx.x;
    const int wave = tid >> 6, lane = tid & 63;
    const int l15  = lane & 15, quad = lane >> 4;
    // XCD swizzle (bijective: 256 = 8*32)
    const int lid = (int)blockIdx.y * 8 + (int)blockIdx.x;
    const int s   = (lid & 7) * 32 + (lid >> 3);
    const int bm = (s / 8) * 128, bn = (s % 8) * 128;
    const int wm = (wave & 1) * 64, wn = (wave >> 1) * 64;

    const bf16_t* Ab = A + (size_t)bm * K;
    const bf16_t* Wb = W + (size_t)bn * K;
    const int NST = K / 64;

    f32x4 acc[4][4];
    #pragma unroll
    for (int i = 0; i < 4; ++i)
        #pragma unroll
        for (int j = 0; j < 4; ++j) acc[i][j] = (f32x4)0.f;

    stage_tile<128>(Ab, K, As[0], wave, lane);
    stage_tile<128>(Wb, K, Bs[0], wave, lane);
    stage_tile<128>(Ab + 64, K, As[1], wave, lane);
    stage_tile<128>(Wb + 64, K, Bs[1], wave, lane);

    for (int t = 0; t < NST; ++t) {
        if (t + 1 < NST) WAIT_VM8(); else WAIT_VM0();
        wg_barrier();
        const unsigned short* Ac = As[t & 1];
        const unsigned short* Bc = Bs[t & 1];
        bf16x8 af[4][2], bfr[4][2];
        #pragma unroll
        for (int mt = 0; mt < 4; ++mt)
            #pragma unroll
            for (int kh = 0; kh < 2; ++kh)
                af[mt][kh] = *(const bf16x8*)(Ac + (wm + mt*16 + l15)*64
                                              + (((kh*4 + quad) ^ (l15 & 7))*8));
        #pragma unroll
        for (int nt = 0; nt < 4; ++nt)
            #pragma unroll
            for (int kh = 0; kh < 2; ++kh)
                bfr[nt][kh] = *(const bf16x8*)(Bc + (wn + nt*16 + l15)*64
                                               + (((kh*4 + quad) ^ (l15 & 7))*8));
        __builtin_amdgcn_s_setprio(1);
        #pragma unroll
        for (int mt = 0; mt < 4; ++mt)
            #pragma unroll
            for (int nt = 0; nt < 4; ++nt) {
                acc[mt][nt] = MFMA(af[mt][0], bfr[nt][0], acc[mt][nt]);
                acc[mt][nt] = MFMA(af[mt][1], bfr[nt][1], acc[mt][nt]);
            }
        __builtin_amdgcn_s_setprio(0);
        WAIT_LGKM0();
        wg_barrier();
        if (t + 2 < NST) {
            stage_tile<128>(Ab + (t+2)*64, K, As[t & 1], wave, lane);
            stage_tile<128>(Wb + (t+2)*64, K, Bs[t & 1], wave, lane);
        }
    }

    #pragma unroll
    for (int nt = 0; nt < 4; ++nt) {
        const int col = bn + wn + nt*16 + l15;
        const float bj = bias[col] * bmul;
        #pragma unroll
        for (int mt = 0; mt < 4; ++mt)
            #pragma unroll
            for (int r = 0; r < 4; ++r) {
                const int row = bm + wm + mt*16 + quad*4 + r;
                C[(size_t)row * N + col] = acc[mt][nt][r] + bj;
            }
    }
}

// work-balanced q-tile mapping: adjacent bx pairs and (b=0,b=1) pairs both
// sum to a constant number of kv-steps (34), so any dispatch->CU pattern
// (fill-first or round-robin) balances.
__device__ inline int qt_map(int bx, int b) {
    const int qh = bx >> 1;
    return (((bx ^ b) & 1) ? qh : 15 - qh);
}

// ---------------------------------------------------------------------------
// AR: fixed-max flash attention, one block owns one 128-row q-tile (no
// split-s, no atomics).  Counted-vmcnt dbuf K/V staging; swapped QK^T (S^T)
// + in-register P repack (cvt_pk + ds_bpermute).  Epilogue normalizes by the
// wave-local row sum (redistributed via ds_bpermute) and stores yarb (bf16).
// ---------------------------------------------------------------------------
__global__ __launch_bounds__(256) void attn_ar_mfma(
    const bf16_t* __restrict__ qkb, const bf16_t* __restrict__ vtg,
    bf16_t* __restrict__ yarb)
{
    const int h = blockIdx.y, b = blockIdx.z;
    const int qt = qt_map((int)blockIdx.x, b);
    const int tid = threadIdx.x, wave = tid >> 6, lane = tid & 63;
    const int l15 = lane & 15, quad = lane >> 4;
    const int q0 = qt * 128;
    const int bh = b * NHH + h;

    __shared__ __align__(16) unsigned short Qs[128 * 64];
    __shared__ __align__(16) unsigned short Ks[2][64 * 64];
    __shared__ __align__(16) unsigned short Vs[2][64 * 64];

    const int nit = 2*qt + 2;   // kv tiles 0 .. 2qt+1 (always >= 2)

    const bf16_t* kg = qkb + (size_t)(b*TT)*(2*DDE) + DDE + h*HDD;
    const bf16_t* vg = vtg + (size_t)(bh*64)*TT;

    // prologue: Q (4 loads/wave) + tiles 0,1 (4 loads/wave each)
    stage_tile<128>(qkb + (size_t)(b*TT + q0) * (2*DDE) + h*HDD, 2*DDE, Qs, wave, lane);
    stage_tile<64>(kg, 2*DDE, Ks[0], wave, lane);
    stage_tile<64>(vg, TT, Vs[0], wave, lane);
    stage_tile<64>(kg + (size_t)64*(2*DDE), 2*DDE, Ks[1], wave, lane);
    stage_tile<64>(vg + 64, TT, Vs[1], wave, lane);
    WAIT_VM4();            // Q + tile0 done, tile1 in flight
    wg_barrier();

    bf16x8 qf[2][2];
    #pragma unroll
    for (int mt = 0; mt < 2; ++mt)
        #pragma unroll
        for (int kc = 0; kc < 2; ++kc)
            qf[mt][kc] = *(const bf16x8*)(Qs + (wave*32 + mt*16 + l15)*64
                                          + ((kc*4 + quad) ^ (l15 & 7))*8);

    f32x4 o[2][4];
    float lrow[2];
    #pragma unroll
    for (int mt = 0; mt < 2; ++mt) {
        #pragma unroll
        for (int nt = 0; nt < 4; ++nt) o[mt][nt] = (f32x4)0.f;
        lrow[mt] = 0.f;
    }

    const int qw0 = q0 + wave * 32;
    // bpermute byte indices for cross-quad P repack
    const int idxA = ((((2*quad    ) & 3) << 4) + l15) << 2;
    const int idxB = ((((2*quad + 1) & 3) << 4) + l15) << 2;

    for (int it = 0; it < nit; ++it) {
        if (it > 0) {
            if (it + 1 < nit) WAIT_VM4(); else WAIT_VM0();
            wg_barrier();
        }
        const int s0 = it * 64;
        if (s0 <= qw0 + 31) {
            const unsigned short* Kc = Ks[it & 1];
            const unsigned short* Vc = Vs[it & 1];

            // swapped QK: sv holds S^T — key = nt*16+quad*4+r, query = l15
            f32x4 sv[2][4];
            __builtin_amdgcn_s_setprio(1);
            #pragma unroll
            for (int nt = 0; nt < 4; ++nt) {
                const unsigned short* kr = Kc + (nt*16 + l15)*64;
                bf16x8 kb0 = *(const bf16x8*)(kr + ((quad    ) ^ (l15 & 7))*8);
                bf16x8 kb1 = *(const bf16x8*)(kr + ((quad + 4) ^ (l15 & 7))*8);
                #pragma unroll
                for (int mt = 0; mt < 2; ++mt) {
                    f32x4 z = (f32x4)0.f;
                    z = MFMA(kb0, qf[mt][0], z);
                    z = MFMA(kb1, qf[mt][1], z);
                    sv[mt][nt] = z;
                }
            }
            __builtin_amdgcn_s_setprio(0);

            const bool domask = (s0 + 63 > qw0);
            bf16x8 pa[2][2];
            #pragma unroll
            for (int mt = 0; mt < 2; ++mt) {
                const int qg = qw0 + mt*16 + l15;
                unsigned int pk[4][2];
                float lr = 0.f;
                #pragma unroll
                for (int nt = 0; nt < 4; ++nt) {
                    float pv[4];
                    #pragma unroll
                    for (int r = 0; r < 4; ++r) {
                        float p = exp2f(sv[mt][nt][r]);
                        if (domask) {
                            const int sg = s0 + nt*16 + quad*4 + r;
                            if (sg > qg) p = 0.f;
                        }
                        lr += p;
                        pv[r] = p;
                    }
                    pk[nt][0] = cvtpk(pv[0], pv[1]);
                    pk[nt][1] = cvtpk(pv[2], pv[3]);
                }
                lrow[mt] += lr;
                // repack S^T (C-layout) -> PV A-fragment
                #pragma unroll
                for (int sc = 0; sc < 2; ++sc) {
                    union { unsigned int u[4]; bf16x8 v; } pu;
                    #pragma unroll
                    for (int jp = 0; jp < 4; ++jp) {
                        const int idx = (jp & 2) ? idxB : idxA;
                        const int lo = __builtin_amdgcn_ds_bpermute(idx, (int)pk[2*sc  ][jp & 1]);
                        const int hi = __builtin_amdgcn_ds_bpermute(idx, (int)pk[2*sc+1][jp & 1]);
                        pu.u[jp] = (quad & 2) ? (unsigned)hi : (unsigned)lo;
                    }
                    pa[mt][sc] = pu.v;
                }
            }

            __builtin_amdgcn_s_setprio(1);
            #pragma unroll
            for (int nt = 0; nt < 4; ++nt) {
                const unsigned short* vr = Vc + (nt*16 + l15)*64;
                bf16x8 vb0 = *(const bf16x8*)(vr + ((quad    ) ^ (l15 & 7))*8);
                bf16x8 vb1 = *(const bf16x8*)(vr + ((quad + 4) ^ (l15 & 7))*8);
                #pragma unroll
                for (int mt = 0; mt < 2; ++mt) {
                    o[mt][nt] = MFMA(pa[mt][0], vb0, o[mt][nt]);
                    o[mt][nt] = MFMA(pa[mt][1], vb1, o[mt][nt]);
                }
            }
            __builtin_amdgcn_s_setprio(0);
        }
        WAIT_LGKM0();
        wg_barrier();
        if (it + 2 < nit) {
            stage_tile<64>(kg + (size_t)(it+2)*64*(2*DDE), 2*DDE, Ks[it & 1], wave, lane);
            stage_tile<64>(vg + (it+2)*64, TT, Vs[it & 1], wave, lane);
        }
    }

    // epilogue: normalize and store bf16 (no atomics).
    // lrow reduce over quads -> every lane holds row-sum for query row l15.
    float lvv[2];
    #pragma unroll
    for (int mt = 0; mt < 2; ++mt) {
        float lv = lrow[mt];
        lv += __shfl_xor(lv, 16);
        lv += __shfl_xor(lv, 32);
        lvv[mt] = lv;
    }
    // o rows are C-layout (quad*4+r): fetch that row's sum from lane quad*4+r
    float inv[2][4];
    #pragma unroll
    for (int mt = 0; mt < 2; ++mt)
        #pragma unroll
        for (int r = 0; r < 4; ++r) {
            const int src = (quad*4 + r) << 2;
            const float sum = __int_as_float(
                __builtin_amdgcn_ds_bpermute(src, __float_as_int(lvv[mt])));
            inv[mt][r] = 1.f / sum;
        }
    #pragma unroll
    for (int mt = 0; mt < 2; ++mt)
        #pragma unroll
        for (int nt = 0; nt < 4; ++nt)
            #pragma unroll
            for (int r = 0; r < 4; ++r) {
                const int row = qw0 + mt*16 + quad*4 + r;
                const int col = h*HDD + nt*16 + l15;
                yarb[(size_t)(b*TT + row)*DDE + col] = (bf16_t)(o[mt][nt][r] * inv[mt][r]);
            }
}

// ---------------------------------------------------------------------------
// MA: linear causal attention, one block per q-tile (no split-s/atomics).
// Epilogue fuses combine: ysumb = bf16(yarb + o).
// ---------------------------------------------------------------------------
__global__ __launch_bounds__(256) void attn_ma_mfma(
    const bf16_t* __restrict__ qab, const bf16_t* __restrict__ kcs,
    const bf16_t* __restrict__ etg, const bf16_t* __restrict__ yarb,
    bf16_t* __restrict__ ysumb)
{
    const int h = blockIdx.y, b = blockIdx.z;
    const int qt = qt_map((int)blockIdx.x, b);
    const int tid = threadIdx.x, wave = tid >> 6, lane = tid & 63;
    const int l15 = lane & 15, quad = lane >> 4;
    const int q0 = qt * 128;
    const int bh = b * NHH + h;

    __shared__ __align__(16) unsigned short Qs[128 * 64];
    __shared__ __align__(16) unsigned short Ks[2][64 * 64];
    __shared__ __align__(16) unsigned short Es[2][64 * 64];
    __shared__ float Rl[128];

    const int nit = 2*qt + 2;

    const bf16_t* kg = kcs + (size_t)(b*TT)*DDE + h*HDD;
    const bf16_t* eg = etg + (size_t)(bh*64)*TT;

    stage_tile<128>(qab + (size_t)(b*TT + q0)*DDE + h*HDD, DDE, Qs, wave, lane);
    stage_tile<64>(kg, DDE, Ks[0], wave, lane);
    stage_tile<64>(eg, TT, Es[0], wave, lane);
    stage_tile<64>(kg + (size_t)64*DDE, DDE, Ks[1], wave, lane);
    stage_tile<64>(eg + 64, TT, Es[1], wave, lane);
    WAIT_VM4();
    wg_barrier();

    if (tid < 128) {
        float s = 0.f;
        #pragma unroll
        for (int c = 0; c < 8; ++c) {
            bf16x8 v = *(const bf16x8*)(Qs + tid*64 + c*8);
            #pragma unroll
            for (int u = 0; u < 8; ++u) s += (float)v[u];
        }
        Rl[tid] = s;
    }
    WAIT_LGKM0();
    wg_barrier();

    bf16x8 qf[2][2];
    float Rr[2];
    #pragma unroll
    for (int mt = 0; mt < 2; ++mt) {
        #pragma unroll
        for (int kc = 0; kc < 2; ++kc)
            qf[mt][kc] = *(const bf16x8*)(Qs + (wave*32 + mt*16 + l15)*64
                                          + ((kc*4 + quad) ^ (l15 & 7))*8);
        Rr[mt] = 0.5f * Rl[wave*32 + mt*16 + l15];
    }

    f32x4 o[2][4];
    #pragma unroll
    for (int mt = 0; mt < 2; ++mt)
        #pragma unroll
        for (int nt = 0; nt < 4; ++nt) o[mt][nt] = (f32x4)0.f;

    const int qw0 = q0 + wave * 32;
    const int idxA = ((((2*quad    ) & 3) << 4) + l15) << 2;
    const int idxB = ((((2*quad + 1) & 3) << 4) + l15) << 2;

    for (int it = 0; it < nit; ++it) {
        if (it > 0) {
            if (it + 1 < nit) WAIT_VM4(); else WAIT_VM0();
            wg_barrier();
        }
        const int s0 = it * 64;
        if (s0 <= qw0 + 31) {
            const unsigned short* Kc = Ks[it & 1];
            const unsigned short* Ec = Es[it & 1];

            f32x4 sv[2][4];
            __builtin_amdgcn_s_setprio(1);
            #pragma unroll
            for (int nt = 0; nt < 4; ++nt) {
                const unsigned short* kr = Kc + (nt*16 + l15)*64;
                bf16x8 kb0 = *(const bf16x8*)(kr + ((quad    ) ^ (l15 & 7))*8);
                bf16x8 kb1 = *(const bf16x8*)(kr + ((quad + 4) ^ (l15 & 7))*8);
                #pragma unroll
                for (int mt = 0; mt < 2; ++mt) {
                    f32x4 z = (f32x4)0.f;
                    z = MFMA(kb0, qf[mt][0], z);
                    z = MFMA(kb1, qf[mt][1], z);
                    sv[mt][nt] = z;
                }
            }
            __builtin_amdgcn_s_setprio(0);

            const bool domask = (s0 + 63 > qw0);
            const bool m0 = (it == 0);
            bf16x8 pa[2][2];
            #pragma unroll
            for (int mt = 0; mt < 2; ++mt) {
                const int qg = qw0 + mt*16 + l15;
                unsigned int pk[4][2];
                #pragma unroll
                for (int nt = 0; nt < 4; ++nt) {
                    float pv[4];
                    #pragma unroll
                    for (int r = 0; r < 4; ++r) {
                        const int sg = s0 + nt*16 + quad*4 + r;
                        float p = sv[mt][nt][r] + Rr[mt];
                        if (m0 && sg == 0) p = 0.f;
                        if (domask && sg > qg) p = 0.f;
                        pv[r] = p;
                    }
                    pk[nt][0] = cvtpk(pv[0], pv[1]);
                    pk[nt][1] = cvtpk(pv[2], pv[3]);
                }
                #pragma unroll
                for (int sc = 0; sc < 2; ++sc) {
                    union { unsigned int u[4]; bf16x8 v; } pu;
                    #pragma unroll
                    for (int jp = 0; jp < 4; ++jp) {
                        const int idx = (jp & 2) ? idxB : idxA;
                        const int lo = __builtin_amdgcn_ds_bpermute(idx, (int)pk[2*sc  ][jp & 1]);
                        const int hi = __builtin_amdgcn_ds_bpermute(idx, (int)pk[2*sc+1][jp & 1]);
                        pu.u[jp] = (quad & 2) ? (unsigned)hi : (unsigned)lo;
                    }
                    pa[mt][sc] = pu.v;
                }
            }

            __builtin_amdgcn_s_setprio(1);
            #pragma unroll
            for (int nt = 0; nt < 4; ++nt) {
                const unsigned short* er = Ec + (nt*16 + l15)*64;
                bf16x8 eb0 = *(const bf16x8*)(er + ((quad    ) ^ (l15 & 7))*8);
                bf16x8 eb1 = *(const bf16x8*)(er + ((quad + 4) ^ (l15 & 7))*8);
                #pragma unroll
                for (int mt = 0; mt < 2; ++mt) {
                    o[mt][nt] = MFMA(pa[mt][0], eb0, o[mt][nt]);
                    o[mt][nt] = MFMA(pa[mt][1], eb1, o[mt][nt]);
                }
            }
            __builtin_amdgcn_s_setprio(0);
        }
        WAIT_LGKM0();
        wg_barrier();
        if (it + 2 < nit) {
            stage_tile<64>(kg + (size_t)(it+2)*64*DDE, DDE, Ks[it & 1], wave, lane);
            stage_tile<64>(eg + (it+2)*64, TT, Es[it & 1], wave, lane);
        }
    }

    // epilogue: ysumb = bf16(yarb + o)  (each (row,col) owned exactly once)
    #pragma unroll
    for (int mt = 0; mt < 2; ++mt)
        #pragma unroll
        for (int nt = 0; nt < 4; ++nt)
            #pragma unroll
            for (int r = 0; r < 4; ++r) {
                const int row = qw0 + mt*16 + quad*4 + r;
                const int col = h*HDD + nt*16 + l15;
                const size_t e = (size_t)(b*TT + row)*DDE + col;
                ysumb[e] = (bf16_t)((float)yarb[e] + o[mt][nt][r]);
            }
}

// ---------------------------------------------------------------------------
extern "C" void kernel_launch(void* const* d_in, const int* in_sizes, int n_in,
                              void* d_out, int out_size, void* d_ws, size_t ws_size,
                              hipStream_t stream)
{
    const float* x      = (const float*)d_in[0];
    const float* w_attn = (const float*)d_in[1];
    const float* b_attn = (const float*)d_in[2];
    const float* w_k2   = (const float*)d_in[3];
    const float* b_k2   = (const float*)d_in[4];
    const float* w_proj = (const float*)d_in[5];
    const float* b_proj = (const float*)d_in[6];

    const size_t NX  = (size_t)BB*TT*DDE;
    const size_t NWA = (size_t)2*DDE*DDE;
    const size_t NW  = (size_t)DDE*DDE;
    const size_t NQK = (size_t)BB*TT*2*DDE;

    bf16_t* xb   = (bf16_t*)d_ws;
    bf16_t* wab  = xb   + NX;
    bf16_t* wkb  = wab  + NWA;
    bf16_t* wpb  = wkb  + NW;
    bf16_t* qkb  = wpb  + NW;
    bf16_t* qab  = qkb  + NQK;
    bf16_t* kcs  = qab  + NX;
    bf16_t* vtg  = kcs  + NX;          // aliased by etg after attn_ar
    bf16_t* ysumb= vtg  + NX;          // old yo region
    bf16_t* yarb = (bf16_t*)((float*)(vtg + NX) + NX);  // unchanged address
    bf16_t* etg  = vtg;

    const size_t NCVT = NX + NWA + NW + NW;
    cvt_all<<<NCVT / 1024, 256, 0, stream>>>(x, w_attn, w_k2, w_proj, xb);

    transpose_head<<<dim3(TT/64, NHH, BB), 256, 0, stream>>>(xb, vtg);

    const int M = BB * TT;
    gemm_qkk2<<<dim3(24, M/128), 256, 0, stream>>>(xb, wab, wkb, b_attn, b_k2,
                                                    qkb, qab, kcs);

    attn_ar_mfma<<<dim3(16, NHH, BB), 256, 0, stream>>>(qkb, vtg, yarb);
    build_etg<<<dim3(TT/64, NHH, BB), 256, 0, stream>>>(yarb, xb, etg);
    attn_ma_mfma<<<dim3(16, NHH, BB), 256, 0, stream>>>(qab, kcs, etg, yarb, ysumb);

    gemm_proj<<<dim3(DDE/128, M/128), 256, 0, stream>>>(ysumb, wpb, b_proj,
                                                        (float*)d_out, M, DDE, DDE, 2.f);
}

// Round 5
// 266.375 us; speedup vs baseline: 1.1421x; 1.0971x over previous
//
#include <hip/hip_runtime.h>
#include <hip/hip_bf16.h>
#include <math.h>

#define BB  2
#define TT  2048
#define DDE 1024
#define NHH 16
#define HDD 64

typedef __bf16 bf16_t;
typedef __attribute__((ext_vector_type(8))) __bf16 bf16x8;
typedef __attribute__((ext_vector_type(4))) __bf16 bf16x4;
typedef __attribute__((ext_vector_type(4))) float  f32x4;

#define MFMA(a, b, c) __builtin_amdgcn_mfma_f32_16x16x32_bf16((a), (b), (c), 0, 0, 0)

// counted waits: loads for the NEXT tile stay in flight across barriers (T4)
#define WAIT_VM8()   asm volatile("s_waitcnt vmcnt(8)" ::: "memory")
#define WAIT_VM4()   asm volatile("s_waitcnt vmcnt(4)" ::: "memory")
#define WAIT_VM0()   asm volatile("s_waitcnt vmcnt(0)" ::: "memory")
#define WAIT_LGKM0() asm volatile("s_waitcnt lgkmcnt(0)" ::: "memory")

// raw workgroup barrier (no vmcnt drain), fenced against compiler reordering
__device__ inline void wg_barrier() {
    __builtin_amdgcn_sched_barrier(0);
    __builtin_amdgcn_s_barrier();
    __builtin_amdgcn_sched_barrier(0);
}

// pack 2 f32 -> 1 u32 of 2 bf16 (RNE), no builtin on gfx950
__device__ inline unsigned int cvtpk(float a, float b) {
    unsigned int r;
    asm("v_cvt_pk_bf16_f32 %0, %1, %2" : "=v"(r) : "v"(a), "v"(b));
    return r;
}

__device__ inline void gll16(const bf16_t* g, unsigned short* l) {
    __builtin_amdgcn_global_load_lds(
        (const __attribute__((address_space(1))) void*)g,
        (__attribute__((address_space(3))) void*)l, 16, 0, 0);
}

// Stage [ROWS x 64] bf16 tile (row stride gstride elems) into LDS via
// global_load_lds, chunk-swizzled: LDS elem [r][ (c ^ (r&7))*8 + j ].
// Per-wave gll16 count: ROWS/32  (128 -> 4, 64 -> 2).
template<int ROWS>
__device__ inline void stage_tile(const bf16_t* g0, size_t gstride,
                                  unsigned short* lds, int wave, int lane)
{
    const int r8 = lane >> 3;
    const int ck = (lane & 7) ^ r8;
    constexpr int RW = ROWS / 4;
    const bf16_t* g = g0 + (size_t)(wave * RW + r8) * gstride + ck * 8;
    unsigned short* l = lds + wave * RW * 64 + lane * 8;
    #pragma unroll
    for (int i = 0; i < RW / 8; ++i)
        gll16(g + (size_t)(i * 8) * gstride, l + i * 512);
}

// ---------------------------------------------------------------------------
// fused fp32->bf16 conversion of x, w_attn, w_k2, w_proj into the contiguous
// ws region starting at xb.  Segment boundaries are multiples of 1024 elems.
// ---------------------------------------------------------------------------
__global__ __launch_bounds__(256) void cvt_all(
    const float* __restrict__ x, const float* __restrict__ wa,
    const float* __restrict__ wk, const float* __restrict__ wp,
    bf16_t* __restrict__ out)
{
    const size_t NX  = (size_t)BB*TT*DDE;
    const size_t NWA = (size_t)2*DDE*DDE;
    const size_t NW  = (size_t)DDE*DDE;
    const size_t e = ((size_t)blockIdx.x * 256 + threadIdx.x) * 4;
    const float* src;
    if (e < NX)                 src = x  + e;
    else if (e < NX + NWA)      src = wa + (e - NX);
    else if (e < NX + NWA + NW) src = wk + (e - NX - NWA);
    else                        src = wp + (e - NX - NWA - NW);
    float4 v = *(const float4*)src;
    bf16x4 o;
    o[0] = (bf16_t)v.x; o[1] = (bf16_t)v.y;
    o[2] = (bf16_t)v.z; o[3] = (bf16_t)v.w;
    *(bf16x4*)(out + e) = o;
}

// ---------------------------------------------------------------------------
// Per-head 64x64 transpose: dst[bh][d][t] = src[b][t][h*64+d].
// ---------------------------------------------------------------------------
__global__ __launch_bounds__(256) void transpose_head(
    const bf16_t* __restrict__ src, bf16_t* __restrict__ dst)
{
    const int t0 = blockIdx.x * 64, h = blockIdx.y, b = blockIdx.z;
    const int tid = threadIdx.x;
    __shared__ __align__(16) bf16_t tile[64 * 64];

    #pragma unroll
    for (int it = 0; it < 2; ++it) {
        const int t = it * 32 + (tid >> 3);
        const int cw = tid & 7;
        const int slot = (cw + (t >> 3)) & 7;
        bf16x8 v = *(const bf16x8*)(src + (size_t)(b*TT + t0 + t)*DDE + h*HDD + cw*8);
        *(bf16x8*)(tile + t*64 + slot*8) = v;
    }
    __syncthreads();
    const int bh = b * NHH + h;
    #pragma unroll
    for (int it = 0; it < 2; ++it) {
        const int d = it * 32 + (tid >> 3);
        const int co = tid & 7;
        const int slot = ((d >> 3) + co) & 7;
        bf16x8 o;
        #pragma unroll
        for (int j = 0; j < 8; ++j)
            o[j] = tile[(co*8 + j)*64 + slot*8 + (d & 7)];
        *(bf16x8*)(dst + (size_t)(bh*64 + d)*TT + t0 + co*8) = o;
    }
}

// ---------------------------------------------------------------------------
// E-transpose: etg[bh][d][t] = x[t][d] - n[t-1][d]  (0 at t==0),
// where n = yarb (normalized AR output, written by attn_ar).
// ---------------------------------------------------------------------------
__global__ __launch_bounds__(256) void build_etg(
    const bf16_t* __restrict__ yarb, const bf16_t* __restrict__ xb,
    bf16_t* __restrict__ etg)
{
    const int t0 = blockIdx.x * 64, h = blockIdx.y, b = blockIdx.z;
    const int tid = threadIdx.x;
    const int bh = b * NHH + h;
    __shared__ __align__(16) bf16_t tile[64 * 64];

    #pragma unroll
    for (int it = 0; it < 2; ++it) {
        const int t = it * 32 + (tid >> 3);
        const int cw = tid & 7;
        const int slot = (cw + (t >> 3)) & 7;
        const int tg = t0 + t;
        bf16x8 ev;
        if (tg == 0) {
            #pragma unroll
            for (int u = 0; u < 8; ++u) ev[u] = (bf16_t)0.f;
        } else {
            bf16x8 xv = *(const bf16x8*)(xb   + (size_t)(b*TT + tg)*DDE + h*HDD + cw*8);
            bf16x8 nv = *(const bf16x8*)(yarb + (size_t)(b*TT + tg - 1)*DDE + h*HDD + cw*8);
            #pragma unroll
            for (int u = 0; u < 8; ++u)
                ev[u] = (bf16_t)((float)xv[u] - (float)nv[u]);
        }
        *(bf16x8*)(tile + t*64 + slot*8) = ev;
    }
    __syncthreads();
    #pragma unroll
    for (int it = 0; it < 2; ++it) {
        const int d = it * 32 + (tid >> 3);
        const int co = tid & 7;
        const int slot = ((d >> 3) + co) & 7;
        bf16x8 o;
        #pragma unroll
        for (int j = 0; j < 8; ++j)
            o[j] = tile[(co*8 + j)*64 + slot*8 + (d & 7)];
        *(bf16x8*)(etg + (size_t)(bh*64 + d)*TT + t0 + co*8) = o;
    }
}

// ---------------------------------------------------------------------------
// Fused QKV GEMM, BK=64, counted-vmcnt dbuf pipeline + XCD-aware swizzle.
// Region by column tile:
//   [0,1024):  q -> qkb = q*0.125*log2(e) (exp2 domain), qab = leaky(q*0.125)
//   [1024,2048): k -> qkb raw
//   [2048,3072): k2 -> kcs[t+1] = sigmoid(k2*0.0025)-0.5 (shifted, row0=0)
// ---------------------------------------------------------------------------
__global__ __launch_bounds__(256) void gemm_qkk2(
    const bf16_t* __restrict__ A, const bf16_t* __restrict__ wab,
    const bf16_t* __restrict__ wkb, const float* __restrict__ b_attn,
    const float* __restrict__ b_k2, bf16_t* __restrict__ qkb,
    bf16_t* __restrict__ qab, bf16_t* __restrict__ kcs)
{
    __shared__ __align__(16) unsigned short As[2][128 * 64];
    __shared__ __align__(16) unsigned short Bs[2][128 * 64];
    const int tid  = threadIdx.x;
    const int wave = tid >> 6, lane = tid & 63;
    const int l15  = lane & 15, quad = lane >> 4;
    // XCD swizzle (bijective: 768 = 8*96)
    const int lid = (int)blockIdx.y * 24 + (int)blockIdx.x;
    const int s   = (lid & 7) * 96 + (lid >> 3);
    const int bm = (s / 24) * 128, bn = (s % 24) * 128;
    const int wm = (wave & 1) * 64, wn = (wave >> 1) * 64;
    const int region = bn >> 10;
    const int K = DDE;
    constexpr int NST = DDE / 64;   // 16 K-steps

    const bf16_t* W = (region < 2) ? wab + (size_t)bn * K
                                   : wkb + (size_t)(bn - 2048) * K;
    const float* bp = (region < 2) ? b_attn + bn : b_k2 + (bn - 2048);
    const bf16_t* Ab = A + (size_t)bm * K;

    f32x4 acc[4][4];
    #pragma unroll
    for (int i = 0; i < 4; ++i)
        #pragma unroll
        for (int j = 0; j < 4; ++j) acc[i][j] = (f32x4)0.f;

    // prologue: stage K-steps 0 and 1 (8 gll16/wave each)
    stage_tile<128>(Ab, K, As[0], wave, lane);
    stage_tile<128>(W,  K, Bs[0], wave, lane);
    stage_tile<128>(Ab + 64, K, As[1], wave, lane);
    stage_tile<128>(W  + 64, K, Bs[1], wave, lane);

    for (int t = 0; t < NST; ++t) {
        // wait tile t landed; tile t+1's 8 loads stay in flight
        if (t + 1 < NST) WAIT_VM8(); else WAIT_VM0();
        wg_barrier();
        const unsigned short* Ac = As[t & 1];
        const unsigned short* Bc = Bs[t & 1];
        bf16x8 af[4][2], bfr[4][2];
        #pragma unroll
        for (int mt = 0; mt < 4; ++mt)
            #pragma unroll
            for (int kh = 0; kh < 2; ++kh)
                af[mt][kh] = *(const bf16x8*)(Ac + (wm + mt*16 + l15)*64
                                              + (((kh*4 + quad) ^ (l15 & 7))*8));
        #pragma unroll
        for (int nt = 0; nt < 4; ++nt)
            #pragma unroll
            for (int kh = 0; kh < 2; ++kh)
                bfr[nt][kh] = *(const bf16x8*)(Bc + (wn + nt*16 + l15)*64
                                               + (((kh*4 + quad) ^ (l15 & 7))*8));
        __builtin_amdgcn_s_setprio(1);
        #pragma unroll
        for (int mt = 0; mt < 4; ++mt)
            #pragma unroll
            for (int nt = 0; nt < 4; ++nt) {
                acc[mt][nt] = MFMA(af[mt][0], bfr[nt][0], acc[mt][nt]);
                acc[mt][nt] = MFMA(af[mt][1], bfr[nt][1], acc[mt][nt]);
            }
        __builtin_amdgcn_s_setprio(0);
        // all waves done reading buf[t&1] before restaging into it
        WAIT_LGKM0();
        wg_barrier();
        if (t + 2 < NST) {
            stage_tile<128>(Ab + (t+2)*64, K, As[t & 1], wave, lane);
            stage_tile<128>(W  + (t+2)*64, K, Bs[t & 1], wave, lane);
        }
    }

    #pragma unroll
    for (int nt = 0; nt < 4; ++nt) {
        const int cl = wn + nt*16 + l15;
        const float bj = bp[cl];
        const int cg = bn + cl;
        #pragma unroll
        for (int mt = 0; mt < 4; ++mt)
            #pragma unroll
            for (int r = 0; r < 4; ++r) {
                const int row = bm + wm + mt*16 + quad*4 + r;
                const float v = acc[mt][nt][r] + bj;
                if (region == 0) {
                    qkb[(size_t)row * (2*DDE) + cg] = (bf16_t)(v * 0.180336880f);
                    const float z = v * 0.125f;
                    qab[(size_t)row * DDE + cg] = (bf16_t)((v > 0.f) ? 0.02f*z : z);
                } else if (region == 1) {
                    qkb[(size_t)row * (2*DDE) + cg] = (bf16_t)v;
                } else {
                    const int c2 = cg - 2048;
                    const float kc = 1.f/(1.f + __expf(-v*0.0025f)) - 0.5f;
                    if (((row + 1) & (TT - 1)) != 0)
                        kcs[(size_t)(row + 1) * DDE + c2] = (bf16_t)kc;
                    if ((row & (TT - 1)) == 0)
                        kcs[(size_t)row * DDE + c2] = (bf16_t)0.f;
                }
            }
    }
}

// ---------------------------------------------------------------------------
// proj GEMM, BK=64, counted-vmcnt dbuf pipeline + XCD swizzle (fp32 out):
// C = A W^T + 2*bias
// ---------------------------------------------------------------------------
__global__ __launch_bounds__(256) void gemm_proj(
    const bf16_t* __restrict__ A, const bf16_t* __restrict__ W,
    const float* __restrict__ bias, float* __restrict__ C,
    int M, int N, int K, float bmul)
{
    __shared__ __align__(16) unsigned short As[2][128 * 64];
    __shared__ __align__(16) unsigned short Bs[2][128 * 64];
    const int tid  = threadIdx.x;
    const int wave = tid >> 6, lane = tid & 63;
    const int l15  = lane & 15, quad = lane >> 4;
    // XCD swizzle (bijective: 256 = 8*32)
    const int lid = (int)blockIdx.y * 8 + (int)blockIdx.x;
    const int s   = (lid & 7) * 32 + (lid >> 3);
    const int bm = (s / 8) * 128, bn = (s % 8) * 128;
    const int wm = (wave & 1) * 64, wn = (wave >> 1) * 64;

    const bf16_t* Ab = A + (size_t)bm * K;
    const bf16_t* Wb = W + (size_t)bn * K;
    const int NST = K / 64;

    f32x4 acc[4][4];
    #pragma unroll
    for (int i = 0; i < 4; ++i)
        #pragma unroll
        for (int j = 0; j < 4; ++j) acc[i][j] = (f32x4)0.f;

    stage_tile<128>(Ab, K, As[0], wave, lane);
    stage_tile<128>(Wb, K, Bs[0], wave, lane);
    stage_tile<128>(Ab + 64, K, As[1], wave, lane);
    stage_tile<128>(Wb + 64, K, Bs[1], wave, lane);

    for (int t = 0; t < NST; ++t) {
        if (t + 1 < NST) WAIT_VM8(); else WAIT_VM0();
        wg_barrier();
        const unsigned short* Ac = As[t & 1];
        const unsigned short* Bc = Bs[t & 1];
        bf16x8 af[4][2], bfr[4][2];
        #pragma unroll
        for (int mt = 0; mt < 4; ++mt)
            #pragma unroll
            for (int kh = 0; kh < 2; ++kh)
                af[mt][kh] = *(const bf16x8*)(Ac + (wm + mt*16 + l15)*64
                                              + (((kh*4 + quad) ^ (l15 & 7))*8));
        #pragma unroll
        for (int nt = 0; nt < 4; ++nt)
            #pragma unroll
            for (int kh = 0; kh < 2; ++kh)
                bfr[nt][kh] = *(const bf16x8*)(Bc + (wn + nt*16 + l15)*64
                                               + (((kh*4 + quad) ^ (l15 & 7))*8));
        __builtin_amdgcn_s_setprio(1);
        #pragma unroll
        for (int mt = 0; mt < 4; ++mt)
            #pragma unroll
            for (int nt = 0; nt < 4; ++nt) {
                acc[mt][nt] = MFMA(af[mt][0], bfr[nt][0], acc[mt][nt]);
                acc[mt][nt] = MFMA(af[mt][1], bfr[nt][1], acc[mt][nt]);
            }
        __builtin_amdgcn_s_setprio(0);
        WAIT_LGKM0();
        wg_barrier();
        if (t + 2 < NST) {
            stage_tile<128>(Ab + (t+2)*64, K, As[t & 1], wave, lane);
            stage_tile<128>(Wb + (t+2)*64, K, Bs[t & 1], wave, lane);
        }
    }

    #pragma unroll
    for (int nt = 0; nt < 4; ++nt) {
        const int col = bn + wn + nt*16 + l15;
        const float bj = bias[col] * bmul;
        #pragma unroll
        for (int mt = 0; mt < 4; ++mt)
            #pragma unroll
            for (int r = 0; r < 4; ++r) {
                const int row = bm + wm + mt*16 + quad*4 + r;
                C[(size_t)row * N + col] = acc[mt][nt][r] + bj;
            }
    }
}

// co-residency-balanced q-tile map over 32 tiles.  Blocks sharing a CU are
// {id, id+256, id+512, id+768} = same bx with (h>=8, b) varying; u selects
// one of 4 XOR-bijections so each CU's 4 blocks total exactly 66 kv-steps.
__device__ inline int qt_map32(int bx, int h, int b) {
    const int u = ((h >> 3) & 1) | (b << 1);
    int qt = (u & 1) ? (bx ^ 31) : bx;
    if (u & 2) qt ^= 16;
    return qt;
}

// ---------------------------------------------------------------------------
// AR: fixed-max flash attention.  One block owns one 64-row q-tile (no
// atomics); 1024 blocks = 4/CU (LDS exactly 40 KB).  Counted-vmcnt dbuf K/V;
// swapped QK^T (S^T) + in-register P repack (cvt_pk + ds_bpermute).
// Epilogue normalizes by the wave-local row sum and stores yarb (bf16).
// ---------------------------------------------------------------------------
__global__ __launch_bounds__(256) void attn_ar_mfma(
    const bf16_t* __restrict__ qkb, const bf16_t* __restrict__ vtg,
    bf16_t* __restrict__ yarb)
{
    const int h = blockIdx.y, b = blockIdx.z;
    const int qt = qt_map32((int)blockIdx.x, h, b);
    const int tid = threadIdx.x, wave = tid >> 6, lane = tid & 63;
    const int l15 = lane & 15, quad = lane >> 4;
    const int q0 = qt * 64;
    const int bh = b * NHH + h;

    __shared__ __align__(16) unsigned short Qs[64 * 64];
    __shared__ __align__(16) unsigned short Ks[2][64 * 64];
    __shared__ __align__(16) unsigned short Vs[2][64 * 64];

    const int nit = qt + 1;   // kv tiles 0 .. qt

    const bf16_t* kg = qkb + (size_t)(b*TT)*(2*DDE) + DDE + h*HDD;
    const bf16_t* vg = vtg + (size_t)(bh*64)*TT;

    // prologue: Q (2 loads/wave) + tiles 0[,1] (4 loads/wave each)
    stage_tile<64>(qkb + (size_t)(b*TT + q0) * (2*DDE) + h*HDD, 2*DDE, Qs, wave, lane);
    stage_tile<64>(kg, 2*DDE, Ks[0], wave, lane);
    stage_tile<64>(vg, TT, Vs[0], wave, lane);
    if (nit > 1) {
        stage_tile<64>(kg + (size_t)64*(2*DDE), 2*DDE, Ks[1], wave, lane);
        stage_tile<64>(vg + 64, TT, Vs[1], wave, lane);
        WAIT_VM4();            // Q + tile0 done, tile1 in flight
    } else {
        WAIT_VM0();
    }
    wg_barrier();

    bf16x8 qf[2];
    #pragma unroll
    for (int kc = 0; kc < 2; ++kc)
        qf[kc] = *(const bf16x8*)(Qs + (wave*16 + l15)*64
                                  + ((kc*4 + quad) ^ (l15 & 7))*8);

    f32x4 o[4];
    float lrow = 0.f;
    #pragma unroll
    for (int nt = 0; nt < 4; ++nt) o[nt] = (f32x4)0.f;

    const int qw0 = q0 + wave * 16;
    // bpermute byte indices for cross-quad P repack
    const int idxA = ((((2*quad    ) & 3) << 4) + l15) << 2;
    const int idxB = ((((2*quad + 1) & 3) << 4) + l15) << 2;

    for (int it = 0; it < nit; ++it) {
        if (it > 0) {
            if (it + 1 < nit) WAIT_VM4(); else WAIT_VM0();
            wg_barrier();
        }
        const int s0 = it * 64;
        const unsigned short* Kc = Ks[it & 1];
        const unsigned short* Vc = Vs[it & 1];

        // swapped QK: sv holds S^T — key = nt*16+quad*4+r, query = l15
        f32x4 sv[4];
        __builtin_amdgcn_s_setprio(1);
        #pragma unroll
        for (int nt = 0; nt < 4; ++nt) {
            const unsigned short* kr = Kc + (nt*16 + l15)*64;
            bf16x8 kb0 = *(const bf16x8*)(kr + ((quad    ) ^ (l15 & 7))*8);
            bf16x8 kb1 = *(const bf16x8*)(kr + ((quad + 4) ^ (l15 & 7))*8);
            f32x4 z = (f32x4)0.f;
            z = MFMA(kb0, qf[0], z);
            z = MFMA(kb1, qf[1], z);
            sv[nt] = z;
        }
        __builtin_amdgcn_s_setprio(0);

        const bool domask = (s0 + 63 > qw0);
        const int qg = qw0 + l15;
        unsigned int pk[4][2];
        #pragma unroll
        for (int nt = 0; nt < 4; ++nt) {
            float pv[4];
            #pragma unroll
            for (int r = 0; r < 4; ++r) {
                float p = exp2f(sv[nt][r]);
                if (domask) {
                    const int sg = s0 + nt*16 + quad*4 + r;
                    if (sg > qg) p = 0.f;
                }
                lrow += p;
                pv[r] = p;
            }
            pk[nt][0] = cvtpk(pv[0], pv[1]);
            pk[nt][1] = cvtpk(pv[2], pv[3]);
        }
        // repack S^T (C-layout) -> PV A-fragment
        bf16x8 pa[2];
        #pragma unroll
        for (int sc = 0; sc < 2; ++sc) {
            union { unsigned int u[4]; bf16x8 v; } pu;
            #pragma unroll
            for (int jp = 0; jp < 4; ++jp) {
                const int idx = (jp & 2) ? idxB : idxA;
                const int lo = __builtin_amdgcn_ds_bpermute(idx, (int)pk[2*sc  ][jp & 1]);
                const int hi = __builtin_amdgcn_ds_bpermute(idx, (int)pk[2*sc+1][jp & 1]);
                pu.u[jp] = (quad & 2) ? (unsigned)hi : (unsigned)lo;
            }
            pa[sc] = pu.v;
        }

        __builtin_amdgcn_s_setprio(1);
        #pragma unroll
        for (int nt = 0; nt < 4; ++nt) {
            const unsigned short* vr = Vc + (nt*16 + l15)*64;
            bf16x8 vb0 = *(const bf16x8*)(vr + ((quad    ) ^ (l15 & 7))*8);
            bf16x8 vb1 = *(const bf16x8*)(vr + ((quad + 4) ^ (l15 & 7))*8);
            o[nt] = MFMA(pa[0], vb0, o[nt]);
            o[nt] = MFMA(pa[1], vb1, o[nt]);
        }
        __builtin_amdgcn_s_setprio(0);

        WAIT_LGKM0();
        wg_barrier();
        if (it + 2 < nit) {
            stage_tile<64>(kg + (size_t)(it+2)*64*(2*DDE), 2*DDE, Ks[it & 1], wave, lane);
            stage_tile<64>(vg + (it+2)*64, TT, Vs[it & 1], wave, lane);
        }
    }

    // epilogue: normalize and store bf16 (no atomics).
    float lv = lrow;
    lv += __shfl_xor(lv, 16);
    lv += __shfl_xor(lv, 32);
    // o rows are C-layout (quad*4+r): fetch that row's sum from lane quad*4+r
    float inv[4];
    #pragma unroll
    for (int r = 0; r < 4; ++r) {
        const int src = (quad*4 + r) << 2;
        const float sum = __int_as_float(
            __builtin_amdgcn_ds_bpermute(src, __float_as_int(lv)));
        inv[r] = 1.f / sum;
    }
    #pragma unroll
    for (int nt = 0; nt < 4; ++nt)
        #pragma unroll
        for (int r = 0; r < 4; ++r) {
            const int row = qw0 + quad*4 + r;
            const int col = h*HDD + nt*16 + l15;
            yarb[(size_t)(b*TT + row)*DDE + col] = (bf16_t)(o[nt][r] * inv[r]);
        }
}

// ---------------------------------------------------------------------------
// MA: linear causal attention, one block per 64-row q-tile (no atomics).
// Q row-sum computed in-register from qf fragments (no LDS Rl).
// Epilogue fuses combine: ysumb = bf16(yarb + o).
// ---------------------------------------------------------------------------
__global__ __launch_bounds__(256) void attn_ma_mfma(
    const bf16_t* __restrict__ qab, const bf16_t* __restrict__ kcs,
    const bf16_t* __restrict__ etg, const bf16_t* __restrict__ yarb,
    bf16_t* __restrict__ ysumb)
{
    const int h = blockIdx.y, b = blockIdx.z;
    const int qt = qt_map32((int)blockIdx.x, h, b);
    const int tid = threadIdx.x, wave = tid >> 6, lane = tid & 63;
    const int l15 = lane & 15, quad = lane >> 4;
    const int q0 = qt * 64;
    const int bh = b * NHH + h;

    __shared__ __align__(16) unsigned short Qs[64 * 64];
    __shared__ __align__(16) unsigned short Ks[2][64 * 64];
    __shared__ __align__(16) unsigned short Es[2][64 * 64];

    const int nit = qt + 1;

    const bf16_t* kg = kcs + (size_t)(b*TT)*DDE + h*HDD;
    const bf16_t* eg = etg + (size_t)(bh*64)*TT;

    stage_tile<64>(qab + (size_t)(b*TT + q0)*DDE + h*HDD, DDE, Qs, wave, lane);
    stage_tile<64>(kg, DDE, Ks[0], wave, lane);
    stage_tile<64>(eg, TT, Es[0], wave, lane);
    if (nit > 1) {
        stage_tile<64>(kg + (size_t)64*DDE, DDE, Ks[1], wave, lane);
        stage_tile<64>(eg + 64, TT, Es[1], wave, lane);
        WAIT_VM4();
    } else {
        WAIT_VM0();
    }
    wg_barrier();

    bf16x8 qf[2];
    #pragma unroll
    for (int kc = 0; kc < 2; ++kc)
        qf[kc] = *(const bf16x8*)(Qs + (wave*16 + l15)*64
                                  + ((kc*4 + quad) ^ (l15 & 7))*8);

    // Q row-sum (64 cols) in-register: lane holds 16 elems; quad butterfly.
    float rs = 0.f;
    #pragma unroll
    for (int kc = 0; kc < 2; ++kc)
        #pragma unroll
        for (int u = 0; u < 8; ++u) rs += (float)qf[kc][u];
    rs += __shfl_xor(rs, 16);
    rs += __shfl_xor(rs, 32);
    const float Rr = 0.5f * rs;     // row-sum for query row l15 (all quads)

    f32x4 o[4];
    #pragma unroll
    for (int nt = 0; nt < 4; ++nt) o[nt] = (f32x4)0.f;

    const int qw0 = q0 + wave * 16;
    const int idxA = ((((2*quad    ) & 3) << 4) + l15) << 2;
    const int idxB = ((((2*quad + 1) & 3) << 4) + l15) << 2;

    for (int it = 0; it < nit; ++it) {
        if (it > 0) {
            if (it + 1 < nit) WAIT_VM4(); else WAIT_VM0();
            wg_barrier();
        }
        const int s0 = it * 64;
        const unsigned short* Kc = Ks[it & 1];
        const unsigned short* Ec = Es[it & 1];

        f32x4 sv[4];
        __builtin_amdgcn_s_setprio(1);
        #pragma unroll
        for (int nt = 0; nt < 4; ++nt) {
            const unsigned short* kr = Kc + (nt*16 + l15)*64;
            bf16x8 kb0 = *(const bf16x8*)(kr + ((quad    ) ^ (l15 & 7))*8);
            bf16x8 kb1 = *(const bf16x8*)(kr + ((quad + 4) ^ (l15 & 7))*8);
            f32x4 z = (f32x4)0.f;
            z = MFMA(kb0, qf[0], z);
            z = MFMA(kb1, qf[1], z);
            sv[nt] = z;
        }
        __builtin_amdgcn_s_setprio(0);

        const bool domask = (s0 + 63 > qw0);
        const bool m0 = (it == 0);
        const int qg = qw0 + l15;
        unsigned int pk[4][2];
        #pragma unroll
        for (int nt = 0; nt < 4; ++nt) {
            float pv[4];
            #pragma unroll
            for (int r = 0; r < 4; ++r) {
                const int sg = s0 + nt*16 + quad*4 + r;
                float p = sv[nt][r] + Rr;
                if (m0 && sg == 0) p = 0.f;
                if (domask && sg > qg) p = 0.f;
                pv[r] = p;
            }
            pk[nt][0] = cvtpk(pv[0], pv[1]);
            pk[nt][1] = cvtpk(pv[2], pv[3]);
        }
        bf16x8 pa[2];
        #pragma unroll
        for (int sc = 0; sc < 2; ++sc) {
            union { unsigned int u[4]; bf16x8 v; } pu;
            #pragma unroll
            for (int jp = 0; jp < 4; ++jp) {
                const int idx = (jp & 2) ? idxB : idxA;
                const int lo = __builtin_amdgcn_ds_bpermute(idx, (int)pk[2*sc  ][jp & 1]);
                const int hi = __builtin_amdgcn_ds_bpermute(idx, (int)pk[2*sc+1][jp & 1]);
                pu.u[jp] = (quad & 2) ? (unsigned)hi : (unsigned)lo;
            }
            pa[sc] = pu.v;
        }

        __builtin_amdgcn_s_setprio(1);
        #pragma unroll
        for (int nt = 0; nt < 4; ++nt) {
            const unsigned short* er = Ec + (nt*16 + l15)*64;
            bf16x8 eb0 = *(const bf16x8*)(er + ((quad    ) ^ (l15 & 7))*8);
            bf16x8 eb1 = *(const bf16x8*)(er + ((quad + 4) ^ (l15 & 7))*8);
            o[nt] = MFMA(pa[0], eb0, o[nt]);
            o[nt] = MFMA(pa[1], eb1, o[nt]);
        }
        __builtin_amdgcn_s_setprio(0);

        WAIT_LGKM0();
        wg_barrier();
        if (it + 2 < nit) {
            stage_tile<64>(kg + (size_t)(it+2)*64*DDE, DDE, Ks[it & 1], wave, lane);
            stage_tile<64>(eg + (it+2)*64, TT, Es[it & 1], wave, lane);
        }
    }

    // epilogue: ysumb = bf16(yarb + o)  (each (row,col) owned exactly once)
    #pragma unroll
    for (int nt = 0; nt < 4; ++nt)
        #pragma unroll
        for (int r = 0; r < 4; ++r) {
            const int row = qw0 + quad*4 + r;
            const int col = h*HDD + nt*16 + l15;
            const size_t e = (size_t)(b*TT + row)*DDE + col;
            ysumb[e] = (bf16_t)((float)yarb[e] + o[nt][r]);
        }
}

// ---------------------------------------------------------------------------
extern "C" void kernel_launch(void* const* d_in, const int* in_sizes, int n_in,
                              void* d_out, int out_size, void* d_ws, size_t ws_size,
                              hipStream_t stream)
{
    const float* x      = (const float*)d_in[0];
    const float* w_attn = (const float*)d_in[1];
    const float* b_attn = (const float*)d_in[2];
    const float* w_k2   = (const float*)d_in[3];
    const float* b_k2   = (const float*)d_in[4];
    const float* w_proj = (const float*)d_in[5];
    const float* b_proj = (const float*)d_in[6];

    const size_t NX  = (size_t)BB*TT*DDE;
    const size_t NWA = (size_t)2*DDE*DDE;
    const size_t NW  = (size_t)DDE*DDE;
    const size_t NQK = (size_t)BB*TT*2*DDE;

    bf16_t* xb   = (bf16_t*)d_ws;
    bf16_t* wab  = xb   + NX;
    bf16_t* wkb  = wab  + NWA;
    bf16_t* wpb  = wkb  + NW;
    bf16_t* qkb  = wpb  + NW;
    bf16_t* qab  = qkb  + NQK;
    bf16_t* kcs  = qab  + NX;
    bf16_t* vtg  = kcs  + NX;          // aliased by etg after attn_ar
    bf16_t* ysumb= vtg  + NX;
    bf16_t* yarb = (bf16_t*)((float*)(vtg + NX) + NX);
    bf16_t* etg  = vtg;

    const size_t NCVT = NX + NWA + NW + NW;
    cvt_all<<<NCVT / 1024, 256, 0, stream>>>(x, w_attn, w_k2, w_proj, xb);

    transpose_head<<<dim3(TT/64, NHH, BB), 256, 0, stream>>>(xb, vtg);

    const int M = BB * TT;
    gemm_qkk2<<<dim3(24, M/128), 256, 0, stream>>>(xb, wab, wkb, b_attn, b_k2,
                                                    qkb, qab, kcs);

    attn_ar_mfma<<<dim3(32, NHH, BB), 256, 0, stream>>>(qkb, vtg, yarb);
    build_etg<<<dim3(TT/64, NHH, BB), 256, 0, stream>>>(yarb, xb, etg);
    attn_ma_mfma<<<dim3(32, NHH, BB), 256, 0, stream>>>(qab, kcs, etg, yarb, ysumb);

    gemm_proj<<<dim3(DDE/128, M/128), 256, 0, stream>>>(ysumb, wpb, b_proj,
                                                        (float*)d_out, M, DDE, DDE, 2.f);
}

// Round 6
// 255.360 us; speedup vs baseline: 1.1914x; 1.0431x over previous
//
#include <hip/hip_runtime.h>
#include <hip/hip_bf16.h>
#include <math.h>

#define BB  2
#define TT  2048
#define DDE 1024
#define NHH 16
#define HDD 64

typedef __bf16 bf16_t;
typedef __attribute__((ext_vector_type(8))) __bf16 bf16x8;
typedef __attribute__((ext_vector_type(4))) __bf16 bf16x4;
typedef __attribute__((ext_vector_type(4))) float  f32x4;

#define MFMA(a, b, c) __builtin_amdgcn_mfma_f32_16x16x32_bf16((a), (b), (c), 0, 0, 0)

// counted waits: loads for the NEXT tile stay in flight across barriers (T4)
#define WAIT_VM6()   asm volatile("s_waitcnt vmcnt(6)" ::: "memory")
#define WAIT_VM4()   asm volatile("s_waitcnt vmcnt(4)" ::: "memory")
#define WAIT_VM0()   asm volatile("s_waitcnt vmcnt(0)" ::: "memory")
#define WAIT_LGKM0() asm volatile("s_waitcnt lgkmcnt(0)" ::: "memory")

// raw workgroup barrier (no vmcnt drain), fenced against compiler reordering
__device__ inline void wg_barrier() {
    __builtin_amdgcn_sched_barrier(0);
    __builtin_amdgcn_s_barrier();
    __builtin_amdgcn_sched_barrier(0);
}

// pack 2 f32 -> 1 u32 of 2 bf16 (RNE), no builtin on gfx950
__device__ inline unsigned int cvtpk(float a, float b) {
    unsigned int r;
    asm("v_cvt_pk_bf16_f32 %0, %1, %2" : "=v"(r) : "v"(a), "v"(b));
    return r;
}

__device__ inline void gll16(const bf16_t* g, unsigned short* l) {
    __builtin_amdgcn_global_load_lds(
        (const __attribute__((address_space(1))) void*)g,
        (__attribute__((address_space(3))) void*)l, 16, 0, 0);
}

// Stage [ROWS x 64] bf16 tile (row stride gstride elems) into LDS via
// global_load_lds, chunk-swizzled: LDS elem [r][ (c ^ (r&7))*8 + j ].
// Per-wave gll16 count: ROWS/32  (128 -> 4, 64 -> 2).
template<int ROWS>
__device__ inline void stage_tile(const bf16_t* g0, size_t gstride,
                                  unsigned short* lds, int wave, int lane)
{
    const int r8 = lane >> 3;
    const int ck = (lane & 7) ^ r8;
    constexpr int RW = ROWS / 4;
    const bf16_t* g = g0 + (size_t)(wave * RW + r8) * gstride + ck * 8;
    unsigned short* l = lds + wave * RW * 64 + lane * 8;
    #pragma unroll
    for (int i = 0; i < RW / 8; ++i)
        gll16(g + (size_t)(i * 8) * gstride, l + i * 512);
}

// ---------------------------------------------------------------------------
// fused fp32->bf16 conversion of x, w_attn, w_k2, w_proj into the contiguous
// ws region starting at xb.  Segment boundaries are multiples of 1024 elems.
// ---------------------------------------------------------------------------
__global__ __launch_bounds__(256) void cvt_all(
    const float* __restrict__ x, const float* __restrict__ wa,
    const float* __restrict__ wk, const float* __restrict__ wp,
    bf16_t* __restrict__ out)
{
    const size_t NX  = (size_t)BB*TT*DDE;
    const size_t NWA = (size_t)2*DDE*DDE;
    const size_t NW  = (size_t)DDE*DDE;
    const size_t e = ((size_t)blockIdx.x * 256 + threadIdx.x) * 4;
    const float* src;
    if (e < NX)                 src = x  + e;
    else if (e < NX + NWA)      src = wa + (e - NX);
    else if (e < NX + NWA + NW) src = wk + (e - NX - NWA);
    else                        src = wp + (e - NX - NWA - NW);
    float4 v = *(const float4*)src;
    bf16x4 o;
    o[0] = (bf16_t)v.x; o[1] = (bf16_t)v.y;
    o[2] = (bf16_t)v.z; o[3] = (bf16_t)v.w;
    *(bf16x4*)(out + e) = o;
}

// ---------------------------------------------------------------------------
// Per-head 64x64 transpose: dst[bh][d][t] = src[b][t][h*64+d].
// ---------------------------------------------------------------------------
__global__ __launch_bounds__(256) void transpose_head(
    const bf16_t* __restrict__ src, bf16_t* __restrict__ dst)
{
    const int t0 = blockIdx.x * 64, h = blockIdx.y, b = blockIdx.z;
    const int tid = threadIdx.x;
    __shared__ __align__(16) bf16_t tile[64 * 64];

    #pragma unroll
    for (int it = 0; it < 2; ++it) {
        const int t = it * 32 + (tid >> 3);
        const int cw = tid & 7;
        const int slot = (cw + (t >> 3)) & 7;
        bf16x8 v = *(const bf16x8*)(src + (size_t)(b*TT + t0 + t)*DDE + h*HDD + cw*8);
        *(bf16x8*)(tile + t*64 + slot*8) = v;
    }
    __syncthreads();
    const int bh = b * NHH + h;
    #pragma unroll
    for (int it = 0; it < 2; ++it) {
        const int d = it * 32 + (tid >> 3);
        const int co = tid & 7;
        const int slot = ((d >> 3) + co) & 7;
        bf16x8 o;
        #pragma unroll
        for (int j = 0; j < 8; ++j)
            o[j] = tile[(co*8 + j)*64 + slot*8 + (d & 7)];
        *(bf16x8*)(dst + (size_t)(bh*64 + d)*TT + t0 + co*8) = o;
    }
}

// ---------------------------------------------------------------------------
// E-transpose: etg[bh][d][t] = x[t][d] - n[t-1][d]  (0 at t==0),
// where n = yarb (normalized AR output, written by attn_ar).
// ---------------------------------------------------------------------------
__global__ __launch_bounds__(256) void build_etg(
    const bf16_t* __restrict__ yarb, const bf16_t* __restrict__ xb,
    bf16_t* __restrict__ etg)
{
    const int t0 = blockIdx.x * 64, h = blockIdx.y, b = blockIdx.z;
    const int tid = threadIdx.x;
    const int bh = b * NHH + h;
    __shared__ __align__(16) bf16_t tile[64 * 64];

    #pragma unroll
    for (int it = 0; it < 2; ++it) {
        const int t = it * 32 + (tid >> 3);
        const int cw = tid & 7;
        const int slot = (cw + (t >> 3)) & 7;
        const int tg = t0 + t;
        bf16x8 ev;
        if (tg == 0) {
            #pragma unroll
            for (int u = 0; u < 8; ++u) ev[u] = (bf16_t)0.f;
        } else {
            bf16x8 xv = *(const bf16x8*)(xb   + (size_t)(b*TT + tg)*DDE + h*HDD + cw*8);
            bf16x8 nv = *(const bf16x8*)(yarb + (size_t)(b*TT + tg - 1)*DDE + h*HDD + cw*8);
            #pragma unroll
            for (int u = 0; u < 8; ++u)
                ev[u] = (bf16_t)((float)xv[u] - (float)nv[u]);
        }
        *(bf16x8*)(tile + t*64 + slot*8) = ev;
    }
    __syncthreads();
    #pragma unroll
    for (int it = 0; it < 2; ++it) {
        const int d = it * 32 + (tid >> 3);
        const int co = tid & 7;
        const int slot = ((d >> 3) + co) & 7;
        bf16x8 o;
        #pragma unroll
        for (int j = 0; j < 8; ++j)
            o[j] = tile[(co*8 + j)*64 + slot*8 + (d & 7)];
        *(bf16x8*)(etg + (size_t)(bh*64 + d)*TT + t0 + co*8) = o;
    }
}

// ---------------------------------------------------------------------------
// Fused QKV GEMM, BM=64 x BN=128, BK=64, counted-vmcnt dbuf pipeline.
// 1536 blocks (6/CU by grid, 3/CU by LDS=48KB) -> ~12 resident waves/CU so
// implicit wave-overlap hides per-step latency (the 768-block/64KB version
// plateaued at 390 TF regardless of schedule).  Region by column tile:
//   [0,1024):  q -> qkb = q*0.125*log2(e) (exp2 domain), qab = leaky(q*0.125)
//   [1024,2048): k -> qkb raw
//   [2048,3072): k2 -> kcs[t+1] = sigmoid(k2*0.0025)-0.5 (shifted, row0=0)
// ---------------------------------------------------------------------------
__global__ __launch_bounds__(256) void gemm_qkk2(
    const bf16_t* __restrict__ A, const bf16_t* __restrict__ wab,
    const bf16_t* __restrict__ wkb, const float* __restrict__ b_attn,
    const float* __restrict__ b_k2, bf16_t* __restrict__ qkb,
    bf16_t* __restrict__ qab, bf16_t* __restrict__ kcs)
{
    __shared__ __align__(16) unsigned short As[2][64 * 64];
    __shared__ __align__(16) unsigned short Bs[2][128 * 64];
    const int tid  = threadIdx.x;
    const int wave = tid >> 6, lane = tid & 63;
    const int l15  = lane & 15, quad = lane >> 4;
    // XCD swizzle (bijective: 1536 = 8*192): each XCD owns 8 contiguous
    // m-rows x all 24 n-tiles; per-k-step slab (A 64KB + B 384KB) L2-fits.
    const int lid = (int)blockIdx.y * 24 + (int)blockIdx.x;
    const int s   = (lid & 7) * 192 + (lid >> 3);
    const int bm = (s / 24) * 64, bn = (s % 24) * 128;
    const int wm = (wave & 1) * 32, wn = (wave >> 1) * 64;
    const int region = bn >> 10;
    const int K = DDE;
    constexpr int NST = DDE / 64;   // 16 K-steps

    const bf16_t* W = (region < 2) ? wab + (size_t)bn * K
                                   : wkb + (size_t)(bn - 2048) * K;
    const float* bp = (region < 2) ? b_attn + bn : b_k2 + (bn - 2048);
    const bf16_t* Ab = A + (size_t)bm * K;

    f32x4 acc[2][4];
    #pragma unroll
    for (int i = 0; i < 2; ++i)
        #pragma unroll
        for (int j = 0; j < 4; ++j) acc[i][j] = (f32x4)0.f;

    // prologue: stage K-steps 0 and 1 (6 gll16/wave each: 2 A + 4 B)
    stage_tile<64>(Ab, K, As[0], wave, lane);
    stage_tile<128>(W,  K, Bs[0], wave, lane);
    stage_tile<64>(Ab + 64, K, As[1], wave, lane);
    stage_tile<128>(W  + 64, K, Bs[1], wave, lane);

    for (int t = 0; t < NST; ++t) {
        // wait tile t landed; tile t+1's 6 loads stay in flight
        if (t + 1 < NST) WAIT_VM6(); else WAIT_VM0();
        wg_barrier();
        const unsigned short* Ac = As[t & 1];
        const unsigned short* Bc = Bs[t & 1];
        bf16x8 af[2][2], bfr[4][2];
        #pragma unroll
        for (int mt = 0; mt < 2; ++mt)
            #pragma unroll
            for (int kh = 0; kh < 2; ++kh)
                af[mt][kh] = *(const bf16x8*)(Ac + (wm + mt*16 + l15)*64
                                              + (((kh*4 + quad) ^ (l15 & 7))*8));
        #pragma unroll
        for (int nt = 0; nt < 4; ++nt)
            #pragma unroll
            for (int kh = 0; kh < 2; ++kh)
                bfr[nt][kh] = *(const bf16x8*)(Bc + (wn + nt*16 + l15)*64
                                               + (((kh*4 + quad) ^ (l15 & 7))*8));
        __builtin_amdgcn_s_setprio(1);
        #pragma unroll
        for (int mt = 0; mt < 2; ++mt)
            #pragma unroll
            for (int nt = 0; nt < 4; ++nt) {
                acc[mt][nt] = MFMA(af[mt][0], bfr[nt][0], acc[mt][nt]);
                acc[mt][nt] = MFMA(af[mt][1], bfr[nt][1], acc[mt][nt]);
            }
        __builtin_amdgcn_s_setprio(0);
        // all waves done reading buf[t&1] before restaging into it
        WAIT_LGKM0();
        wg_barrier();
        if (t + 2 < NST) {
            stage_tile<64>(Ab + (t+2)*64, K, As[t & 1], wave, lane);
            stage_tile<128>(W  + (t+2)*64, K, Bs[t & 1], wave, lane);
        }
    }

    #pragma unroll
    for (int nt = 0; nt < 4; ++nt) {
        const int cl = wn + nt*16 + l15;
        const float bj = bp[cl];
        const int cg = bn + cl;
        #pragma unroll
        for (int mt = 0; mt < 2; ++mt)
            #pragma unroll
            for (int r = 0; r < 4; ++r) {
                const int row = bm + wm + mt*16 + quad*4 + r;
                const float v = acc[mt][nt][r] + bj;
                if (region == 0) {
                    qkb[(size_t)row * (2*DDE) + cg] = (bf16_t)(v * 0.180336880f);
                    const float z = v * 0.125f;
                    qab[(size_t)row * DDE + cg] = (bf16_t)((v > 0.f) ? 0.02f*z : z);
                } else if (region == 1) {
                    qkb[(size_t)row * (2*DDE) + cg] = (bf16_t)v;
                } else {
                    const int c2 = cg - 2048;
                    const float kc = 1.f/(1.f + __expf(-v*0.0025f)) - 0.5f;
                    if (((row + 1) & (TT - 1)) != 0)
                        kcs[(size_t)(row + 1) * DDE + c2] = (bf16_t)kc;
                    if ((row & (TT - 1)) == 0)
                        kcs[(size_t)row * DDE + c2] = (bf16_t)0.f;
                }
            }
    }
}

// ---------------------------------------------------------------------------
// proj GEMM, BM=64 x BN=64, BK=64, counted-vmcnt dbuf (fp32 out):
// C = A W^T + 2*bias.  1024 blocks (4/CU by grid, 5/CU by LDS=32KB).
// ---------------------------------------------------------------------------
__global__ __launch_bounds__(256) void gemm_proj(
    const bf16_t* __restrict__ A, const bf16_t* __restrict__ W,
    const float* __restrict__ bias, float* __restrict__ C,
    int M, int N, int K, float bmul)
{
    __shared__ __align__(16) unsigned short As[2][64 * 64];
    __shared__ __align__(16) unsigned short Bs[2][64 * 64];
    const int tid  = threadIdx.x;
    const int wave = tid >> 6, lane = tid & 63;
    const int l15  = lane & 15, quad = lane >> 4;
    // XCD swizzle (bijective: 1024 = 8*128)
    const int lid = (int)blockIdx.y * 16 + (int)blockIdx.x;
    const int s   = (lid & 7) * 128 + (lid >> 3);
    const int bm = (s / 16) * 64, bn = (s % 16) * 64;
    const int wm = (wave & 1) * 32, wn = (wave >> 1) * 32;

    const bf16_t* Ab = A + (size_t)bm * K;
    const bf16_t* Wb = W + (size_t)bn * K;
    const int NST = K / 64;

    f32x4 acc[2][2];
    #pragma unroll
    for (int i = 0; i < 2; ++i)
        #pragma unroll
        for (int j = 0; j < 2; ++j) acc[i][j] = (f32x4)0.f;

    stage_tile<64>(Ab, K, As[0], wave, lane);
    stage_tile<64>(Wb, K, Bs[0], wave, lane);
    stage_tile<64>(Ab + 64, K, As[1], wave, lane);
    stage_tile<64>(Wb + 64, K, Bs[1], wave, lane);

    for (int t = 0; t < NST; ++t) {
        if (t + 1 < NST) WAIT_VM4(); else WAIT_VM0();
        wg_barrier();
        const unsigned short* Ac = As[t & 1];
        const unsigned short* Bc = Bs[t & 1];
        bf16x8 af[2][2], bfr[2][2];
        #pragma unroll
        for (int mt = 0; mt < 2; ++mt)
            #pragma unroll
            for (int kh = 0; kh < 2; ++kh)
                af[mt][kh] = *(const bf16x8*)(Ac + (wm + mt*16 + l15)*64
                                              + (((kh*4 + quad) ^ (l15 & 7))*8));
        #pragma unroll
        for (int nt = 0; nt < 2; ++nt)
            #pragma unroll
            for (int kh = 0; kh < 2; ++kh)
                bfr[nt][kh] = *(const bf16x8*)(Bc + (wn + nt*16 + l15)*64
                                               + (((kh*4 + quad) ^ (l15 & 7))*8));
        __builtin_amdgcn_s_setprio(1);
        #pragma unroll
        for (int mt = 0; mt < 2; ++mt)
            #pragma unroll
            for (int nt = 0; nt < 2; ++nt) {
                acc[mt][nt] = MFMA(af[mt][0], bfr[nt][0], acc[mt][nt]);
                acc[mt][nt] = MFMA(af[mt][1], bfr[nt][1], acc[mt][nt]);
            }
        __builtin_amdgcn_s_setprio(0);
        WAIT_LGKM0();
        wg_barrier();
        if (t + 2 < NST) {
            stage_tile<64>(Ab + (t+2)*64, K, As[t & 1], wave, lane);
            stage_tile<64>(Wb + (t+2)*64, K, Bs[t & 1], wave, lane);
        }
    }

    #pragma unroll
    for (int nt = 0; nt < 2; ++nt) {
        const int col = bn + wn + nt*16 + l15;
        const float bj = bias[col] * bmul;
        #pragma unroll
        for (int mt = 0; mt < 2; ++mt)
            #pragma unroll
            for (int r = 0; r < 4; ++r) {
                const int row = bm + wm + mt*16 + quad*4 + r;
                C[(size_t)row * N + col] = acc[mt][nt][r] + bj;
            }
    }
}

// co-residency-balanced q-tile map over 32 tiles.  Blocks sharing a CU are
// {id, id+256, id+512, id+768} = same bx with (h>=8, b) varying; u selects
// one of 4 XOR-bijections so each CU's 4 blocks total exactly 66 kv-steps.
__device__ inline int qt_map32(int bx, int h, int b) {
    const int u = ((h >> 3) & 1) | (b << 1);
    int qt = (u & 1) ? (bx ^ 31) : bx;
    if (u & 2) qt ^= 16;
    return qt;
}

// ---------------------------------------------------------------------------
// AR: fixed-max flash attention.  One block owns one 64-row q-tile (no
// atomics); 1024 blocks = 4/CU (LDS exactly 40 KB).  Counted-vmcnt dbuf K/V;
// swapped QK^T (S^T) + in-register P repack (cvt_pk + ds_bpermute).
// Epilogue normalizes by the wave-local row sum and stores yarb (bf16).
// ---------------------------------------------------------------------------
__global__ __launch_bounds__(256) void attn_ar_mfma(
    const bf16_t* __restrict__ qkb, const bf16_t* __restrict__ vtg,
    bf16_t* __restrict__ yarb)
{
    const int h = blockIdx.y, b = blockIdx.z;
    const int qt = qt_map32((int)blockIdx.x, h, b);
    const int tid = threadIdx.x, wave = tid >> 6, lane = tid & 63;
    const int l15 = lane & 15, quad = lane >> 4;
    const int q0 = qt * 64;
    const int bh = b * NHH + h;

    __shared__ __align__(16) unsigned short Qs[64 * 64];
    __shared__ __align__(16) unsigned short Ks[2][64 * 64];
    __shared__ __align__(16) unsigned short Vs[2][64 * 64];

    const int nit = qt + 1;   // kv tiles 0 .. qt

    const bf16_t* kg = qkb + (size_t)(b*TT)*(2*DDE) + DDE + h*HDD;
    const bf16_t* vg = vtg + (size_t)(bh*64)*TT;

    // prologue: Q (2 loads/wave) + tiles 0[,1] (4 loads/wave each)
    stage_tile<64>(qkb + (size_t)(b*TT + q0) * (2*DDE) + h*HDD, 2*DDE, Qs, wave, lane);
    stage_tile<64>(kg, 2*DDE, Ks[0], wave, lane);
    stage_tile<64>(vg, TT, Vs[0], wave, lane);
    if (nit > 1) {
        stage_tile<64>(kg + (size_t)64*(2*DDE), 2*DDE, Ks[1], wave, lane);
        stage_tile<64>(vg + 64, TT, Vs[1], wave, lane);
        WAIT_VM4();            // Q + tile0 done, tile1 in flight
    } else {
        WAIT_VM0();
    }
    wg_barrier();

    bf16x8 qf[2];
    #pragma unroll
    for (int kc = 0; kc < 2; ++kc)
        qf[kc] = *(const bf16x8*)(Qs + (wave*16 + l15)*64
                                  + ((kc*4 + quad) ^ (l15 & 7))*8);

    f32x4 o[4];
    float lrow = 0.f;
    #pragma unroll
    for (int nt = 0; nt < 4; ++nt) o[nt] = (f32x4)0.f;

    const int qw0 = q0 + wave * 16;
    // bpermute byte indices for cross-quad P repack
    const int idxA = ((((2*quad    ) & 3) << 4) + l15) << 2;
    const int idxB = ((((2*quad + 1) & 3) << 4) + l15) << 2;

    for (int it = 0; it < nit; ++it) {
        if (it > 0) {
            if (it + 1 < nit) WAIT_VM4(); else WAIT_VM0();
            wg_barrier();
        }
        const int s0 = it * 64;
        const unsigned short* Kc = Ks[it & 1];
        const unsigned short* Vc = Vs[it & 1];

        // swapped QK: sv holds S^T — key = nt*16+quad*4+r, query = l15
        f32x4 sv[4];
        __builtin_amdgcn_s_setprio(1);
        #pragma unroll
        for (int nt = 0; nt < 4; ++nt) {
            const unsigned short* kr = Kc + (nt*16 + l15)*64;
            bf16x8 kb0 = *(const bf16x8*)(kr + ((quad    ) ^ (l15 & 7))*8);
            bf16x8 kb1 = *(const bf16x8*)(kr + ((quad + 4) ^ (l15 & 7))*8);
            f32x4 z = (f32x4)0.f;
            z = MFMA(kb0, qf[0], z);
            z = MFMA(kb1, qf[1], z);
            sv[nt] = z;
        }
        __builtin_amdgcn_s_setprio(0);

        const bool domask = (s0 + 63 > qw0);
        const int qg = qw0 + l15;
        unsigned int pk[4][2];
        #pragma unroll
        for (int nt = 0; nt < 4; ++nt) {
            float pv[4];
            #pragma unroll
            for (int r = 0; r < 4; ++r) {
                float p = exp2f(sv[nt][r]);
                if (domask) {
                    const int sg = s0 + nt*16 + quad*4 + r;
                    if (sg > qg) p = 0.f;
                }
                lrow += p;
                pv[r] = p;
            }
            pk[nt][0] = cvtpk(pv[0], pv[1]);
            pk[nt][1] = cvtpk(pv[2], pv[3]);
        }
        // repack S^T (C-layout) -> PV A-fragment
        bf16x8 pa[2];
        #pragma unroll
        for (int sc = 0; sc < 2; ++sc) {
            union { unsigned int u[4]; bf16x8 v; } pu;
            #pragma unroll
            for (int jp = 0; jp < 4; ++jp) {
                const int idx = (jp & 2) ? idxB : idxA;
                const int lo = __builtin_amdgcn_ds_bpermute(idx, (int)pk[2*sc  ][jp & 1]);
                const int hi = __builtin_amdgcn_ds_bpermute(idx, (int)pk[2*sc+1][jp & 1]);
                pu.u[jp] = (quad & 2) ? (unsigned)hi : (unsigned)lo;
            }
            pa[sc] = pu.v;
        }

        __builtin_amdgcn_s_setprio(1);
        #pragma unroll
        for (int nt = 0; nt < 4; ++nt) {
            const unsigned short* vr = Vc + (nt*16 + l15)*64;
            bf16x8 vb0 = *(const bf16x8*)(vr + ((quad    ) ^ (l15 & 7))*8);
            bf16x8 vb1 = *(const bf16x8*)(vr + ((quad + 4) ^ (l15 & 7))*8);
            o[nt] = MFMA(pa[0], vb0, o[nt]);
            o[nt] = MFMA(pa[1], vb1, o[nt]);
        }
        __builtin_amdgcn_s_setprio(0);

        WAIT_LGKM0();
        wg_barrier();
        if (it + 2 < nit) {
            stage_tile<64>(kg + (size_t)(it+2)*64*(2*DDE), 2*DDE, Ks[it & 1], wave, lane);
            stage_tile<64>(vg + (it+2)*64, TT, Vs[it & 1], wave, lane);
        }
    }

    // epilogue: normalize and store bf16 (no atomics).
    float lv = lrow;
    lv += __shfl_xor(lv, 16);
    lv += __shfl_xor(lv, 32);
    // o rows are C-layout (quad*4+r): fetch that row's sum from lane quad*4+r
    float inv[4];
    #pragma unroll
    for (int r = 0; r < 4; ++r) {
        const int src = (quad*4 + r) << 2;
        const float sum = __int_as_float(
            __builtin_amdgcn_ds_bpermute(src, __float_as_int(lv)));
        inv[r] = 1.f / sum;
    }
    #pragma unroll
    for (int nt = 0; nt < 4; ++nt)
        #pragma unroll
        for (int r = 0; r < 4; ++r) {
            const int row = qw0 + quad*4 + r;
            const int col = h*HDD + nt*16 + l15;
            yarb[(size_t)(b*TT + row)*DDE + col] = (bf16_t)(o[nt][r] * inv[r]);
        }
}

// ---------------------------------------------------------------------------
// MA: linear causal attention, one block per 64-row q-tile (no atomics).
// Q row-sum computed in-register from qf fragments (no LDS Rl).
// Epilogue fuses combine: ysumb = bf16(yarb + o).
// ---------------------------------------------------------------------------
__global__ __launch_bounds__(256) void attn_ma_mfma(
    const bf16_t* __restrict__ qab, const bf16_t* __restrict__ kcs,
    const bf16_t* __restrict__ etg, const bf16_t* __restrict__ yarb,
    bf16_t* __restrict__ ysumb)
{
    const int h = blockIdx.y, b = blockIdx.z;
    const int qt = qt_map32((int)blockIdx.x, h, b);
    const int tid = threadIdx.x, wave = tid >> 6, lane = tid & 63;
    const int l15 = lane & 15, quad = lane >> 4;
    const int q0 = qt * 64;
    const int bh = b * NHH + h;

    __shared__ __align__(16) unsigned short Qs[64 * 64];
    __shared__ __align__(16) unsigned short Ks[2][64 * 64];
    __shared__ __align__(16) unsigned short Es[2][64 * 64];

    const int nit = qt + 1;

    const bf16_t* kg = kcs + (size_t)(b*TT)*DDE + h*HDD;
    const bf16_t* eg = etg + (size_t)(bh*64)*TT;

    stage_tile<64>(qab + (size_t)(b*TT + q0)*DDE + h*HDD, DDE, Qs, wave, lane);
    stage_tile<64>(kg, DDE, Ks[0], wave, lane);
    stage_tile<64>(eg, TT, Es[0], wave, lane);
    if (nit > 1) {
        stage_tile<64>(kg + (size_t)64*DDE, DDE, Ks[1], wave, lane);
        stage_tile<64>(eg + 64, TT, Es[1], wave, lane);
        WAIT_VM4();
    } else {
        WAIT_VM0();
    }
    wg_barrier();

    bf16x8 qf[2];
    #pragma unroll
    for (int kc = 0; kc < 2; ++kc)
        qf[kc] = *(const bf16x8*)(Qs + (wave*16 + l15)*64
                                  + ((kc*4 + quad) ^ (l15 & 7))*8);

    // Q row-sum (64 cols) in-register: lane holds 16 elems; quad butterfly.
    float rs = 0.f;
    #pragma unroll
    for (int kc = 0; kc < 2; ++kc)
        #pragma unroll
        for (int u = 0; u < 8; ++u) rs += (float)qf[kc][u];
    rs += __shfl_xor(rs, 16);
    rs += __shfl_xor(rs, 32);
    const float Rr = 0.5f * rs;     // row-sum for query row l15 (all quads)

    f32x4 o[4];
    #pragma unroll
    for (int nt = 0; nt < 4; ++nt) o[nt] = (f32x4)0.f;

    const int qw0 = q0 + wave * 16;
    const int idxA = ((((2*quad    ) & 3) << 4) + l15) << 2;
    const int idxB = ((((2*quad + 1) & 3) << 4) + l15) << 2;

    for (int it = 0; it < nit; ++it) {
        if (it > 0) {
            if (it + 1 < nit) WAIT_VM4(); else WAIT_VM0();
            wg_barrier();
        }
        const int s0 = it * 64;
        const unsigned short* Kc = Ks[it & 1];
        const unsigned short* Ec = Es[it & 1];

        f32x4 sv[4];
        __builtin_amdgcn_s_setprio(1);
        #pragma unroll
        for (int nt = 0; nt < 4; ++nt) {
            const unsigned short* kr = Kc + (nt*16 + l15)*64;
            bf16x8 kb0 = *(const bf16x8*)(kr + ((quad    ) ^ (l15 & 7))*8);
            bf16x8 kb1 = *(const bf16x8*)(kr + ((quad + 4) ^ (l15 & 7))*8);
            f32x4 z = (f32x4)0.f;
            z = MFMA(kb0, qf[0], z);
            z = MFMA(kb1, qf[1], z);
            sv[nt] = z;
        }
        __builtin_amdgcn_s_setprio(0);

        const bool domask = (s0 + 63 > qw0);
        const bool m0 = (it == 0);
        const int qg = qw0 + l15;
        unsigned int pk[4][2];
        #pragma unroll
        for (int nt = 0; nt < 4; ++nt) {
            float pv[4];
            #pragma unroll
            for (int r = 0; r < 4; ++r) {
                const int sg = s0 + nt*16 + quad*4 + r;
                float p = sv[nt][r] + Rr;
                if (m0 && sg == 0) p = 0.f;
                if (domask && sg > qg) p = 0.f;
                pv[r] = p;
            }
            pk[nt][0] = cvtpk(pv[0], pv[1]);
            pk[nt][1] = cvtpk(pv[2], pv[3]);
        }
        bf16x8 pa[2];
        #pragma unroll
        for (int sc = 0; sc < 2; ++sc) {
            union { unsigned int u[4]; bf16x8 v; } pu;
            #pragma unroll
            for (int jp = 0; jp < 4; ++jp) {
                const int idx = (jp & 2) ? idxB : idxA;
                const int lo = __builtin_amdgcn_ds_bpermute(idx, (int)pk[2*sc  ][jp & 1]);
                const int hi = __builtin_amdgcn_ds_bpermute(idx, (int)pk[2*sc+1][jp & 1]);
                pu.u[jp] = (quad & 2) ? (unsigned)hi : (unsigned)lo;
            }
            pa[sc] = pu.v;
        }

        __builtin_amdgcn_s_setprio(1);
        #pragma unroll
        for (int nt = 0; nt < 4; ++nt) {
            const unsigned short* er = Ec + (nt*16 + l15)*64;
            bf16x8 eb0 = *(const bf16x8*)(er + ((quad    ) ^ (l15 & 7))*8);
            bf16x8 eb1 = *(const bf16x8*)(er + ((quad + 4) ^ (l15 & 7))*8);
            o[nt] = MFMA(pa[0], eb0, o[nt]);
            o[nt] = MFMA(pa[1], eb1, o[nt]);
        }
        __builtin_amdgcn_s_setprio(0);

        WAIT_LGKM0();
        wg_barrier();
        if (it + 2 < nit) {
            stage_tile<64>(kg + (size_t)(it+2)*64*DDE, DDE, Ks[it & 1], wave, lane);
            stage_tile<64>(eg + (it+2)*64, TT, Es[it & 1], wave, lane);
        }
    }

    // epilogue: ysumb = bf16(yarb + o)  (each (row,col) owned exactly once)
    #pragma unroll
    for (int nt = 0; nt < 4; ++nt)
        #pragma unroll
        for (int r = 0; r < 4; ++r) {
            const int row = qw0 + quad*4 + r;
            const int col = h*HDD + nt*16 + l15;
            const size_t e = (size_t)(b*TT + row)*DDE + col;
            ysumb[e] = (bf16_t)((float)yarb[e] + o[nt][r]);
        }
}

// ---------------------------------------------------------------------------
extern "C" void kernel_launch(void* const* d_in, const int* in_sizes, int n_in,
                              void* d_out, int out_size, void* d_ws, size_t ws_size,
                              hipStream_t stream)
{
    const float* x      = (const float*)d_in[0];
    const float* w_attn = (const float*)d_in[1];
    const float* b_attn = (const float*)d_in[2];
    const float* w_k2   = (const float*)d_in[3];
    const float* b_k2   = (const float*)d_in[4];
    const float* w_proj = (const float*)d_in[5];
    const float* b_proj = (const float*)d_in[6];

    const size_t NX  = (size_t)BB*TT*DDE;
    const size_t NWA = (size_t)2*DDE*DDE;
    const size_t NW  = (size_t)DDE*DDE;
    const size_t NQK = (size_t)BB*TT*2*DDE;

    bf16_t* xb   = (bf16_t*)d_ws;
    bf16_t* wab  = xb   + NX;
    bf16_t* wkb  = wab  + NWA;
    bf16_t* wpb  = wkb  + NW;
    bf16_t* qkb  = wpb  + NW;
    bf16_t* qab  = qkb  + NQK;
    bf16_t* kcs  = qab  + NX;
    bf16_t* vtg  = kcs  + NX;          // aliased by etg after attn_ar
    bf16_t* ysumb= vtg  + NX;
    bf16_t* yarb = (bf16_t*)((float*)(vtg + NX) + NX);
    bf16_t* etg  = vtg;

    const size_t NCVT = NX + NWA + NW + NW;
    cvt_all<<<NCVT / 1024, 256, 0, stream>>>(x, w_attn, w_k2, w_proj, xb);

    transpose_head<<<dim3(TT/64, NHH, BB), 256, 0, stream>>>(xb, vtg);

    const int M = BB * TT;
    gemm_qkk2<<<dim3(24, M/64), 256, 0, stream>>>(xb, wab, wkb, b_attn, b_k2,
                                                   qkb, qab, kcs);

    attn_ar_mfma<<<dim3(32, NHH, BB), 256, 0, stream>>>(qkb, vtg, yarb);
    build_etg<<<dim3(TT/64, NHH, BB), 256, 0, stream>>>(yarb, xb, etg);
    attn_ma_mfma<<<dim3(32, NHH, BB), 256, 0, stream>>>(qab, kcs, etg, yarb, ysumb);

    gemm_proj<<<dim3(DDE/64, M/64), 256, 0, stream>>>(ysumb, wpb, b_proj,
                                                      (float*)d_out, M, DDE, DDE, 2.f);
}

// Round 7
// 240.320 us; speedup vs baseline: 1.2659x; 1.0626x over previous
//
#include <hip/hip_runtime.h>
#include <hip/hip_bf16.h>
#include <math.h>

#define BB  2
#define TT  2048
#define DDE 1024
#define NHH 16
#define HDD 64

typedef __bf16 bf16_t;
typedef __attribute__((ext_vector_type(8))) __bf16 bf16x8;
typedef __attribute__((ext_vector_type(4))) __bf16 bf16x4;
typedef __attribute__((ext_vector_type(4))) float  f32x4;

#define MFMA(a, b, c) __builtin_amdgcn_mfma_f32_16x16x32_bf16((a), (b), (c), 0, 0, 0)

// counted waits: loads for the NEXT tile stay in flight across barriers (T4)
#define WAIT_VM6()   asm volatile("s_waitcnt vmcnt(6)" ::: "memory")
#define WAIT_VM4()   asm volatile("s_waitcnt vmcnt(4)" ::: "memory")
#define WAIT_VM0()   asm volatile("s_waitcnt vmcnt(0)" ::: "memory")
#define WAIT_LGKM0() asm volatile("s_waitcnt lgkmcnt(0)" ::: "memory")

// raw workgroup barrier (no vmcnt drain), fenced against compiler reordering
__device__ inline void wg_barrier() {
    __builtin_amdgcn_sched_barrier(0);
    __builtin_amdgcn_s_barrier();
    __builtin_amdgcn_sched_barrier(0);
}

// pack 2 f32 -> 1 u32 of 2 bf16 (RNE), no builtin on gfx950
__device__ inline unsigned int cvtpk(float a, float b) {
    unsigned int r;
    asm("v_cvt_pk_bf16_f32 %0, %1, %2" : "=v"(r) : "v"(a), "v"(b));
    return r;
}

// v_permlane16_swap_b32: swaps a's odd 16-lane rows with b's even 16-lane
// rows.  After: a = {a.r0, b.r0, a.r2, b.r2}, b = {a.r1, b.r1, a.r3, b.r3}.
__device__ inline void pl16swap(unsigned int &a, unsigned int &b) {
    asm("v_permlane16_swap_b32 %0, %1" : "+v"(a), "+v"(b));
}

__device__ inline void gll16(const bf16_t* g, unsigned short* l) {
    __builtin_amdgcn_global_load_lds(
        (const __attribute__((address_space(1))) void*)g,
        (__attribute__((address_space(3))) void*)l, 16, 0, 0);
}

// Stage [ROWS x 64] bf16 tile (row stride gstride elems) into LDS via
// global_load_lds, chunk-swizzled: LDS elem [r][ (c ^ (r&7))*8 + j ].
// Per-wave gll16 count: ROWS/32  (128 -> 4, 64 -> 2).
template<int ROWS>
__device__ inline void stage_tile(const bf16_t* g0, size_t gstride,
                                  unsigned short* lds, int wave, int lane)
{
    const int r8 = lane >> 3;
    const int ck = (lane & 7) ^ r8;
    constexpr int RW = ROWS / 4;
    const bf16_t* g = g0 + (size_t)(wave * RW + r8) * gstride + ck * 8;
    unsigned short* l = lds + wave * RW * 64 + lane * 8;
    #pragma unroll
    for (int i = 0; i < RW / 8; ++i)
        gll16(g + (size_t)(i * 8) * gstride, l + i * 512);
}

// ---------------------------------------------------------------------------
// fused fp32->bf16 conversion of x, w_attn, w_k2, w_proj into the contiguous
// ws region starting at xb.  Segment boundaries are multiples of 1024 elems.
// ---------------------------------------------------------------------------
__global__ __launch_bounds__(256) void cvt_all(
    const float* __restrict__ x, const float* __restrict__ wa,
    const float* __restrict__ wk, const float* __restrict__ wp,
    bf16_t* __restrict__ out)
{
    const size_t NX  = (size_t)BB*TT*DDE;
    const size_t NWA = (size_t)2*DDE*DDE;
    const size_t NW  = (size_t)DDE*DDE;
    const size_t e = ((size_t)blockIdx.x * 256 + threadIdx.x) * 4;
    const float* src;
    if (e < NX)                 src = x  + e;
    else if (e < NX + NWA)      src = wa + (e - NX);
    else if (e < NX + NWA + NW) src = wk + (e - NX - NWA);
    else                        src = wp + (e - NX - NWA - NW);
    float4 v = *(const float4*)src;
    bf16x4 o;
    o[0] = (bf16_t)v.x; o[1] = (bf16_t)v.y;
    o[2] = (bf16_t)v.z; o[3] = (bf16_t)v.w;
    *(bf16x4*)(out + e) = o;
}

// ---------------------------------------------------------------------------
// Per-head 64x64 transpose: dst[bh][d][t] = src[b][t][h*64+d].
// ---------------------------------------------------------------------------
__global__ __launch_bounds__(256) void transpose_head(
    const bf16_t* __restrict__ src, bf16_t* __restrict__ dst)
{
    const int t0 = blockIdx.x * 64, h = blockIdx.y, b = blockIdx.z;
    const int tid = threadIdx.x;
    __shared__ __align__(16) bf16_t tile[64 * 64];

    #pragma unroll
    for (int it = 0; it < 2; ++it) {
        const int t = it * 32 + (tid >> 3);
        const int cw = tid & 7;
        const int slot = (cw + (t >> 3)) & 7;
        bf16x8 v = *(const bf16x8*)(src + (size_t)(b*TT + t0 + t)*DDE + h*HDD + cw*8);
        *(bf16x8*)(tile + t*64 + slot*8) = v;
    }
    __syncthreads();
    const int bh = b * NHH + h;
    #pragma unroll
    for (int it = 0; it < 2; ++it) {
        const int d = it * 32 + (tid >> 3);
        const int co = tid & 7;
        const int slot = ((d >> 3) + co) & 7;
        bf16x8 o;
        #pragma unroll
        for (int j = 0; j < 8; ++j)
            o[j] = tile[(co*8 + j)*64 + slot*8 + (d & 7)];
        *(bf16x8*)(dst + (size_t)(bh*64 + d)*TT + t0 + co*8) = o;
    }
}

// ---------------------------------------------------------------------------
// E-transpose: etg[bh][d][t] = x[t][d] - n[t-1][d]  (0 at t==0),
// where n = yarb (normalized AR output, written by attn_ar).
// ---------------------------------------------------------------------------
__global__ __launch_bounds__(256) void build_etg(
    const bf16_t* __restrict__ yarb, const bf16_t* __restrict__ xb,
    bf16_t* __restrict__ etg)
{
    const int t0 = blockIdx.x * 64, h = blockIdx.y, b = blockIdx.z;
    const int tid = threadIdx.x;
    const int bh = b * NHH + h;
    __shared__ __align__(16) bf16_t tile[64 * 64];

    #pragma unroll
    for (int it = 0; it < 2; ++it) {
        const int t = it * 32 + (tid >> 3);
        const int cw = tid & 7;
        const int slot = (cw + (t >> 3)) & 7;
        const int tg = t0 + t;
        bf16x8 ev;
        if (tg == 0) {
            #pragma unroll
            for (int u = 0; u < 8; ++u) ev[u] = (bf16_t)0.f;
        } else {
            bf16x8 xv = *(const bf16x8*)(xb   + (size_t)(b*TT + tg)*DDE + h*HDD + cw*8);
            bf16x8 nv = *(const bf16x8*)(yarb + (size_t)(b*TT + tg - 1)*DDE + h*HDD + cw*8);
            #pragma unroll
            for (int u = 0; u < 8; ++u)
                ev[u] = (bf16_t)((float)xv[u] - (float)nv[u]);
        }
        *(bf16x8*)(tile + t*64 + slot*8) = ev;
    }
    __syncthreads();
    #pragma unroll
    for (int it = 0; it < 2; ++it) {
        const int d = it * 32 + (tid >> 3);
        const int co = tid & 7;
        const int slot = ((d >> 3) + co) & 7;
        bf16x8 o;
        #pragma unroll
        for (int j = 0; j < 8; ++j)
            o[j] = tile[(co*8 + j)*64 + slot*8 + (d & 7)];
        *(bf16x8*)(etg + (size_t)(bh*64 + d)*TT + t0 + co*8) = o;
    }
}

// ---------------------------------------------------------------------------
// Fused QKV GEMM, BM=64 x BN=128, BK=64, counted-vmcnt dbuf pipeline.
// Region by column tile:
//   [0,1024):  q -> qkb = q*0.125*log2(e) (exp2 domain), qab = leaky(q*0.125)
//   [1024,2048): k -> qkb raw
//   [2048,3072): k2 -> kcs[t+1] = sigmoid(k2*0.0025)-0.5 (shifted, row0=0)
// ---------------------------------------------------------------------------
__global__ __launch_bounds__(256) void gemm_qkk2(
    const bf16_t* __restrict__ A, const bf16_t* __restrict__ wab,
    const bf16_t* __restrict__ wkb, const float* __restrict__ b_attn,
    const float* __restrict__ b_k2, bf16_t* __restrict__ qkb,
    bf16_t* __restrict__ qab, bf16_t* __restrict__ kcs)
{
    __shared__ __align__(16) unsigned short As[2][64 * 64];
    __shared__ __align__(16) unsigned short Bs[2][128 * 64];
    const int tid  = threadIdx.x;
    const int wave = tid >> 6, lane = tid & 63;
    const int l15  = lane & 15, quad = lane >> 4;
    // XCD swizzle (bijective: 1536 = 8*192): each XCD owns 8 contiguous
    // m-rows x all 24 n-tiles; per-k-step slab (A 64KB + B 384KB) L2-fits.
    const int lid = (int)blockIdx.y * 24 + (int)blockIdx.x;
    const int s   = (lid & 7) * 192 + (lid >> 3);
    const int bm = (s / 24) * 64, bn = (s % 24) * 128;
    const int wm = (wave & 1) * 32, wn = (wave >> 1) * 64;
    const int region = bn >> 10;
    const int K = DDE;
    constexpr int NST = DDE / 64;   // 16 K-steps

    const bf16_t* W = (region < 2) ? wab + (size_t)bn * K
                                   : wkb + (size_t)(bn - 2048) * K;
    const float* bp = (region < 2) ? b_attn + bn : b_k2 + (bn - 2048);
    const bf16_t* Ab = A + (size_t)bm * K;

    f32x4 acc[2][4];
    #pragma unroll
    for (int i = 0; i < 2; ++i)
        #pragma unroll
        for (int j = 0; j < 4; ++j) acc[i][j] = (f32x4)0.f;

    // prologue: stage K-steps 0 and 1 (6 gll16/wave each: 2 A + 4 B)
    stage_tile<64>(Ab, K, As[0], wave, lane);
    stage_tile<128>(W,  K, Bs[0], wave, lane);
    stage_tile<64>(Ab + 64, K, As[1], wave, lane);
    stage_tile<128>(W  + 64, K, Bs[1], wave, lane);

    for (int t = 0; t < NST; ++t) {
        // wait tile t landed; tile t+1's 6 loads stay in flight
        if (t + 1 < NST) WAIT_VM6(); else WAIT_VM0();
        wg_barrier();
        const unsigned short* Ac = As[t & 1];
        const unsigned short* Bc = Bs[t & 1];
        bf16x8 af[2][2], bfr[4][2];
        #pragma unroll
        for (int mt = 0; mt < 2; ++mt)
            #pragma unroll
            for (int kh = 0; kh < 2; ++kh)
                af[mt][kh] = *(const bf16x8*)(Ac + (wm + mt*16 + l15)*64
                                              + (((kh*4 + quad) ^ (l15 & 7))*8));
        #pragma unroll
        for (int nt = 0; nt < 4; ++nt)
            #pragma unroll
            for (int kh = 0; kh < 2; ++kh)
                bfr[nt][kh] = *(const bf16x8*)(Bc + (wn + nt*16 + l15)*64
                                               + (((kh*4 + quad) ^ (l15 & 7))*8));
        __builtin_amdgcn_s_setprio(1);
        #pragma unroll
        for (int mt = 0; mt < 2; ++mt)
            #pragma unroll
            for (int nt = 0; nt < 4; ++nt) {
                acc[mt][nt] = MFMA(af[mt][0], bfr[nt][0], acc[mt][nt]);
                acc[mt][nt] = MFMA(af[mt][1], bfr[nt][1], acc[mt][nt]);
            }
        __builtin_amdgcn_s_setprio(0);
        // all waves done reading buf[t&1] before restaging into it
        WAIT_LGKM0();
        wg_barrier();
        if (t + 2 < NST) {
            stage_tile<64>(Ab + (t+2)*64, K, As[t & 1], wave, lane);
            stage_tile<128>(W  + (t+2)*64, K, Bs[t & 1], wave, lane);
        }
    }

    #pragma unroll
    for (int nt = 0; nt < 4; ++nt) {
        const int cl = wn + nt*16 + l15;
        const float bj = bp[cl];
        const int cg = bn + cl;
        #pragma unroll
        for (int mt = 0; mt < 2; ++mt)
            #pragma unroll
            for (int r = 0; r < 4; ++r) {
                const int row = bm + wm + mt*16 + quad*4 + r;
                const float v = acc[mt][nt][r] + bj;
                if (region == 0) {
                    qkb[(size_t)row * (2*DDE) + cg] = (bf16_t)(v * 0.180336880f);
                    const float z = v * 0.125f;
                    qab[(size_t)row * DDE + cg] = (bf16_t)((v > 0.f) ? 0.02f*z : z);
                } else if (region == 1) {
                    qkb[(size_t)row * (2*DDE) + cg] = (bf16_t)v;
                } else {
                    const int c2 = cg - 2048;
                    const float kc = 1.f/(1.f + __expf(-v*0.0025f)) - 0.5f;
                    if (((row + 1) & (TT - 1)) != 0)
                        kcs[(size_t)(row + 1) * DDE + c2] = (bf16_t)kc;
                    if ((row & (TT - 1)) == 0)
                        kcs[(size_t)row * DDE + c2] = (bf16_t)0.f;
                }
            }
    }
}

// ---------------------------------------------------------------------------
// proj GEMM, BM=64 x BN=64, BK=64, counted-vmcnt dbuf (fp32 out):
// C = A W^T + 2*bias.  1024 blocks (4/CU by grid, 5/CU by LDS=32KB).
// ---------------------------------------------------------------------------
__global__ __launch_bounds__(256) void gemm_proj(
    const bf16_t* __restrict__ A, const bf16_t* __restrict__ W,
    const float* __restrict__ bias, float* __restrict__ C,
    int M, int N, int K, float bmul)
{
    __shared__ __align__(16) unsigned short As[2][64 * 64];
    __shared__ __align__(16) unsigned short Bs[2][64 * 64];
    const int tid  = threadIdx.x;
    const int wave = tid >> 6, lane = tid & 63;
    const int l15  = lane & 15, quad = lane >> 4;
    // XCD swizzle (bijective: 1024 = 8*128)
    const int lid = (int)blockIdx.y * 16 + (int)blockIdx.x;
    const int s   = (lid & 7) * 128 + (lid >> 3);
    const int bm = (s / 16) * 64, bn = (s % 16) * 64;
    const int wm = (wave & 1) * 32, wn = (wave >> 1) * 32;

    const bf16_t* Ab = A + (size_t)bm * K;
    const bf16_t* Wb = W + (size_t)bn * K;
    const int NST = K / 64;

    f32x4 acc[2][2];
    #pragma unroll
    for (int i = 0; i < 2; ++i)
        #pragma unroll
        for (int j = 0; j < 2; ++j) acc[i][j] = (f32x4)0.f;

    stage_tile<64>(Ab, K, As[0], wave, lane);
    stage_tile<64>(Wb, K, Bs[0], wave, lane);
    stage_tile<64>(Ab + 64, K, As[1], wave, lane);
    stage_tile<64>(Wb + 64, K, Bs[1], wave, lane);

    for (int t = 0; t < NST; ++t) {
        if (t + 1 < NST) WAIT_VM4(); else WAIT_VM0();
        wg_barrier();
        const unsigned short* Ac = As[t & 1];
        const unsigned short* Bc = Bs[t & 1];
        bf16x8 af[2][2], bfr[2][2];
        #pragma unroll
        for (int mt = 0; mt < 2; ++mt)
            #pragma unroll
            for (int kh = 0; kh < 2; ++kh)
                af[mt][kh] = *(const bf16x8*)(Ac + (wm + mt*16 + l15)*64
                                              + (((kh*4 + quad) ^ (l15 & 7))*8));
        #pragma unroll
        for (int nt = 0; nt < 2; ++nt)
            #pragma unroll
            for (int kh = 0; kh < 2; ++kh)
                bfr[nt][kh] = *(const bf16x8*)(Bc + (wn + nt*16 + l15)*64
                                               + (((kh*4 + quad) ^ (l15 & 7))*8));
        __builtin_amdgcn_s_setprio(1);
        #pragma unroll
        for (int mt = 0; mt < 2; ++mt)
            #pragma unroll
            for (int nt = 0; nt < 2; ++nt) {
                acc[mt][nt] = MFMA(af[mt][0], bfr[nt][0], acc[mt][nt]);
                acc[mt][nt] = MFMA(af[mt][1], bfr[nt][1], acc[mt][nt]);
            }
        __builtin_amdgcn_s_setprio(0);
        WAIT_LGKM0();
        wg_barrier();
        if (t + 2 < NST) {
            stage_tile<64>(Ab + (t+2)*64, K, As[t & 1], wave, lane);
            stage_tile<64>(Wb + (t+2)*64, K, Bs[t & 1], wave, lane);
        }
    }

    #pragma unroll
    for (int nt = 0; nt < 2; ++nt) {
        const int col = bn + wn + nt*16 + l15;
        const float bj = bias[col] * bmul;
        #pragma unroll
        for (int mt = 0; mt < 2; ++mt)
            #pragma unroll
            for (int r = 0; r < 4; ++r) {
                const int row = bm + wm + mt*16 + quad*4 + r;
                C[(size_t)row * N + col] = acc[mt][nt][r] + bj;
            }
    }
}

// co-residency-balanced q-tile map over 32 tiles.  Blocks sharing a CU are
// {id, id+256, id+512, id+768} = same bx with (h>=8, b) varying; u selects
// one of 4 XOR-bijections so each CU's 4 blocks total exactly 66 kv-steps.
__device__ inline int qt_map32(int bx, int h, int b) {
    const int u = ((h >> 3) & 1) | (b << 1);
    int qt = (u & 1) ? (bx ^ 31) : bx;
    if (u & 2) qt ^= 16;
    return qt;
}

// ---------------------------------------------------------------------------
// AR: fixed-max flash attention.  One block owns one 64-row q-tile (no
// atomics); 1024 blocks = 4/CU (LDS 40 KB).  Counted-vmcnt dbuf K/V;
// swapped QK^T (S^T); P repack via 4x v_permlane16_swap (register-only,
// replaces 16 ds_bpermute/tile); denominators via ones-MFMA (C-layout
// aligned with o).  Epilogue normalizes and stores yarb (bf16).
// ---------------------------------------------------------------------------
__global__ __launch_bounds__(256) void attn_ar_mfma(
    const bf16_t* __restrict__ qkb, const bf16_t* __restrict__ vtg,
    bf16_t* __restrict__ yarb)
{
    const int h = blockIdx.y, b = blockIdx.z;
    const int qt = qt_map32((int)blockIdx.x, h, b);
    const int tid = threadIdx.x, wave = tid >> 6, lane = tid & 63;
    const int l15 = lane & 15, quad = lane >> 4;
    const int q0 = qt * 64;
    const int bh = b * NHH + h;

    __shared__ __align__(16) unsigned short Qs[64 * 64];
    __shared__ __align__(16) unsigned short Ks[2][64 * 64];
    __shared__ __align__(16) unsigned short Vs[2][64 * 64];

    const int nit = qt + 1;   // kv tiles 0 .. qt

    const bf16_t* kg = qkb + (size_t)(b*TT)*(2*DDE) + DDE + h*HDD;
    const bf16_t* vg = vtg + (size_t)(bh*64)*TT;

    // prologue: Q (2 loads/wave) + tiles 0[,1] (4 loads/wave each)
    stage_tile<64>(qkb + (size_t)(b*TT + q0) * (2*DDE) + h*HDD, 2*DDE, Qs, wave, lane);
    stage_tile<64>(kg, 2*DDE, Ks[0], wave, lane);
    stage_tile<64>(vg, TT, Vs[0], wave, lane);
    if (nit > 1) {
        stage_tile<64>(kg + (size_t)64*(2*DDE), 2*DDE, Ks[1], wave, lane);
        stage_tile<64>(vg + 64, TT, Vs[1], wave, lane);
        WAIT_VM4();            // Q + tile0 done, tile1 in flight
    } else {
        WAIT_VM0();
    }
    wg_barrier();

    bf16x8 qf[2];
    #pragma unroll
    for (int kc = 0; kc < 2; ++kc)
        qf[kc] = *(const bf16x8*)(Qs + (wave*16 + l15)*64
                                  + ((kc*4 + quad) ^ (l15 & 7))*8);

    f32x4 o[4];
    f32x4 ls = (f32x4)0.f;        // softmax denominators (C-layout rows)
    #pragma unroll
    for (int nt = 0; nt < 4; ++nt) o[nt] = (f32x4)0.f;
    bf16x8 onesb;
    #pragma unroll
    for (int j = 0; j < 8; ++j) onesb[j] = (bf16_t)1.f;

    const int qw0 = q0 + wave * 16;
    // after permlane repack, quad q holds key-chunk cq = bitswap(q)
    const int cq = ((quad & 1) << 1) | (quad >> 1);

    for (int it = 0; it < nit; ++it) {
        if (it > 0) {
            if (it + 1 < nit) WAIT_VM4(); else WAIT_VM0();
            wg_barrier();
        }
        const int s0 = it * 64;
        const unsigned short* Kc = Ks[it & 1];
        const unsigned short* Vc = Vs[it & 1];

        // swapped QK: sv holds S^T — key = nt*16+quad*4+r, query = l15
        f32x4 sv[4];
        __builtin_amdgcn_s_setprio(1);
        #pragma unroll
        for (int nt = 0; nt < 4; ++nt) {
            const unsigned short* kr = Kc + (nt*16 + l15)*64;
            bf16x8 kb0 = *(const bf16x8*)(kr + ((quad    ) ^ (l15 & 7))*8);
            bf16x8 kb1 = *(const bf16x8*)(kr + ((quad + 4) ^ (l15 & 7))*8);
            f32x4 z = (f32x4)0.f;
            z = MFMA(kb0, qf[0], z);
            z = MFMA(kb1, qf[1], z);
            sv[nt] = z;
        }
        __builtin_amdgcn_s_setprio(0);

        const bool domask = (s0 + 63 > qw0);
        const int qg = qw0 + l15;
        unsigned int pk[4][2];
        #pragma unroll
        for (int nt = 0; nt < 4; ++nt) {
            float pv[4];
            #pragma unroll
            for (int r = 0; r < 4; ++r) {
                float p = exp2f(sv[nt][r]);
                if (domask) {
                    const int sg = s0 + nt*16 + quad*4 + r;
                    if (sg > qg) p = 0.f;
                }
                pv[r] = p;
            }
            pk[nt][0] = cvtpk(pv[0], pv[1]);
            pk[nt][1] = cvtpk(pv[2], pv[3]);
        }
        // repack S^T (C-layout) -> PV A-fragment with 4 permlane16_swap:
        // pl16swap(u,v): u' = {u@q0,v@q0,u@q2,v@q2}, v' = {u@q1,v@q1,u@q3,v@q3}
        // -> pa[sc] = [u'w0,u'w1,v'w0,v'w1]: quad q holds keys cq*8..cq*8+7.
        bf16x8 pa[2];
        #pragma unroll
        for (int sc = 0; sc < 2; ++sc) {
            pl16swap(pk[2*sc][0], pk[2*sc+1][0]);
            pl16swap(pk[2*sc][1], pk[2*sc+1][1]);
            union { unsigned int u[4]; bf16x8 v; } pu;
            pu.u[0] = pk[2*sc][0];
            pu.u[1] = pk[2*sc][1];
            pu.u[2] = pk[2*sc+1][0];
            pu.u[3] = pk[2*sc+1][1];
            pa[sc] = pu.v;
        }

        __builtin_amdgcn_s_setprio(1);
        // denominators: rowsum via ones-B MFMA (lands in same lane/reg as o)
        ls = MFMA(pa[0], onesb, ls);
        ls = MFMA(pa[1], onesb, ls);
        #pragma unroll
        for (int nt = 0; nt < 4; ++nt) {
            const unsigned short* vr = Vc + (nt*16 + l15)*64;
            bf16x8 vb0 = *(const bf16x8*)(vr + ((cq    ) ^ (l15 & 7))*8);
            bf16x8 vb1 = *(const bf16x8*)(vr + ((cq + 4) ^ (l15 & 7))*8);
            o[nt] = MFMA(pa[0], vb0, o[nt]);
            o[nt] = MFMA(pa[1], vb1, o[nt]);
        }
        __builtin_amdgcn_s_setprio(0);

        WAIT_LGKM0();
        wg_barrier();
        if (it + 2 < nit) {
            stage_tile<64>(kg + (size_t)(it+2)*64*(2*DDE), 2*DDE, Ks[it & 1], wave, lane);
            stage_tile<64>(vg + (it+2)*64, TT, Vs[it & 1], wave, lane);
        }
    }

    // epilogue: normalize and store bf16 (no atomics, no redistribution —
    // ls[r] is the denominator for row quad*4+r, same as o[nt][r]).
    float inv[4];
    #pragma unroll
    for (int r = 0; r < 4; ++r) inv[r] = 1.f / ls[r];
    #pragma unroll
    for (int nt = 0; nt < 4; ++nt)
        #pragma unroll
        for (int r = 0; r < 4; ++r) {
            const int row = qw0 + quad*4 + r;
            const int col = h*HDD + nt*16 + l15;
            yarb[(size_t)(b*TT + row)*DDE + col] = (bf16_t)(o[nt][r] * inv[r]);
        }
}

// ---------------------------------------------------------------------------
// MA: linear causal attention, one block per 64-row q-tile (no atomics).
// Same permlane repack; Q row-sum in-register; fused combine epilogue.
// ---------------------------------------------------------------------------
__global__ __launch_bounds__(256) void attn_ma_mfma(
    const bf16_t* __restrict__ qab, const bf16_t* __restrict__ kcs,
    const bf16_t* __restrict__ etg, const bf16_t* __restrict__ yarb,
    bf16_t* __restrict__ ysumb)
{
    const int h = blockIdx.y, b = blockIdx.z;
    const int qt = qt_map32((int)blockIdx.x, h, b);
    const int tid = threadIdx.x, wave = tid >> 6, lane = tid & 63;
    const int l15 = lane & 15, quad = lane >> 4;
    const int q0 = qt * 64;
    const int bh = b * NHH + h;

    __shared__ __align__(16) unsigned short Qs[64 * 64];
    __shared__ __align__(16) unsigned short Ks[2][64 * 64];
    __shared__ __align__(16) unsigned short Es[2][64 * 64];

    const int nit = qt + 1;

    const bf16_t* kg = kcs + (size_t)(b*TT)*DDE + h*HDD;
    const bf16_t* eg = etg + (size_t)(bh*64)*TT;

    stage_tile<64>(qab + (size_t)(b*TT + q0)*DDE + h*HDD, DDE, Qs, wave, lane);
    stage_tile<64>(kg, DDE, Ks[0], wave, lane);
    stage_tile<64>(eg, TT, Es[0], wave, lane);
    if (nit > 1) {
        stage_tile<64>(kg + (size_t)64*DDE, DDE, Ks[1], wave, lane);
        stage_tile<64>(eg + 64, TT, Es[1], wave, lane);
        WAIT_VM4();
    } else {
        WAIT_VM0();
    }
    wg_barrier();

    bf16x8 qf[2];
    #pragma unroll
    for (int kc = 0; kc < 2; ++kc)
        qf[kc] = *(const bf16x8*)(Qs + (wave*16 + l15)*64
                                  + ((kc*4 + quad) ^ (l15 & 7))*8);

    // Q row-sum (64 cols) in-register: lane holds 16 elems; quad butterfly.
    float rs = 0.f;
    #pragma unroll
    for (int kc = 0; kc < 2; ++kc)
        #pragma unroll
        for (int u = 0; u < 8; ++u) rs += (float)qf[kc][u];
    rs += __shfl_xor(rs, 16);
    rs += __shfl_xor(rs, 32);
    const float Rr = 0.5f * rs;     // row-sum for query row l15 (all quads)

    f32x4 o[4];
    #pragma unroll
    for (int nt = 0; nt < 4; ++nt) o[nt] = (f32x4)0.f;

    const int qw0 = q0 + wave * 16;
    const int cq = ((quad & 1) << 1) | (quad >> 1);

    for (int it = 0; it < nit; ++it) {
        if (it > 0) {
            if (it + 1 < nit) WAIT_VM4(); else WAIT_VM0();
            wg_barrier();
        }
        const int s0 = it * 64;
        const unsigned short* Kc = Ks[it & 1];
        const unsigned short* Ec = Es[it & 1];

        f32x4 sv[4];
        __builtin_amdgcn_s_setprio(1);
        #pragma unroll
        for (int nt = 0; nt < 4; ++nt) {
            const unsigned short* kr = Kc + (nt*16 + l15)*64;
            bf16x8 kb0 = *(const bf16x8*)(kr + ((quad    ) ^ (l15 & 7))*8);
            bf16x8 kb1 = *(const bf16x8*)(kr + ((quad + 4) ^ (l15 & 7))*8);
            f32x4 z = (f32x4)0.f;
            z = MFMA(kb0, qf[0], z);
            z = MFMA(kb1, qf[1], z);
            sv[nt] = z;
        }
        __builtin_amdgcn_s_setprio(0);

        const bool domask = (s0 + 63 > qw0);
        const bool m0 = (it == 0);
        const int qg = qw0 + l15;
        unsigned int pk[4][2];
        #pragma unroll
        for (int nt = 0; nt < 4; ++nt) {
            float pv[4];
            #pragma unroll
            for (int r = 0; r < 4; ++r) {
                const int sg = s0 + nt*16 + quad*4 + r;
                float p = sv[nt][r] + Rr;
                if (m0 && sg == 0) p = 0.f;
                if (domask && sg > qg) p = 0.f;
                pv[r] = p;
            }
            pk[nt][0] = cvtpk(pv[0], pv[1]);
            pk[nt][1] = cvtpk(pv[2], pv[3]);
        }
        bf16x8 pa[2];
        #pragma unroll
        for (int sc = 0; sc < 2; ++sc) {
            pl16swap(pk[2*sc][0], pk[2*sc+1][0]);
            pl16swap(pk[2*sc][1], pk[2*sc+1][1]);
            union { unsigned int u[4]; bf16x8 v; } pu;
            pu.u[0] = pk[2*sc][0];
            pu.u[1] = pk[2*sc][1];
            pu.u[2] = pk[2*sc+1][0];
            pu.u[3] = pk[2*sc+1][1];
            pa[sc] = pu.v;
        }

        __builtin_amdgcn_s_setprio(1);
        #pragma unroll
        for (int nt = 0; nt < 4; ++nt) {
            const unsigned short* er = Ec + (nt*16 + l15)*64;
            bf16x8 eb0 = *(const bf16x8*)(er + ((cq    ) ^ (l15 & 7))*8);
            bf16x8 eb1 = *(const bf16x8*)(er + ((cq + 4) ^ (l15 & 7))*8);
            o[nt] = MFMA(pa[0], eb0, o[nt]);
            o[nt] = MFMA(pa[1], eb1, o[nt]);
        }
        __builtin_amdgcn_s_setprio(0);

        WAIT_LGKM0();
        wg_barrier();
        if (it + 2 < nit) {
            stage_tile<64>(kg + (size_t)(it+2)*64*DDE, DDE, Ks[it & 1], wave, lane);
            stage_tile<64>(eg + (it+2)*64, TT, Es[it & 1], wave, lane);
        }
    }

    // epilogue: ysumb = bf16(yarb + o)  (each (row,col) owned exactly once)
    #pragma unroll
    for (int nt = 0; nt < 4; ++nt)
        #pragma unroll
        for (int r = 0; r < 4; ++r) {
            const int row = qw0 + quad*4 + r;
            const int col = h*HDD + nt*16 + l15;
            const size_t e = (size_t)(b*TT + row)*DDE + col;
            ysumb[e] = (bf16_t)((float)yarb[e] + o[nt][r]);
        }
}

// ---------------------------------------------------------------------------
extern "C" void kernel_launch(void* const* d_in, const int* in_sizes, int n_in,
                              void* d_out, int out_size, void* d_ws, size_t ws_size,
                              hipStream_t stream)
{
    const float* x      = (const float*)d_in[0];
    const float* w_attn = (const float*)d_in[1];
    const float* b_attn = (const float*)d_in[2];
    const float* w_k2   = (const float*)d_in[3];
    const float* b_k2   = (const float*)d_in[4];
    const float* w_proj = (const float*)d_in[5];
    const float* b_proj = (const float*)d_in[6];

    const size_t NX  = (size_t)BB*TT*DDE;
    const size_t NWA = (size_t)2*DDE*DDE;
    const size_t NW  = (size_t)DDE*DDE;
    const size_t NQK = (size_t)BB*TT*2*DDE;

    bf16_t* xb   = (bf16_t*)d_ws;
    bf16_t* wab  = xb   + NX;
    bf16_t* wkb  = wab  + NWA;
    bf16_t* wpb  = wkb  + NW;
    bf16_t* qkb  = wpb  + NW;
    bf16_t* qab  = qkb  + NQK;
    bf16_t* kcs  = qab  + NX;
    bf16_t* vtg  = kcs  + NX;          // aliased by etg after attn_ar
    bf16_t* ysumb= vtg  + NX;
    bf16_t* yarb = (bf16_t*)((float*)(vtg + NX) + NX);
    bf16_t* etg  = vtg;

    const size_t NCVT = NX + NWA + NW + NW;
    cvt_all<<<NCVT / 1024, 256, 0, stream>>>(x, w_attn, w_k2, w_proj, xb);

    transpose_head<<<dim3(TT/64, NHH, BB), 256, 0, stream>>>(xb, vtg);

    const int M = BB * TT;
    gemm_qkk2<<<dim3(24, M/64), 256, 0, stream>>>(xb, wab, wkb, b_attn, b_k2,
                                                   qkb, qab, kcs);

    attn_ar_mfma<<<dim3(32, NHH, BB), 256, 0, stream>>>(qkb, vtg, yarb);
    build_etg<<<dim3(TT/64, NHH, BB), 256, 0, stream>>>(yarb, xb, etg);
    attn_ma_mfma<<<dim3(32, NHH, BB), 256, 0, stream>>>(qab, kcs, etg, yarb, ysumb);

    gemm_proj<<<dim3(DDE/64, M/64), 256, 0, stream>>>(ysumb, wpb, b_proj,
                                                      (float*)d_out, M, DDE, DDE, 2.f);
}

// Round 8
// 240.060 us; speedup vs baseline: 1.2673x; 1.0011x over previous
//
#include <hip/hip_runtime.h>
#include <hip/hip_bf16.h>
#include <math.h>

#define BB  2
#define TT  2048
#define DDE 1024
#define NHH 16
#define HDD 64

typedef __bf16 bf16_t;
typedef __attribute__((ext_vector_type(8))) __bf16 bf16x8;
typedef __attribute__((ext_vector_type(4))) __bf16 bf16x4;
typedef __attribute__((ext_vector_type(4))) float  f32x4;

#define MFMA(a, b, c) __builtin_amdgcn_mfma_f32_16x16x32_bf16((a), (b), (c), 0, 0, 0)

// counted waits: loads for the NEXT tile stay in flight across barriers (T4)
#define WAIT_VM6()   asm volatile("s_waitcnt vmcnt(6)" ::: "memory")
#define WAIT_VM4()   asm volatile("s_waitcnt vmcnt(4)" ::: "memory")
#define WAIT_VM2()   asm volatile("s_waitcnt vmcnt(2)" ::: "memory")
#define WAIT_VM0()   asm volatile("s_waitcnt vmcnt(0)" ::: "memory")
#define WAIT_LGKM0() asm volatile("s_waitcnt lgkmcnt(0)" ::: "memory")

// raw workgroup barrier (no vmcnt drain), fenced against compiler reordering
__device__ inline void wg_barrier() {
    __builtin_amdgcn_sched_barrier(0);
    __builtin_amdgcn_s_barrier();
    __builtin_amdgcn_sched_barrier(0);
}

// pack 2 f32 -> 1 u32 of 2 bf16 (RNE), no builtin on gfx950
__device__ inline unsigned int cvtpk(float a, float b) {
    unsigned int r;
    asm("v_cvt_pk_bf16_f32 %0, %1, %2" : "=v"(r) : "v"(a), "v"(b));
    return r;
}

// v_permlane16_swap_b32: swaps a's odd 16-lane rows with b's even 16-lane
// rows.  After: a = {a.r0, b.r0, a.r2, b.r2}, b = {a.r1, b.r1, a.r3, b.r3}.
__device__ inline void pl16swap(unsigned int &a, unsigned int &b) {
    asm("v_permlane16_swap_b32 %0, %1" : "+v"(a), "+v"(b));
}

__device__ inline void gll16(const bf16_t* g, unsigned short* l) {
    __builtin_amdgcn_global_load_lds(
        (const __attribute__((address_space(1))) void*)g,
        (__attribute__((address_space(3))) void*)l, 16, 0, 0);
}

// Stage [ROWS x 64] bf16 tile (row stride gstride elems) into LDS via
// global_load_lds, chunk-swizzled: LDS elem [r][ (c ^ (r&7))*8 + j ].
// Per-wave gll16 count: ROWS/(NW*8).
template<int ROWS, int NW = 4>
__device__ inline void stage_tile(const bf16_t* g0, size_t gstride,
                                  unsigned short* lds, int wave, int lane)
{
    const int r8 = lane >> 3;
    const int ck = (lane & 7) ^ r8;
    constexpr int RW = ROWS / NW;
    const bf16_t* g = g0 + (size_t)(wave * RW + r8) * gstride + ck * 8;
    unsigned short* l = lds + wave * RW * 64 + lane * 8;
    #pragma unroll
    for (int i = 0; i < RW / 8; ++i)
        gll16(g + (size_t)(i * 8) * gstride, l + i * 512);
}

// ---------------------------------------------------------------------------
// fused fp32->bf16 conversion of x, w_attn, w_k2, w_proj into the contiguous
// ws region starting at xb.  Segment boundaries are multiples of 1024 elems.
// ---------------------------------------------------------------------------
__global__ __launch_bounds__(256) void cvt_all(
    const float* __restrict__ x, const float* __restrict__ wa,
    const float* __restrict__ wk, const float* __restrict__ wp,
    bf16_t* __restrict__ out)
{
    const size_t NX  = (size_t)BB*TT*DDE;
    const size_t NWA = (size_t)2*DDE*DDE;
    const size_t NW  = (size_t)DDE*DDE;
    const size_t e = ((size_t)blockIdx.x * 256 + threadIdx.x) * 4;
    const float* src;
    if (e < NX)                 src = x  + e;
    else if (e < NX + NWA)      src = wa + (e - NX);
    else if (e < NX + NWA + NW) src = wk + (e - NX - NWA);
    else                        src = wp + (e - NX - NWA - NW);
    float4 v = *(const float4*)src;
    bf16x4 o;
    o[0] = (bf16_t)v.x; o[1] = (bf16_t)v.y;
    o[2] = (bf16_t)v.z; o[3] = (bf16_t)v.w;
    *(bf16x4*)(out + e) = o;
}

// ---------------------------------------------------------------------------
// Per-head 64x64 transpose: dst[bh][d][t] = src[b][t][h*64+d].
// ---------------------------------------------------------------------------
__global__ __launch_bounds__(256) void transpose_head(
    const bf16_t* __restrict__ src, bf16_t* __restrict__ dst)
{
    const int t0 = blockIdx.x * 64, h = blockIdx.y, b = blockIdx.z;
    const int tid = threadIdx.x;
    __shared__ __align__(16) bf16_t tile[64 * 64];

    #pragma unroll
    for (int it = 0; it < 2; ++it) {
        const int t = it * 32 + (tid >> 3);
        const int cw = tid & 7;
        const int slot = (cw + (t >> 3)) & 7;
        bf16x8 v = *(const bf16x8*)(src + (size_t)(b*TT + t0 + t)*DDE + h*HDD + cw*8);
        *(bf16x8*)(tile + t*64 + slot*8) = v;
    }
    __syncthreads();
    const int bh = b * NHH + h;
    #pragma unroll
    for (int it = 0; it < 2; ++it) {
        const int d = it * 32 + (tid >> 3);
        const int co = tid & 7;
        const int slot = ((d >> 3) + co) & 7;
        bf16x8 o;
        #pragma unroll
        for (int j = 0; j < 8; ++j)
            o[j] = tile[(co*8 + j)*64 + slot*8 + (d & 7)];
        *(bf16x8*)(dst + (size_t)(bh*64 + d)*TT + t0 + co*8) = o;
    }
}

// ---------------------------------------------------------------------------
// E-transpose: etg[bh][d][t] = x[t][d] - n[t-1][d]  (0 at t==0),
// where n = yarb (normalized AR output, written by attn_ar).
// ---------------------------------------------------------------------------
__global__ __launch_bounds__(256) void build_etg(
    const bf16_t* __restrict__ yarb, const bf16_t* __restrict__ xb,
    bf16_t* __restrict__ etg)
{
    const int t0 = blockIdx.x * 64, h = blockIdx.y, b = blockIdx.z;
    const int tid = threadIdx.x;
    const int bh = b * NHH + h;
    __shared__ __align__(16) bf16_t tile[64 * 64];

    #pragma unroll
    for (int it = 0; it < 2; ++it) {
        const int t = it * 32 + (tid >> 3);
        const int cw = tid & 7;
        const int slot = (cw + (t >> 3)) & 7;
        const int tg = t0 + t;
        bf16x8 ev;
        if (tg == 0) {
            #pragma unroll
            for (int u = 0; u < 8; ++u) ev[u] = (bf16_t)0.f;
        } else {
            bf16x8 xv = *(const bf16x8*)(xb   + (size_t)(b*TT + tg)*DDE + h*HDD + cw*8);
            bf16x8 nv = *(const bf16x8*)(yarb + (size_t)(b*TT + tg - 1)*DDE + h*HDD + cw*8);
            #pragma unroll
            for (int u = 0; u < 8; ++u)
                ev[u] = (bf16_t)((float)xv[u] - (float)nv[u]);
        }
        *(bf16x8*)(tile + t*64 + slot*8) = ev;
    }
    __syncthreads();
    #pragma unroll
    for (int it = 0; it < 2; ++it) {
        const int d = it * 32 + (tid >> 3);
        const int co = tid & 7;
        const int slot = ((d >> 3) + co) & 7;
        bf16x8 o;
        #pragma unroll
        for (int j = 0; j < 8; ++j)
            o[j] = tile[(co*8 + j)*64 + slot*8 + (d & 7)];
        *(bf16x8*)(etg + (size_t)(bh*64 + d)*TT + t0 + co*8) = o;
    }
}

// ---------------------------------------------------------------------------
// Fused QKV GEMM, BM=64 x BN=128, BK=64, counted-vmcnt dbuf pipeline.
// Region by column tile:
//   [0,1024):  q -> qkb = q*0.125*log2(e) (exp2 domain), qab = leaky(q*0.125)
//   [1024,2048): k -> qkb raw
//   [2048,3072): k2 -> kcs[t+1] = sigmoid(k2*0.0025)-0.5 (shifted, row0=0)
// ---------------------------------------------------------------------------
__global__ __launch_bounds__(256) void gemm_qkk2(
    const bf16_t* __restrict__ A, const bf16_t* __restrict__ wab,
    const bf16_t* __restrict__ wkb, const float* __restrict__ b_attn,
    const float* __restrict__ b_k2, bf16_t* __restrict__ qkb,
    bf16_t* __restrict__ qab, bf16_t* __restrict__ kcs)
{
    __shared__ __align__(16) unsigned short As[2][64 * 64];
    __shared__ __align__(16) unsigned short Bs[2][128 * 64];
    const int tid  = threadIdx.x;
    const int wave = tid >> 6, lane = tid & 63;
    const int l15  = lane & 15, quad = lane >> 4;
    // XCD swizzle (bijective: 1536 = 8*192): each XCD owns 8 contiguous
    // m-rows x all 24 n-tiles; per-k-step slab (A 64KB + B 384KB) L2-fits.
    const int lid = (int)blockIdx.y * 24 + (int)blockIdx.x;
    const int s   = (lid & 7) * 192 + (lid >> 3);
    const int bm = (s / 24) * 64, bn = (s % 24) * 128;
    const int wm = (wave & 1) * 32, wn = (wave >> 1) * 64;
    const int region = bn >> 10;
    const int K = DDE;
    constexpr int NST = DDE / 64;   // 16 K-steps

    const bf16_t* W = (region < 2) ? wab + (size_t)bn * K
                                   : wkb + (size_t)(bn - 2048) * K;
    const float* bp = (region < 2) ? b_attn + bn : b_k2 + (bn - 2048);
    const bf16_t* Ab = A + (size_t)bm * K;

    f32x4 acc[2][4];
    #pragma unroll
    for (int i = 0; i < 2; ++i)
        #pragma unroll
        for (int j = 0; j < 4; ++j) acc[i][j] = (f32x4)0.f;

    // prologue: stage K-steps 0 and 1 (6 gll16/wave each: 2 A + 4 B)
    stage_tile<64>(Ab, K, As[0], wave, lane);
    stage_tile<128>(W,  K, Bs[0], wave, lane);
    stage_tile<64>(Ab + 64, K, As[1], wave, lane);
    stage_tile<128>(W  + 64, K, Bs[1], wave, lane);

    for (int t = 0; t < NST; ++t) {
        // wait tile t landed; tile t+1's 6 loads stay in flight
        if (t + 1 < NST) WAIT_VM6(); else WAIT_VM0();
        wg_barrier();
        const unsigned short* Ac = As[t & 1];
        const unsigned short* Bc = Bs[t & 1];
        bf16x8 af[2][2], bfr[4][2];
        #pragma unroll
        for (int mt = 0; mt < 2; ++mt)
            #pragma unroll
            for (int kh = 0; kh < 2; ++kh)
                af[mt][kh] = *(const bf16x8*)(Ac + (wm + mt*16 + l15)*64
                                              + (((kh*4 + quad) ^ (l15 & 7))*8));
        #pragma unroll
        for (int nt = 0; nt < 4; ++nt)
            #pragma unroll
            for (int kh = 0; kh < 2; ++kh)
                bfr[nt][kh] = *(const bf16x8*)(Bc + (wn + nt*16 + l15)*64
                                               + (((kh*4 + quad) ^ (l15 & 7))*8));
        __builtin_amdgcn_s_setprio(1);
        #pragma unroll
        for (int mt = 0; mt < 2; ++mt)
            #pragma unroll
            for (int nt = 0; nt < 4; ++nt) {
                acc[mt][nt] = MFMA(af[mt][0], bfr[nt][0], acc[mt][nt]);
                acc[mt][nt] = MFMA(af[mt][1], bfr[nt][1], acc[mt][nt]);
            }
        __builtin_amdgcn_s_setprio(0);
        // all waves done reading buf[t&1] before restaging into it
        WAIT_LGKM0();
        wg_barrier();
        if (t + 2 < NST) {
            stage_tile<64>(Ab + (t+2)*64, K, As[t & 1], wave, lane);
            stage_tile<128>(W  + (t+2)*64, K, Bs[t & 1], wave, lane);
        }
    }

    #pragma unroll
    for (int nt = 0; nt < 4; ++nt) {
        const int cl = wn + nt*16 + l15;
        const float bj = bp[cl];
        const int cg = bn + cl;
        #pragma unroll
        for (int mt = 0; mt < 2; ++mt)
            #pragma unroll
            for (int r = 0; r < 4; ++r) {
                const int row = bm + wm + mt*16 + quad*4 + r;
                const float v = acc[mt][nt][r] + bj;
                if (region == 0) {
                    qkb[(size_t)row * (2*DDE) + cg] = (bf16_t)(v * 0.180336880f);
                    const float z = v * 0.125f;
                    qab[(size_t)row * DDE + cg] = (bf16_t)((v > 0.f) ? 0.02f*z : z);
                } else if (region == 1) {
                    qkb[(size_t)row * (2*DDE) + cg] = (bf16_t)v;
                } else {
                    const int c2 = cg - 2048;
                    const float kc = 1.f/(1.f + __expf(-v*0.0025f)) - 0.5f;
                    if (((row + 1) & (TT - 1)) != 0)
                        kcs[(size_t)(row + 1) * DDE + c2] = (bf16_t)kc;
                    if ((row & (TT - 1)) == 0)
                        kcs[(size_t)row * DDE + c2] = (bf16_t)0.f;
                }
            }
    }
}

// ---------------------------------------------------------------------------
// proj GEMM, BM=64 x BN=64, BK=64, counted-vmcnt dbuf (fp32 out):
// C = A W^T + 2*bias.  1024 blocks (4/CU by grid, 5/CU by LDS=32KB).
// ---------------------------------------------------------------------------
__global__ __launch_bounds__(256) void gemm_proj(
    const bf16_t* __restrict__ A, const bf16_t* __restrict__ W,
    const float* __restrict__ bias, float* __restrict__ C,
    int M, int N, int K, float bmul)
{
    __shared__ __align__(16) unsigned short As[2][64 * 64];
    __shared__ __align__(16) unsigned short Bs[2][64 * 64];
    const int tid  = threadIdx.x;
    const int wave = tid >> 6, lane = tid & 63;
    const int l15  = lane & 15, quad = lane >> 4;
    // XCD swizzle (bijective: 1024 = 8*128)
    const int lid = (int)blockIdx.y * 16 + (int)blockIdx.x;
    const int s   = (lid & 7) * 128 + (lid >> 3);
    const int bm = (s / 16) * 64, bn = (s % 16) * 64;
    const int wm = (wave & 1) * 32, wn = (wave >> 1) * 32;

    const bf16_t* Ab = A + (size_t)bm * K;
    const bf16_t* Wb = W + (size_t)bn * K;
    const int NST = K / 64;

    f32x4 acc[2][2];
    #pragma unroll
    for (int i = 0; i < 2; ++i)
        #pragma unroll
        for (int j = 0; j < 2; ++j) acc[i][j] = (f32x4)0.f;

    stage_tile<64>(Ab, K, As[0], wave, lane);
    stage_tile<64>(Wb, K, Bs[0], wave, lane);
    stage_tile<64>(Ab + 64, K, As[1], wave, lane);
    stage_tile<64>(Wb + 64, K, Bs[1], wave, lane);

    for (int t = 0; t < NST; ++t) {
        if (t + 1 < NST) WAIT_VM4(); else WAIT_VM0();
        wg_barrier();
        const unsigned short* Ac = As[t & 1];
        const unsigned short* Bc = Bs[t & 1];
        bf16x8 af[2][2], bfr[2][2];
        #pragma unroll
        for (int mt = 0; mt < 2; ++mt)
            #pragma unroll
            for (int kh = 0; kh < 2; ++kh)
                af[mt][kh] = *(const bf16x8*)(Ac + (wm + mt*16 + l15)*64
                                              + (((kh*4 + quad) ^ (l15 & 7))*8));
        #pragma unroll
        for (int nt = 0; nt < 2; ++nt)
            #pragma unroll
            for (int kh = 0; kh < 2; ++kh)
                bfr[nt][kh] = *(const bf16x8*)(Bc + (wn + nt*16 + l15)*64
                                               + (((kh*4 + quad) ^ (l15 & 7))*8));
        __builtin_amdgcn_s_setprio(1);
        #pragma unroll
        for (int mt = 0; mt < 2; ++mt)
            #pragma unroll
            for (int nt = 0; nt < 2; ++nt) {
                acc[mt][nt] = MFMA(af[mt][0], bfr[nt][0], acc[mt][nt]);
                acc[mt][nt] = MFMA(af[mt][1], bfr[nt][1], acc[mt][nt]);
            }
        __builtin_amdgcn_s_setprio(0);
        WAIT_LGKM0();
        wg_barrier();
        if (t + 2 < NST) {
            stage_tile<64>(Ab + (t+2)*64, K, As[t & 1], wave, lane);
            stage_tile<64>(Wb + (t+2)*64, K, Bs[t & 1], wave, lane);
        }
    }

    #pragma unroll
    for (int nt = 0; nt < 2; ++nt) {
        const int col = bn + wn + nt*16 + l15;
        const float bj = bias[col] * bmul;
        #pragma unroll
        for (int mt = 0; mt < 2; ++mt)
            #pragma unroll
            for (int r = 0; r < 4; ++r) {
                const int row = bm + wm + mt*16 + quad*4 + r;
                C[(size_t)row * N + col] = acc[mt][nt][r] + bj;
            }
    }
}

// ---------------------------------------------------------------------------
// AR: fixed-max flash attention.  512-thread blocks; each block owns the
// complementary q-tile pair (p, 31-p): waves 0-3 -> qtL rows, waves 4-7 ->
// qtH rows (constant 132 chain-tiles per block -> no tail imbalance).
// One shared 32KB K/V double-buffer; Q fragments load global->reg directly.
// Counted-vmcnt (2 loads/wave/tile); swapped QK^T; permlane16 P repack;
// denominators via ones-MFMA.  Epilogue normalizes, stores yarb (bf16).
// ---------------------------------------------------------------------------
__global__ __launch_bounds__(512) void attn_ar_mfma(
    const bf16_t* __restrict__ qkb, const bf16_t* __restrict__ vtg,
    bf16_t* __restrict__ yarb)
{
    const int h = blockIdx.y, b = blockIdx.z;
    const int p = b ? (15 - (int)blockIdx.x) : (int)blockIdx.x;  // co-CU hedge
    const int qtL = p, qtH = 31 - p;
    const int tid = threadIdx.x, wave = tid >> 6, lane = tid & 63;
    const int l15 = lane & 15, quad = lane >> 4;
    const int qt = (wave < 4) ? qtL : qtH;
    const int qw0 = qt * 64 + (wave & 3) * 16;
    const int bh = b * NHH + h;

    __shared__ __align__(16) unsigned short Ks[2][64 * 64];
    __shared__ __align__(16) unsigned short Vs[2][64 * 64];

    const int nit = qtH + 1;   // kv tiles 0 .. qtH  (>= 17 always)

    const bf16_t* kg = qkb + (size_t)(b*TT)*(2*DDE) + DDE + h*HDD;
    const bf16_t* vg = vtg + (size_t)(bh*64)*TT;

    // Q fragments: direct global->reg (LDS-read XOR cancels staging swizzle,
    // so the global address is just row, chunk*8).  16B x2 per lane.
    const bf16_t* qrow = qkb + (size_t)(b*TT + qw0 + l15)*(2*DDE) + h*HDD;
    bf16x8 qf[2];
    qf[0] = *(const bf16x8*)(qrow + quad*8);
    qf[1] = *(const bf16x8*)(qrow + (quad + 4)*8);

    // prologue: tiles 0,1 (2 gll16/wave each: 1 K + 1 V)
    stage_tile<64, 8>(kg, 2*DDE, Ks[0], wave, lane);
    stage_tile<64, 8>(vg, TT, Vs[0], wave, lane);
    stage_tile<64, 8>(kg + (size_t)64*(2*DDE), 2*DDE, Ks[1], wave, lane);
    stage_tile<64, 8>(vg + 64, TT, Vs[1], wave, lane);
    WAIT_VM2();            // Q + tile0 done, tile1 in flight
    wg_barrier();

    f32x4 o[4];
    f32x4 ls = (f32x4)0.f;        // softmax denominators (C-layout rows)
    #pragma unroll
    for (int nt = 0; nt < 4; ++nt) o[nt] = (f32x4)0.f;
    bf16x8 onesb;
    #pragma unroll
    for (int j = 0; j < 8; ++j) onesb[j] = (bf16_t)1.f;

    // after permlane repack, quad q holds key-chunk cq = bitswap(q)
    const int cq = ((quad & 1) << 1) | (quad >> 1);

    for (int it = 0; it < nit; ++it) {
        if (it > 0) {
            if (it + 1 < nit) WAIT_VM2(); else WAIT_VM0();
            wg_barrier();
        }
        const int s0 = it * 64;
        const unsigned short* Kc = Ks[it & 1];
        const unsigned short* Vc = Vs[it & 1];

        if (s0 <= qw0 + 31) {      // wave active within its causal extent
            // swapped QK: sv holds S^T — key = nt*16+quad*4+r, query = l15
            f32x4 sv[4];
            __builtin_amdgcn_s_setprio(1);
            #pragma unroll
            for (int nt = 0; nt < 4; ++nt) {
                const unsigned short* kr = Kc + (nt*16 + l15)*64;
                bf16x8 kb0 = *(const bf16x8*)(kr + ((quad    ) ^ (l15 & 7))*8);
                bf16x8 kb1 = *(const bf16x8*)(kr + ((quad + 4) ^ (l15 & 7))*8);
                f32x4 z = (f32x4)0.f;
                z = MFMA(kb0, qf[0], z);
                z = MFMA(kb1, qf[1], z);
                sv[nt] = z;
            }
            __builtin_amdgcn_s_setprio(0);

            const bool domask = (s0 + 63 > qw0);
            const int qg = qw0 + l15;
            unsigned int pk[4][2];
            #pragma unroll
            for (int nt = 0; nt < 4; ++nt) {
                float pv[4];
                #pragma unroll
                for (int r = 0; r < 4; ++r) {
                    float pe = exp2f(sv[nt][r]);
                    if (domask) {
                        const int sg = s0 + nt*16 + quad*4 + r;
                        if (sg > qg) pe = 0.f;
                    }
                    pv[r] = pe;
                }
                pk[nt][0] = cvtpk(pv[0], pv[1]);
                pk[nt][1] = cvtpk(pv[2], pv[3]);
            }
            // repack S^T (C-layout) -> PV A-fragment with 4 permlane16_swap
            bf16x8 pa[2];
            #pragma unroll
            for (int sc = 0; sc < 2; ++sc) {
                pl16swap(pk[2*sc][0], pk[2*sc+1][0]);
                pl16swap(pk[2*sc][1], pk[2*sc+1][1]);
                union { unsigned int u[4]; bf16x8 v; } pu;
                pu.u[0] = pk[2*sc][0];
                pu.u[1] = pk[2*sc][1];
                pu.u[2] = pk[2*sc+1][0];
                pu.u[3] = pk[2*sc+1][1];
                pa[sc] = pu.v;
            }

            __builtin_amdgcn_s_setprio(1);
            // denominators: rowsum via ones-B MFMA (same lane/reg as o)
            ls = MFMA(pa[0], onesb, ls);
            ls = MFMA(pa[1], onesb, ls);
            #pragma unroll
            for (int nt = 0; nt < 4; ++nt) {
                const unsigned short* vr = Vc + (nt*16 + l15)*64;
                bf16x8 vb0 = *(const bf16x8*)(vr + ((cq    ) ^ (l15 & 7))*8);
                bf16x8 vb1 = *(const bf16x8*)(vr + ((cq + 4) ^ (l15 & 7))*8);
                o[nt] = MFMA(pa[0], vb0, o[nt]);
                o[nt] = MFMA(pa[1], vb1, o[nt]);
            }
            __builtin_amdgcn_s_setprio(0);
        }
        WAIT_LGKM0();
        wg_barrier();
        if (it + 2 < nit) {
            stage_tile<64, 8>(kg + (size_t)(it+2)*64*(2*DDE), 2*DDE, Ks[it & 1], wave, lane);
            stage_tile<64, 8>(vg + (it+2)*64, TT, Vs[it & 1], wave, lane);
        }
    }

    // epilogue: normalize and store bf16 (ls[r] pairs with o[nt][r] directly)
    float inv[4];
    #pragma unroll
    for (int r = 0; r < 4; ++r) inv[r] = 1.f / ls[r];
    #pragma unroll
    for (int nt = 0; nt < 4; ++nt)
        #pragma unroll
        for (int r = 0; r < 4; ++r) {
            const int row = qw0 + quad*4 + r;
            const int col = h*HDD + nt*16 + l15;
            yarb[(size_t)(b*TT + row)*DDE + col] = (bf16_t)(o[nt][r] * inv[r]);
        }
}

// ---------------------------------------------------------------------------
// MA: linear causal attention, same paired-512-thread structure.
// Q row-sum in-register; fused combine epilogue: ysumb = bf16(yarb + o).
// ---------------------------------------------------------------------------
__global__ __launch_bounds__(512) void attn_ma_mfma(
    const bf16_t* __restrict__ qab, const bf16_t* __restrict__ kcs,
    const bf16_t* __restrict__ etg, const bf16_t* __restrict__ yarb,
    bf16_t* __restrict__ ysumb)
{
    const int h = blockIdx.y, b = blockIdx.z;
    const int p = b ? (15 - (int)blockIdx.x) : (int)blockIdx.x;
    const int qtL = p, qtH = 31 - p;
    const int tid = threadIdx.x, wave = tid >> 6, lane = tid & 63;
    const int l15 = lane & 15, quad = lane >> 4;
    const int qt = (wave < 4) ? qtL : qtH;
    const int qw0 = qt * 64 + (wave & 3) * 16;
    const int bh = b * NHH + h;

    __shared__ __align__(16) unsigned short Ks[2][64 * 64];
    __shared__ __align__(16) unsigned short Es[2][64 * 64];

    const int nit = qtH + 1;

    const bf16_t* kg = kcs + (size_t)(b*TT)*DDE + h*HDD;
    const bf16_t* eg = etg + (size_t)(bh*64)*TT;

    const bf16_t* qrow = qab + (size_t)(b*TT + qw0 + l15)*DDE + h*HDD;
    bf16x8 qf[2];
    qf[0] = *(const bf16x8*)(qrow + quad*8);
    qf[1] = *(const bf16x8*)(qrow + (quad + 4)*8);

    stage_tile<64, 8>(kg, DDE, Ks[0], wave, lane);
    stage_tile<64, 8>(eg, TT, Es[0], wave, lane);
    stage_tile<64, 8>(kg + (size_t)64*DDE, DDE, Ks[1], wave, lane);
    stage_tile<64, 8>(eg + 64, TT, Es[1], wave, lane);
    WAIT_VM2();
    wg_barrier();

    // Q row-sum (64 cols) in-register: lane holds 16 elems; quad butterfly.
    float rs = 0.f;
    #pragma unroll
    for (int kc = 0; kc < 2; ++kc)
        #pragma unroll
        for (int u = 0; u < 8; ++u) rs += (float)qf[kc][u];
    rs += __shfl_xor(rs, 16);
    rs += __shfl_xor(rs, 32);
    const float Rr = 0.5f * rs;     // row-sum for query row l15 (all quads)

    f32x4 o[4];
    #pragma unroll
    for (int nt = 0; nt < 4; ++nt) o[nt] = (f32x4)0.f;

    const int cq = ((quad & 1) << 1) | (quad >> 1);

    for (int it = 0; it < nit; ++it) {
        if (it > 0) {
            if (it + 1 < nit) WAIT_VM2(); else WAIT_VM0();
            wg_barrier();
        }
        const int s0 = it * 64;
        const unsigned short* Kc = Ks[it & 1];
        const unsigned short* Ec = Es[it & 1];

        if (s0 <= qw0 + 31) {
            f32x4 sv[4];
            __builtin_amdgcn_s_setprio(1);
            #pragma unroll
            for (int nt = 0; nt < 4; ++nt) {
                const unsigned short* kr = Kc + (nt*16 + l15)*64;
                bf16x8 kb0 = *(const bf16x8*)(kr + ((quad    ) ^ (l15 & 7))*8);
                bf16x8 kb1 = *(const bf16x8*)(kr + ((quad + 4) ^ (l15 & 7))*8);
                f32x4 z = (f32x4)0.f;
                z = MFMA(kb0, qf[0], z);
                z = MFMA(kb1, qf[1], z);
                sv[nt] = z;
            }
            __builtin_amdgcn_s_setprio(0);

            const bool domask = (s0 + 63 > qw0);
            const bool m0 = (it == 0);
            const int qg = qw0 + l15;
            unsigned int pk[4][2];
            #pragma unroll
            for (int nt = 0; nt < 4; ++nt) {
                float pv[4];
                #pragma unroll
                for (int r = 0; r < 4; ++r) {
                    const int sg = s0 + nt*16 + quad*4 + r;
                    float pe = sv[nt][r] + Rr;
                    if (m0 && sg == 0) pe = 0.f;
                    if (domask && sg > qg) pe = 0.f;
                    pv[r] = pe;
                }
                pk[nt][0] = cvtpk(pv[0], pv[1]);
                pk[nt][1] = cvtpk(pv[2], pv[3]);
            }
            bf16x8 pa[2];
            #pragma unroll
            for (int sc = 0; sc < 2; ++sc) {
                pl16swap(pk[2*sc][0], pk[2*sc+1][0]);
                pl16swap(pk[2*sc][1], pk[2*sc+1][1]);
                union { unsigned int u[4]; bf16x8 v; } pu;
                pu.u[0] = pk[2*sc][0];
                pu.u[1] = pk[2*sc][1];
                pu.u[2] = pk[2*sc+1][0];
                pu.u[3] = pk[2*sc+1][1];
                pa[sc] = pu.v;
            }

            __builtin_amdgcn_s_setprio(1);
            #pragma unroll
            for (int nt = 0; nt < 4; ++nt) {
                const unsigned short* er = Ec + (nt*16 + l15)*64;
                bf16x8 eb0 = *(const bf16x8*)(er + ((cq    ) ^ (l15 & 7))*8);
                bf16x8 eb1 = *(const bf16x8*)(er + ((cq + 4) ^ (l15 & 7))*8);
                o[nt] = MFMA(pa[0], eb0, o[nt]);
                o[nt] = MFMA(pa[1], eb1, o[nt]);
            }
            __builtin_amdgcn_s_setprio(0);
        }
        WAIT_LGKM0();
        wg_barrier();
        if (it + 2 < nit) {
            stage_tile<64, 8>(kg + (size_t)(it+2)*64*DDE, DDE, Ks[it & 1], wave, lane);
            stage_tile<64, 8>(eg + (it+2)*64, TT, Es[it & 1], wave, lane);
        }
    }

    // epilogue: ysumb = bf16(yarb + o)  (each (row,col) owned exactly once)
    #pragma unroll
    for (int nt = 0; nt < 4; ++nt)
        #pragma unroll
        for (int r = 0; r < 4; ++r) {
            const int row = qw0 + quad*4 + r;
            const int col = h*HDD + nt*16 + l15;
            const size_t e = (size_t)(b*TT + row)*DDE + col;
            ysumb[e] = (bf16_t)((float)yarb[e] + o[nt][r]);
        }
}

// ---------------------------------------------------------------------------
extern "C" void kernel_launch(void* const* d_in, const int* in_sizes, int n_in,
                              void* d_out, int out_size, void* d_ws, size_t ws_size,
                              hipStream_t stream)
{
    const float* x      = (const float*)d_in[0];
    const float* w_attn = (const float*)d_in[1];
    const float* b_attn = (const float*)d_in[2];
    const float* w_k2   = (const float*)d_in[3];
    const float* b_k2   = (const float*)d_in[4];
    const float* w_proj = (const float*)d_in[5];
    const float* b_proj = (const float*)d_in[6];

    const size_t NX  = (size_t)BB*TT*DDE;
    const size_t NWA = (size_t)2*DDE*DDE;
    const size_t NW  = (size_t)DDE*DDE;
    const size_t NQK = (size_t)BB*TT*2*DDE;

    bf16_t* xb   = (bf16_t*)d_ws;
    bf16_t* wab  = xb   + NX;
    bf16_t* wkb  = wab  + NWA;
    bf16_t* wpb  = wkb  + NW;
    bf16_t* qkb  = wpb  + NW;
    bf16_t* qab  = qkb  + NQK;
    bf16_t* kcs  = qab  + NX;
    bf16_t* vtg  = kcs  + NX;          // aliased by etg after attn_ar
    bf16_t* ysumb= vtg  + NX;
    bf16_t* yarb = (bf16_t*)((float*)(vtg + NX) + NX);
    bf16_t* etg  = vtg;

    const size_t NCVT = NX + NWA + NW + NW;
    cvt_all<<<NCVT / 1024, 256, 0, stream>>>(x, w_attn, w_k2, w_proj, xb);

    transpose_head<<<dim3(TT/64, NHH, BB), 256, 0, stream>>>(xb, vtg);

    const int M = BB * TT;
    gemm_qkk2<<<dim3(24, M/64), 256, 0, stream>>>(xb, wab, wkb, b_attn, b_k2,
                                                   qkb, qab, kcs);

    attn_ar_mfma<<<dim3(16, NHH, BB), 512, 0, stream>>>(qkb, vtg, yarb);
    build_etg<<<dim3(TT/64, NHH, BB), 256, 0, stream>>>(yarb, xb, etg);
    attn_ma_mfma<<<dim3(16, NHH, BB), 512, 0, stream>>>(qab, kcs, etg, yarb, ysumb);

    gemm_proj<<<dim3(DDE/64, M/64), 256, 0, stream>>>(ysumb, wpb, b_proj,
                                                      (float*)d_out, M, DDE, DDE, 2.f);
}

// Round 9
// 229.280 us; speedup vs baseline: 1.3269x; 1.0470x over previous
//
#include <hip/hip_runtime.h>
#include <hip/hip_bf16.h>
#include <math.h>

#define BB  2
#define TT  2048
#define DDE 1024
#define NHH 16
#define HDD 64

typedef __bf16 bf16_t;
typedef __attribute__((ext_vector_type(8))) __bf16 bf16x8;
typedef __attribute__((ext_vector_type(4))) __bf16 bf16x4;
typedef __attribute__((ext_vector_type(4))) float  f32x4;

#define MFMA(a, b, c) __builtin_amdgcn_mfma_f32_16x16x32_bf16((a), (b), (c), 0, 0, 0)

// counted waits: loads for the NEXT tile stay in flight across barriers (T4)
#define WAIT_VM6()   asm volatile("s_waitcnt vmcnt(6)" ::: "memory")
#define WAIT_VM4()   asm volatile("s_waitcnt vmcnt(4)" ::: "memory")
#define WAIT_VM0()   asm volatile("s_waitcnt vmcnt(0)" ::: "memory")
#define WAIT_LGKM0() asm volatile("s_waitcnt lgkmcnt(0)" ::: "memory")

// raw workgroup barrier (no vmcnt drain), fenced against compiler reordering
__device__ inline void wg_barrier() {
    __builtin_amdgcn_sched_barrier(0);
    __builtin_amdgcn_s_barrier();
    __builtin_amdgcn_sched_barrier(0);
}

// pack 2 f32 -> 1 u32 of 2 bf16 (RNE), no builtin on gfx950
__device__ inline unsigned int cvtpk(float a, float b) {
    unsigned int r;
    asm("v_cvt_pk_bf16_f32 %0, %1, %2" : "=v"(r) : "v"(a), "v"(b));
    return r;
}

// single-instruction 2^x (exp2f without fast-math lowers to the precise
// multi-instruction __ocml path; v_exp_f32 IS exact 2^x, denormals flush->0
// which is exactly what softmax wants for very negative scores)
__device__ inline float fexp2(float x) {
    float r;
    asm("v_exp_f32 %0, %1" : "=v"(r) : "v"(x));
    return r;
}

// v_permlane16_swap_b32: swaps a's odd 16-lane rows with b's even 16-lane
// rows.  After: a = {a.r0, b.r0, a.r2, b.r2}, b = {a.r1, b.r1, a.r3, b.r3}.
__device__ inline void pl16swap(unsigned int &a, unsigned int &b) {
    asm("v_permlane16_swap_b32 %0, %1" : "+v"(a), "+v"(b));
}

__device__ inline void gll16(const bf16_t* g, unsigned short* l) {
    __builtin_amdgcn_global_load_lds(
        (const __attribute__((address_space(1))) void*)g,
        (__attribute__((address_space(3))) void*)l, 16, 0, 0);
}

// Stage [ROWS x 64] bf16 tile (row stride gstride elems) into LDS via
// global_load_lds, chunk-swizzled: LDS elem [r][ (c ^ (r&7))*8 + j ].
// Per-wave gll16 count: ROWS/(NW*8).
template<int ROWS, int NW = 4>
__device__ inline void stage_tile(const bf16_t* g0, size_t gstride,
                                  unsigned short* lds, int wave, int lane)
{
    const int r8 = lane >> 3;
    const int ck = (lane & 7) ^ r8;
    constexpr int RW = ROWS / NW;
    const bf16_t* g = g0 + (size_t)(wave * RW + r8) * gstride + ck * 8;
    unsigned short* l = lds + wave * RW * 64 + lane * 8;
    #pragma unroll
    for (int i = 0; i < RW / 8; ++i)
        gll16(g + (size_t)(i * 8) * gstride, l + i * 512);
}

// ---------------------------------------------------------------------------
// fused fp32->bf16 conversion of x, w_attn, w_k2, w_proj into the contiguous
// ws region starting at xb.  Segment boundaries are multiples of 1024 elems.
// ---------------------------------------------------------------------------
__global__ __launch_bounds__(256) void cvt_all(
    const float* __restrict__ x, const float* __restrict__ wa,
    const float* __restrict__ wk, const float* __restrict__ wp,
    bf16_t* __restrict__ out)
{
    const size_t NX  = (size_t)BB*TT*DDE;
    const size_t NWA = (size_t)2*DDE*DDE;
    const size_t NW  = (size_t)DDE*DDE;
    const size_t e = ((size_t)blockIdx.x * 256 + threadIdx.x) * 4;
    const float* src;
    if (e < NX)                 src = x  + e;
    else if (e < NX + NWA)      src = wa + (e - NX);
    else if (e < NX + NWA + NW) src = wk + (e - NX - NWA);
    else                        src = wp + (e - NX - NWA - NW);
    float4 v = *(const float4*)src;
    bf16x4 o;
    o[0] = (bf16_t)v.x; o[1] = (bf16_t)v.y;
    o[2] = (bf16_t)v.z; o[3] = (bf16_t)v.w;
    *(bf16x4*)(out + e) = o;
}

// ---------------------------------------------------------------------------
// Per-head 64x64 transpose: dst[bh][d][t] = src[b][t][h*64+d].
// ---------------------------------------------------------------------------
__global__ __launch_bounds__(256) void transpose_head(
    const bf16_t* __restrict__ src, bf16_t* __restrict__ dst)
{
    const int t0 = blockIdx.x * 64, h = blockIdx.y, b = blockIdx.z;
    const int tid = threadIdx.x;
    __shared__ __align__(16) bf16_t tile[64 * 64];

    #pragma unroll
    for (int it = 0; it < 2; ++it) {
        const int t = it * 32 + (tid >> 3);
        const int cw = tid & 7;
        const int slot = (cw + (t >> 3)) & 7;
        bf16x8 v = *(const bf16x8*)(src + (size_t)(b*TT + t0 + t)*DDE + h*HDD + cw*8);
        *(bf16x8*)(tile + t*64 + slot*8) = v;
    }
    __syncthreads();
    const int bh = b * NHH + h;
    #pragma unroll
    for (int it = 0; it < 2; ++it) {
        const int d = it * 32 + (tid >> 3);
        const int co = tid & 7;
        const int slot = ((d >> 3) + co) & 7;
        bf16x8 o;
        #pragma unroll
        for (int j = 0; j < 8; ++j)
            o[j] = tile[(co*8 + j)*64 + slot*8 + (d & 7)];
        *(bf16x8*)(dst + (size_t)(bh*64 + d)*TT + t0 + co*8) = o;
    }
}

// ---------------------------------------------------------------------------
// E-transpose: etg[bh][d][t] = x[t][d] - n[t-1][d]  (0 at t==0),
// where n = yarb (normalized AR output, written by attn_ar).
// ---------------------------------------------------------------------------
__global__ __launch_bounds__(256) void build_etg(
    const bf16_t* __restrict__ yarb, const bf16_t* __restrict__ xb,
    bf16_t* __restrict__ etg)
{
    const int t0 = blockIdx.x * 64, h = blockIdx.y, b = blockIdx.z;
    const int tid = threadIdx.x;
    const int bh = b * NHH + h;
    __shared__ __align__(16) bf16_t tile[64 * 64];

    #pragma unroll
    for (int it = 0; it < 2; ++it) {
        const int t = it * 32 + (tid >> 3);
        const int cw = tid & 7;
        const int slot = (cw + (t >> 3)) & 7;
        const int tg = t0 + t;
        bf16x8 ev;
        if (tg == 0) {
            #pragma unroll
            for (int u = 0; u < 8; ++u) ev[u] = (bf16_t)0.f;
        } else {
            bf16x8 xv = *(const bf16x8*)(xb   + (size_t)(b*TT + tg)*DDE + h*HDD + cw*8);
            bf16x8 nv = *(const bf16x8*)(yarb + (size_t)(b*TT + tg - 1)*DDE + h*HDD + cw*8);
            #pragma unroll
            for (int u = 0; u < 8; ++u)
                ev[u] = (bf16_t)((float)xv[u] - (float)nv[u]);
        }
        *(bf16x8*)(tile + t*64 + slot*8) = ev;
    }
    __syncthreads();
    #pragma unroll
    for (int it = 0; it < 2; ++it) {
        const int d = it * 32 + (tid >> 3);
        const int co = tid & 7;
        const int slot = ((d >> 3) + co) & 7;
        bf16x8 o;
        #pragma unroll
        for (int j = 0; j < 8; ++j)
            o[j] = tile[(co*8 + j)*64 + slot*8 + (d & 7)];
        *(bf16x8*)(etg + (size_t)(bh*64 + d)*TT + t0 + co*8) = o;
    }
}

// ---------------------------------------------------------------------------
// Fused QKV GEMM, BM=64 x BN=128, BK=64, counted-vmcnt dbuf pipeline.
// Region by column tile:
//   [0,1024):  q -> qkb = q*0.125*log2(e) (exp2 domain), qab = leaky(q*0.125)
//   [1024,2048): k -> qkb raw
//   [2048,3072): k2 -> kcs[t+1] = sigmoid(k2*0.0025)-0.5 (shifted, row0=0)
// ---------------------------------------------------------------------------
__global__ __launch_bounds__(256) void gemm_qkk2(
    const bf16_t* __restrict__ A, const bf16_t* __restrict__ wab,
    const bf16_t* __restrict__ wkb, const float* __restrict__ b_attn,
    const float* __restrict__ b_k2, bf16_t* __restrict__ qkb,
    bf16_t* __restrict__ qab, bf16_t* __restrict__ kcs)
{
    __shared__ __align__(16) unsigned short As[2][64 * 64];
    __shared__ __align__(16) unsigned short Bs[2][128 * 64];
    const int tid  = threadIdx.x;
    const int wave = tid >> 6, lane = tid & 63;
    const int l15  = lane & 15, quad = lane >> 4;
    // XCD swizzle (bijective: 1536 = 8*192): each XCD owns 8 contiguous
    // m-rows x all 24 n-tiles; per-k-step slab (A 64KB + B 384KB) L2-fits.
    const int lid = (int)blockIdx.y * 24 + (int)blockIdx.x;
    const int s   = (lid & 7) * 192 + (lid >> 3);
    const int bm = (s / 24) * 64, bn = (s % 24) * 128;
    const int wm = (wave & 1) * 32, wn = (wave >> 1) * 64;
    const int region = bn >> 10;
    const int K = DDE;
    constexpr int NST = DDE / 64;   // 16 K-steps

    const bf16_t* W = (region < 2) ? wab + (size_t)bn * K
                                   : wkb + (size_t)(bn - 2048) * K;
    const float* bp = (region < 2) ? b_attn + bn : b_k2 + (bn - 2048);
    const bf16_t* Ab = A + (size_t)bm * K;

    f32x4 acc[2][4];
    #pragma unroll
    for (int i = 0; i < 2; ++i)
        #pragma unroll
        for (int j = 0; j < 4; ++j) acc[i][j] = (f32x4)0.f;

    // prologue: stage K-steps 0 and 1 (6 gll16/wave each: 2 A + 4 B)
    stage_tile<64>(Ab, K, As[0], wave, lane);
    stage_tile<128>(W,  K, Bs[0], wave, lane);
    stage_tile<64>(Ab + 64, K, As[1], wave, lane);
    stage_tile<128>(W  + 64, K, Bs[1], wave, lane);

    for (int t = 0; t < NST; ++t) {
        // wait tile t landed; tile t+1's 6 loads stay in flight
        if (t + 1 < NST) WAIT_VM6(); else WAIT_VM0();
        wg_barrier();
        const unsigned short* Ac = As[t & 1];
        const unsigned short* Bc = Bs[t & 1];
        bf16x8 af[2][2], bfr[4][2];
        #pragma unroll
        for (int mt = 0; mt < 2; ++mt)
            #pragma unroll
            for (int kh = 0; kh < 2; ++kh)
                af[mt][kh] = *(const bf16x8*)(Ac + (wm + mt*16 + l15)*64
                                              + (((kh*4 + quad) ^ (l15 & 7))*8));
        #pragma unroll
        for (int nt = 0; nt < 4; ++nt)
            #pragma unroll
            for (int kh = 0; kh < 2; ++kh)
                bfr[nt][kh] = *(const bf16x8*)(Bc + (wn + nt*16 + l15)*64
                                               + (((kh*4 + quad) ^ (l15 & 7))*8));
        __builtin_amdgcn_s_setprio(1);
        #pragma unroll
        for (int mt = 0; mt < 2; ++mt)
            #pragma unroll
            for (int nt = 0; nt < 4; ++nt) {
                acc[mt][nt] = MFMA(af[mt][0], bfr[nt][0], acc[mt][nt]);
                acc[mt][nt] = MFMA(af[mt][1], bfr[nt][1], acc[mt][nt]);
            }
        __builtin_amdgcn_s_setprio(0);
        // all waves done reading buf[t&1] before restaging into it
        WAIT_LGKM0();
        wg_barrier();
        if (t + 2 < NST) {
            stage_tile<64>(Ab + (t+2)*64, K, As[t & 1], wave, lane);
            stage_tile<128>(W  + (t+2)*64, K, Bs[t & 1], wave, lane);
        }
    }

    #pragma unroll
    for (int nt = 0; nt < 4; ++nt) {
        const int cl = wn + nt*16 + l15;
        const float bj = bp[cl];
        const int cg = bn + cl;
        #pragma unroll
        for (int mt = 0; mt < 2; ++mt)
            #pragma unroll
            for (int r = 0; r < 4; ++r) {
                const int row = bm + wm + mt*16 + quad*4 + r;
                const float v = acc[mt][nt][r] + bj;
                if (region == 0) {
                    qkb[(size_t)row * (2*DDE) + cg] = (bf16_t)(v * 0.180336880f);
                    const float z = v * 0.125f;
                    qab[(size_t)row * DDE + cg] = (bf16_t)((v > 0.f) ? 0.02f*z : z);
                } else if (region == 1) {
                    qkb[(size_t)row * (2*DDE) + cg] = (bf16_t)v;
                } else {
                    const int c2 = cg - 2048;
                    const float kc = 1.f/(1.f + __expf(-v*0.0025f)) - 0.5f;
                    if (((row + 1) & (TT - 1)) != 0)
                        kcs[(size_t)(row + 1) * DDE + c2] = (bf16_t)kc;
                    if ((row & (TT - 1)) == 0)
                        kcs[(size_t)row * DDE + c2] = (bf16_t)0.f;
                }
            }
    }
}

// ---------------------------------------------------------------------------
// proj GEMM, BM=64 x BN=64, BK=64, counted-vmcnt dbuf (fp32 out):
// C = A W^T + 2*bias.  1024 blocks (4/CU by grid, 5/CU by LDS=32KB).
// ---------------------------------------------------------------------------
__global__ __launch_bounds__(256) void gemm_proj(
    const bf16_t* __restrict__ A, const bf16_t* __restrict__ W,
    const float* __restrict__ bias, float* __restrict__ C,
    int M, int N, int K, float bmul)
{
    __shared__ __align__(16) unsigned short As[2][64 * 64];
    __shared__ __align__(16) unsigned short Bs[2][64 * 64];
    const int tid  = threadIdx.x;
    const int wave = tid >> 6, lane = tid & 63;
    const int l15  = lane & 15, quad = lane >> 4;
    // XCD swizzle (bijective: 1024 = 8*128)
    const int lid = (int)blockIdx.y * 16 + (int)blockIdx.x;
    const int s   = (lid & 7) * 128 + (lid >> 3);
    const int bm = (s / 16) * 64, bn = (s % 16) * 64;
    const int wm = (wave & 1) * 32, wn = (wave >> 1) * 32;

    const bf16_t* Ab = A + (size_t)bm * K;
    const bf16_t* Wb = W + (size_t)bn * K;
    const int NST = K / 64;

    f32x4 acc[2][2];
    #pragma unroll
    for (int i = 0; i < 2; ++i)
        #pragma unroll
        for (int j = 0; j < 2; ++j) acc[i][j] = (f32x4)0.f;

    stage_tile<64>(Ab, K, As[0], wave, lane);
    stage_tile<64>(Wb, K, Bs[0], wave, lane);
    stage_tile<64>(Ab + 64, K, As[1], wave, lane);
    stage_tile<64>(Wb + 64, K, Bs[1], wave, lane);

    for (int t = 0; t < NST; ++t) {
        if (t + 1 < NST) WAIT_VM4(); else WAIT_VM0();
        wg_barrier();
        const unsigned short* Ac = As[t & 1];
        const unsigned short* Bc = Bs[t & 1];
        bf16x8 af[2][2], bfr[2][2];
        #pragma unroll
        for (int mt = 0; mt < 2; ++mt)
            #pragma unroll
            for (int kh = 0; kh < 2; ++kh)
                af[mt][kh] = *(const bf16x8*)(Ac + (wm + mt*16 + l15)*64
                                              + (((kh*4 + quad) ^ (l15 & 7))*8));
        #pragma unroll
        for (int nt = 0; nt < 2; ++nt)
            #pragma unroll
            for (int kh = 0; kh < 2; ++kh)
                bfr[nt][kh] = *(const bf16x8*)(Bc + (wn + nt*16 + l15)*64
                                               + (((kh*4 + quad) ^ (l15 & 7))*8));
        __builtin_amdgcn_s_setprio(1);
        #pragma unroll
        for (int mt = 0; mt < 2; ++mt)
            #pragma unroll
            for (int nt = 0; nt < 2; ++nt) {
                acc[mt][nt] = MFMA(af[mt][0], bfr[nt][0], acc[mt][nt]);
                acc[mt][nt] = MFMA(af[mt][1], bfr[nt][1], acc[mt][nt]);
            }
        __builtin_amdgcn_s_setprio(0);
        WAIT_LGKM0();
        wg_barrier();
        if (t + 2 < NST) {
            stage_tile<64>(Ab + (t+2)*64, K, As[t & 1], wave, lane);
            stage_tile<64>(Wb + (t+2)*64, K, Bs[t & 1], wave, lane);
        }
    }

    #pragma unroll
    for (int nt = 0; nt < 2; ++nt) {
        const int col = bn + wn + nt*16 + l15;
        const float bj = bias[col] * bmul;
        #pragma unroll
        for (int mt = 0; mt < 2; ++mt)
            #pragma unroll
            for (int r = 0; r < 4; ++r) {
                const int row = bm + wm + mt*16 + quad*4 + r;
                C[(size_t)row * N + col] = acc[mt][nt][r] + bj;
            }
    }
}

// ---------------------------------------------------------------------------
// AR: fixed-max flash attention.  512-thread blocks; each block owns the
// complementary q-tile pair (p, 31-p): waves 0-3 -> qtL rows, waves 4-7 ->
// qtH rows (constant 132 chain-tiles per block).  TWO kv-tiles per barrier
// iteration (halved barrier count, 2x per-wave ILP between barriers).
// 64KB LDS (2 blocks/CU).  v_exp_f32 softmax; permlane16 P repack;
// denominators via ones-MFMA.  Epilogue normalizes, stores yarb (bf16).
// ---------------------------------------------------------------------------
__global__ __launch_bounds__(512) void attn_ar_mfma(
    const bf16_t* __restrict__ qkb, const bf16_t* __restrict__ vtg,
    bf16_t* __restrict__ yarb)
{
    const int h = blockIdx.y, b = blockIdx.z;
    const int p = b ? (15 - (int)blockIdx.x) : (int)blockIdx.x;  // co-CU hedge
    const int qtL = p, qtH = 31 - p;
    const int tid = threadIdx.x, wave = tid >> 6, lane = tid & 63;
    const int l15 = lane & 15, quad = lane >> 4;
    const int qt = (wave < 4) ? qtL : qtH;
    const int qw0 = qt * 64 + (wave & 3) * 16;
    const int bh = b * NHH + h;

    __shared__ __align__(16) unsigned short Ks[2][2][64 * 64];
    __shared__ __align__(16) unsigned short Vs[2][2][64 * 64];

    const int nit = qtH + 1;          // kv tiles 0 .. qtH  (>= 17 always)
    const int npair = (nit + 1) >> 1; // >= 9 always

    const bf16_t* kg = qkb + (size_t)(b*TT)*(2*DDE) + DDE + h*HDD;
    const bf16_t* vg = vtg + (size_t)(bh*64)*TT;

    // Q fragments: direct global->reg.
    const bf16_t* qrow = qkb + (size_t)(b*TT + qw0 + l15)*(2*DDE) + h*HDD;
    bf16x8 qf[2];
    qf[0] = *(const bf16x8*)(qrow + quad*8);
    qf[1] = *(const bf16x8*)(qrow + (quad + 4)*8);

    // prologue: pairs 0 (tiles 0,1) and 1 (tiles 2,3); 4 loads/wave/pair
    stage_tile<64, 8>(kg, 2*DDE, Ks[0][0], wave, lane);
    stage_tile<64, 8>(vg, TT, Vs[0][0], wave, lane);
    stage_tile<64, 8>(kg + (size_t)64*(2*DDE), 2*DDE, Ks[0][1], wave, lane);
    stage_tile<64, 8>(vg + 64, TT, Vs[0][1], wave, lane);
    {
        const int t2 = min(2, nit-1), t3 = min(3, nit-1);
        stage_tile<64, 8>(kg + (size_t)t2*64*(2*DDE), 2*DDE, Ks[1][0], wave, lane);
        stage_tile<64, 8>(vg + t2*64, TT, Vs[1][0], wave, lane);
        stage_tile<64, 8>(kg + (size_t)t3*64*(2*DDE), 2*DDE, Ks[1][1], wave, lane);
        stage_tile<64, 8>(vg + t3*64, TT, Vs[1][1], wave, lane);
    }
    WAIT_VM4();            // pair0 landed, pair1 in flight
    wg_barrier();

    f32x4 o[4];
    f32x4 ls = (f32x4)0.f;        // softmax denominators (C-layout rows)
    #pragma unroll
    for (int nt = 0; nt < 4; ++nt) o[nt] = (f32x4)0.f;
    bf16x8 onesb;
    #pragma unroll
    for (int j = 0; j < 8; ++j) onesb[j] = (bf16_t)1.f;

    // after permlane repack, quad q holds key-chunk cq = bitswap(q)
    const int cq = ((quad & 1) << 1) | (quad >> 1);

    for (int jp = 0; jp < npair; ++jp) {
        if (jp > 0) {
            if (jp + 1 < npair) WAIT_VM4(); else WAIT_VM0();
            wg_barrier();
        }
        #pragma unroll
        for (int half = 0; half < 2; ++half) {
            const int tt = 2*jp + half;
            const int s0 = tt * 64;
            if (tt < nit && s0 <= qw0 + 31) {
                const unsigned short* Kc = Ks[jp & 1][half];
                const unsigned short* Vc = Vs[jp & 1][half];

                // swapped QK: sv = S^T — key = nt*16+quad*4+r, query = l15
                f32x4 sv[4];
                __builtin_amdgcn_s_setprio(1);
                #pragma unroll
                for (int nt = 0; nt < 4; ++nt) {
                    const unsigned short* kr = Kc + (nt*16 + l15)*64;
                    bf16x8 kb0 = *(const bf16x8*)(kr + ((quad    ) ^ (l15 & 7))*8);
                    bf16x8 kb1 = *(const bf16x8*)(kr + ((quad + 4) ^ (l15 & 7))*8);
                    f32x4 z = (f32x4)0.f;
                    z = MFMA(kb0, qf[0], z);
                    z = MFMA(kb1, qf[1], z);
                    sv[nt] = z;
                }
                __builtin_amdgcn_s_setprio(0);

                const bool domask = (s0 + 63 > qw0);
                const int qg = qw0 + l15;
                unsigned int pk[4][2];
                #pragma unroll
                for (int nt = 0; nt < 4; ++nt) {
                    float pv[4];
                    #pragma unroll
                    for (int r = 0; r < 4; ++r) {
                        float pe = fexp2(sv[nt][r]);
                        if (domask) {
                            const int sg = s0 + nt*16 + quad*4 + r;
                            if (sg > qg) pe = 0.f;
                        }
                        pv[r] = pe;
                    }
                    pk[nt][0] = cvtpk(pv[0], pv[1]);
                    pk[nt][1] = cvtpk(pv[2], pv[3]);
                }
                // repack S^T (C-layout) -> PV A-fragment, 4 permlane16_swap
                bf16x8 pa[2];
                #pragma unroll
                for (int sc = 0; sc < 2; ++sc) {
                    pl16swap(pk[2*sc][0], pk[2*sc+1][0]);
                    pl16swap(pk[2*sc][1], pk[2*sc+1][1]);
                    union { unsigned int u[4]; bf16x8 v; } pu;
                    pu.u[0] = pk[2*sc][0];
                    pu.u[1] = pk[2*sc][1];
                    pu.u[2] = pk[2*sc+1][0];
                    pu.u[3] = pk[2*sc+1][1];
                    pa[sc] = pu.v;
                }

                __builtin_amdgcn_s_setprio(1);
                // denominators: rowsum via ones-B MFMA (same lane/reg as o)
                ls = MFMA(pa[0], onesb, ls);
                ls = MFMA(pa[1], onesb, ls);
                #pragma unroll
                for (int nt = 0; nt < 4; ++nt) {
                    const unsigned short* vr = Vc + (nt*16 + l15)*64;
                    bf16x8 vb0 = *(const bf16x8*)(vr + ((cq    ) ^ (l15 & 7))*8);
                    bf16x8 vb1 = *(const bf16x8*)(vr + ((cq + 4) ^ (l15 & 7))*8);
                    o[nt] = MFMA(pa[0], vb0, o[nt]);
                    o[nt] = MFMA(pa[1], vb1, o[nt]);
                }
                __builtin_amdgcn_s_setprio(0);
            }
        }
        WAIT_LGKM0();
        wg_barrier();
        if (jp + 2 < npair) {
            const int t0 = 2*(jp + 2);              // always < nit
            const int t1 = min(t0 + 1, nit - 1);    // clamp (uniform vmcnt)
            stage_tile<64, 8>(kg + (size_t)t0*64*(2*DDE), 2*DDE, Ks[jp & 1][0], wave, lane);
            stage_tile<64, 8>(vg + t0*64, TT, Vs[jp & 1][0], wave, lane);
            stage_tile<64, 8>(kg + (size_t)t1*64*(2*DDE), 2*DDE, Ks[jp & 1][1], wave, lane);
            stage_tile<64, 8>(vg + t1*64, TT, Vs[jp & 1][1], wave, lane);
        }
    }

    // epilogue: normalize and store bf16 (ls[r] pairs with o[nt][r] directly)
    float inv[4];
    #pragma unroll
    for (int r = 0; r < 4; ++r) inv[r] = 1.f / ls[r];
    #pragma unroll
    for (int nt = 0; nt < 4; ++nt)
        #pragma unroll
        for (int r = 0; r < 4; ++r) {
            const int row = qw0 + quad*4 + r;
            const int col = h*HDD + nt*16 + l15;
            yarb[(size_t)(b*TT + row)*DDE + col] = (bf16_t)(o[nt][r] * inv[r]);
        }
}

// ---------------------------------------------------------------------------
// MA: linear causal attention, same paired-512-thread 2-tiles-per-barrier
// structure.  Q row-sum in-register; fused combine: ysumb = bf16(yarb + o).
// ---------------------------------------------------------------------------
__global__ __launch_bounds__(512) void attn_ma_mfma(
    const bf16_t* __restrict__ qab, const bf16_t* __restrict__ kcs,
    const bf16_t* __restrict__ etg, const bf16_t* __restrict__ yarb,
    bf16_t* __restrict__ ysumb)
{
    const int h = blockIdx.y, b = blockIdx.z;
    const int p = b ? (15 - (int)blockIdx.x) : (int)blockIdx.x;
    const int qtL = p, qtH = 31 - p;
    const int tid = threadIdx.x, wave = tid >> 6, lane = tid & 63;
    const int l15 = lane & 15, quad = lane >> 4;
    const int qt = (wave < 4) ? qtL : qtH;
    const int qw0 = qt * 64 + (wave & 3) * 16;
    const int bh = b * NHH + h;

    __shared__ __align__(16) unsigned short Ks[2][2][64 * 64];
    __shared__ __align__(16) unsigned short Es[2][2][64 * 64];

    const int nit = qtH + 1;
    const int npair = (nit + 1) >> 1;

    const bf16_t* kg = kcs + (size_t)(b*TT)*DDE + h*HDD;
    const bf16_t* eg = etg + (size_t)(bh*64)*TT;

    const bf16_t* qrow = qab + (size_t)(b*TT + qw0 + l15)*DDE + h*HDD;
    bf16x8 qf[2];
    qf[0] = *(const bf16x8*)(qrow + quad*8);
    qf[1] = *(const bf16x8*)(qrow + (quad + 4)*8);

    stage_tile<64, 8>(kg, DDE, Ks[0][0], wave, lane);
    stage_tile<64, 8>(eg, TT, Es[0][0], wave, lane);
    stage_tile<64, 8>(kg + (size_t)64*DDE, DDE, Ks[0][1], wave, lane);
    stage_tile<64, 8>(eg + 64, TT, Es[0][1], wave, lane);
    {
        const int t2 = min(2, nit-1), t3 = min(3, nit-1);
        stage_tile<64, 8>(kg + (size_t)t2*64*DDE, DDE, Ks[1][0], wave, lane);
        stage_tile<64, 8>(eg + t2*64, TT, Es[1][0], wave, lane);
        stage_tile<64, 8>(kg + (size_t)t3*64*DDE, DDE, Ks[1][1], wave, lane);
        stage_tile<64, 8>(eg + t3*64, TT, Es[1][1], wave, lane);
    }
    WAIT_VM4();
    wg_barrier();

    // Q row-sum (64 cols) in-register: lane holds 16 elems; quad butterfly.
    float rs = 0.f;
    #pragma unroll
    for (int kc = 0; kc < 2; ++kc)
        #pragma unroll
        for (int u = 0; u < 8; ++u) rs += (float)qf[kc][u];
    rs += __shfl_xor(rs, 16);
    rs += __shfl_xor(rs, 32);
    const float Rr = 0.5f * rs;     // row-sum for query row l15 (all quads)

    f32x4 o[4];
    #pragma unroll
    for (int nt = 0; nt < 4; ++nt) o[nt] = (f32x4)0.f;

    const int cq = ((quad & 1) << 1) | (quad >> 1);

    for (int jp = 0; jp < npair; ++jp) {
        if (jp > 0) {
            if (jp + 1 < npair) WAIT_VM4(); else WAIT_VM0();
            wg_barrier();
        }
        #pragma unroll
        for (int half = 0; half < 2; ++half) {
            const int tt = 2*jp + half;
            const int s0 = tt * 64;
            if (tt < nit && s0 <= qw0 + 31) {
                const unsigned short* Kc = Ks[jp & 1][half];
                const unsigned short* Ec = Es[jp & 1][half];

                f32x4 sv[4];
                __builtin_amdgcn_s_setprio(1);
                #pragma unroll
                for (int nt = 0; nt < 4; ++nt) {
                    const unsigned short* kr = Kc + (nt*16 + l15)*64;
                    bf16x8 kb0 = *(const bf16x8*)(kr + ((quad    ) ^ (l15 & 7))*8);
                    bf16x8 kb1 = *(const bf16x8*)(kr + ((quad + 4) ^ (l15 & 7))*8);
                    f32x4 z = (f32x4)0.f;
                    z = MFMA(kb0, qf[0], z);
                    z = MFMA(kb1, qf[1], z);
                    sv[nt] = z;
                }
                __builtin_amdgcn_s_setprio(0);

                const bool domask = (s0 + 63 > qw0);
                const bool m0 = (tt == 0);
                const int qg = qw0 + l15;
                unsigned int pk[4][2];
                #pragma unroll
                for (int nt = 0; nt < 4; ++nt) {
                    float pv[4];
                    #pragma unroll
                    for (int r = 0; r < 4; ++r) {
                        const int sg = s0 + nt*16 + quad*4 + r;
                        float pe = sv[nt][r] + Rr;
                        if (m0 && sg == 0) pe = 0.f;
                        if (domask && sg > qg) pe = 0.f;
                        pv[r] = pe;
                    }
                    pk[nt][0] = cvtpk(pv[0], pv[1]);
                    pk[nt][1] = cvtpk(pv[2], pv[3]);
                }
                bf16x8 pa[2];
                #pragma unroll
                for (int sc = 0; sc < 2; ++sc) {
                    pl16swap(pk[2*sc][0], pk[2*sc+1][0]);
                    pl16swap(pk[2*sc][1], pk[2*sc+1][1]);
                    union { unsigned int u[4]; bf16x8 v; } pu;
                    pu.u[0] = pk[2*sc][0];
                    pu.u[1] = pk[2*sc][1];
                    pu.u[2] = pk[2*sc+1][0];
                    pu.u[3] = pk[2*sc+1][1];
                    pa[sc] = pu.v;
                }

                __builtin_amdgcn_s_setprio(1);
                #pragma unroll
                for (int nt = 0; nt < 4; ++nt) {
                    const unsigned short* er = Ec + (nt*16 + l15)*64;
                    bf16x8 eb0 = *(const bf16x8*)(er + ((cq    ) ^ (l15 & 7))*8);
                    bf16x8 eb1 = *(const bf16x8*)(er + ((cq + 4) ^ (l15 & 7))*8);
                    o[nt] = MFMA(pa[0], eb0, o[nt]);
                    o[nt] = MFMA(pa[1], eb1, o[nt]);
                }
                __builtin_amdgcn_s_setprio(0);
            }
        }
        WAIT_LGKM0();
        wg_barrier();
        if (jp + 2 < npair) {
            const int t0 = 2*(jp + 2);
            const int t1 = min(t0 + 1, nit - 1);
            stage_tile<64, 8>(kg + (size_t)t0*64*DDE, DDE, Ks[jp & 1][0], wave, lane);
            stage_tile<64, 8>(eg + t0*64, TT, Es[jp & 1][0], wave, lane);
            stage_tile<64, 8>(kg + (size_t)t1*64*DDE, DDE, Ks[jp & 1][1], wave, lane);
            stage_tile<64, 8>(eg + t1*64, TT, Es[jp & 1][1], wave, lane);
        }
    }

    // epilogue: ysumb = bf16(yarb + o)  (each (row,col) owned exactly once)
    #pragma unroll
    for (int nt = 0; nt < 4; ++nt)
        #pragma unroll
        for (int r = 0; r < 4; ++r) {
            const int row = qw0 + quad*4 + r;
            const int col = h*HDD + nt*16 + l15;
            const size_t e = (size_t)(b*TT + row)*DDE + col;
            ysumb[e] = (bf16_t)((float)yarb[e] + o[nt][r]);
        }
}

// ---------------------------------------------------------------------------
extern "C" void kernel_launch(void* const* d_in, const int* in_sizes, int n_in,
                              void* d_out, int out_size, void* d_ws, size_t ws_size,
                              hipStream_t stream)
{
    const float* x      = (const float*)d_in[0];
    const float* w_attn = (const float*)d_in[1];
    const float* b_attn = (const float*)d_in[2];
    const float* w_k2   = (const float*)d_in[3];
    const float* b_k2   = (const float*)d_in[4];
    const float* w_proj = (const float*)d_in[5];
    const float* b_proj = (const float*)d_in[6];

    const size_t NX  = (size_t)BB*TT*DDE;
    const size_t NWA = (size_t)2*DDE*DDE;
    const size_t NW  = (size_t)DDE*DDE;
    const size_t NQK = (size_t)BB*TT*2*DDE;

    bf16_t* xb   = (bf16_t*)d_ws;
    bf16_t* wab  = xb   + NX;
    bf16_t* wkb  = wab  + NWA;
    bf16_t* wpb  = wkb  + NW;
    bf16_t* qkb  = wpb  + NW;
    bf16_t* qab  = qkb  + NQK;
    bf16_t* kcs  = qab  + NX;
    bf16_t* vtg  = kcs  + NX;          // aliased by etg after attn_ar
    bf16_t* ysumb= vtg  + NX;
    bf16_t* yarb = (bf16_t*)((float*)(vtg + NX) + NX);
    bf16_t* etg  = vtg;

    const size_t NCVT = NX + NWA + NW + NW;
    cvt_all<<<NCVT / 1024, 256, 0, stream>>>(x, w_attn, w_k2, w_proj, xb);

    transpose_head<<<dim3(TT/64, NHH, BB), 256, 0, stream>>>(xb, vtg);

    const int M = BB * TT;
    gemm_qkk2<<<dim3(24, M/64), 256, 0, stream>>>(xb, wab, wkb, b_attn, b_k2,
                                                   qkb, qab, kcs);

    attn_ar_mfma<<<dim3(16, NHH, BB), 512, 0, stream>>>(qkb, vtg, yarb);
    build_etg<<<dim3(TT/64, NHH, BB), 256, 0, stream>>>(yarb, xb, etg);
    attn_ma_mfma<<<dim3(16, NHH, BB), 512, 0, stream>>>(qab, kcs, etg, yarb, ysumb);

    gemm_proj<<<dim3(DDE/64, M/64), 256, 0, stream>>>(ysumb, wpb, b_proj,
                                                      (float*)d_out, M, DDE, DDE, 2.f);
}

// Round 10
// 218.595 us; speedup vs baseline: 1.3917x; 1.0489x over previous
//
#include <hip/hip_runtime.h>
#include <hip/hip_bf16.h>
#include <math.h>

#define BB  2
#define TT  2048
#define DDE 1024
#define NHH 16
#define HDD 64

typedef __bf16 bf16_t;
typedef __attribute__((ext_vector_type(8))) __bf16 bf16x8;
typedef __attribute__((ext_vector_type(4))) __bf16 bf16x4;
typedef __attribute__((ext_vector_type(4))) float  f32x4;

#define MFMA(a, b, c) __builtin_amdgcn_mfma_f32_16x16x32_bf16((a), (b), (c), 0, 0, 0)

// counted waits: loads for the NEXT tile stay in flight across barriers (T4)
#define WAIT_VM6()   asm volatile("s_waitcnt vmcnt(6)" ::: "memory")
#define WAIT_VM4()   asm volatile("s_waitcnt vmcnt(4)" ::: "memory")
#define WAIT_VM0()   asm volatile("s_waitcnt vmcnt(0)" ::: "memory")
#define WAIT_LGKM0() asm volatile("s_waitcnt lgkmcnt(0)" ::: "memory")

// raw workgroup barrier (no vmcnt drain), fenced against compiler reordering
__device__ inline void wg_barrier() {
    __builtin_amdgcn_sched_barrier(0);
    __builtin_amdgcn_s_barrier();
    __builtin_amdgcn_sched_barrier(0);
}

// pack 2 f32 -> 1 u32 of 2 bf16 (RNE), no builtin on gfx950
__device__ inline unsigned int cvtpk(float a, float b) {
    unsigned int r;
    asm("v_cvt_pk_bf16_f32 %0, %1, %2" : "=v"(r) : "v"(a), "v"(b));
    return r;
}

// single-instruction 2^x (exact; denormals flush->0, fine for softmax)
__device__ inline float fexp2(float x) {
    float r;
    asm("v_exp_f32 %0, %1" : "=v"(r) : "v"(x));
    return r;
}

// v_permlane16_swap_b32: swaps a's odd 16-lane rows with b's even 16-lane
// rows.  After: a = {a.r0, b.r0, a.r2, b.r2}, b = {a.r1, b.r1, a.r3, b.r3}.
__device__ inline void pl16swap(unsigned int &a, unsigned int &b) {
    asm("v_permlane16_swap_b32 %0, %1" : "+v"(a), "+v"(b));
}

__device__ inline void gll16(const bf16_t* g, unsigned short* l) {
    __builtin_amdgcn_global_load_lds(
        (const __attribute__((address_space(1))) void*)g,
        (__attribute__((address_space(3))) void*)l, 16, 0, 0);
}

// Stage [ROWS x 64] bf16 tile (row stride gstride elems) into LDS via
// global_load_lds, chunk-swizzled: LDS elem [r][ (c ^ (r&7))*8 + j ].
// Per-wave gll16 count: ROWS/(NW*8).
template<int ROWS, int NW = 4>
__device__ inline void stage_tile(const bf16_t* g0, size_t gstride,
                                  unsigned short* lds, int wave, int lane)
{
    const int r8 = lane >> 3;
    const int ck = (lane & 7) ^ r8;
    constexpr int RW = ROWS / NW;
    const bf16_t* g = g0 + (size_t)(wave * RW + r8) * gstride + ck * 8;
    unsigned short* l = lds + wave * RW * 64 + lane * 8;
    #pragma unroll
    for (int i = 0; i < RW / 8; ++i)
        gll16(g + (size_t)(i * 8) * gstride, l + i * 512);
}

// ---------------------------------------------------------------------------
// fused fp32->bf16 conversion of x, w_attn, w_k2, w_proj into the contiguous
// ws region starting at xb.  Segment boundaries are multiples of 1024 elems.
// ---------------------------------------------------------------------------
__global__ __launch_bounds__(256) void cvt_all(
    const float* __restrict__ x, const float* __restrict__ wa,
    const float* __restrict__ wk, const float* __restrict__ wp,
    bf16_t* __restrict__ out)
{
    const size_t NX  = (size_t)BB*TT*DDE;
    const size_t NWA = (size_t)2*DDE*DDE;
    const size_t NW  = (size_t)DDE*DDE;
    const size_t e = ((size_t)blockIdx.x * 256 + threadIdx.x) * 4;
    const float* src;
    if (e < NX)                 src = x  + e;
    else if (e < NX + NWA)      src = wa + (e - NX);
    else if (e < NX + NWA + NW) src = wk + (e - NX - NWA);
    else                        src = wp + (e - NX - NWA - NW);
    float4 v = *(const float4*)src;
    bf16x4 o;
    o[0] = (bf16_t)v.x; o[1] = (bf16_t)v.y;
    o[2] = (bf16_t)v.z; o[3] = (bf16_t)v.w;
    *(bf16x4*)(out + e) = o;
}

// ---------------------------------------------------------------------------
// Per-head 64x64 transpose: dst[bh][d][t] = src[b][t][h*64+d].
// ---------------------------------------------------------------------------
__global__ __launch_bounds__(256) void transpose_head(
    const bf16_t* __restrict__ src, bf16_t* __restrict__ dst)
{
    const int t0 = blockIdx.x * 64, h = blockIdx.y, b = blockIdx.z;
    const int tid = threadIdx.x;
    __shared__ __align__(16) bf16_t tile[64 * 64];

    #pragma unroll
    for (int it = 0; it < 2; ++it) {
        const int t = it * 32 + (tid >> 3);
        const int cw = tid & 7;
        const int slot = (cw + (t >> 3)) & 7;
        bf16x8 v = *(const bf16x8*)(src + (size_t)(b*TT + t0 + t)*DDE + h*HDD + cw*8);
        *(bf16x8*)(tile + t*64 + slot*8) = v;
    }
    __syncthreads();
    const int bh = b * NHH + h;
    #pragma unroll
    for (int it = 0; it < 2; ++it) {
        const int d = it * 32 + (tid >> 3);
        const int co = tid & 7;
        const int slot = ((d >> 3) + co) & 7;
        bf16x8 o;
        #pragma unroll
        for (int j = 0; j < 8; ++j)
            o[j] = tile[(co*8 + j)*64 + slot*8 + (d & 7)];
        *(bf16x8*)(dst + (size_t)(bh*64 + d)*TT + t0 + co*8) = o;
    }
}

// ---------------------------------------------------------------------------
// E-transpose: etg[bh][d][t] = x[t][d] - n[t-1][d]  (0 at t==0),
// where n = yarb (normalized AR output, written by attn_ar).
// ---------------------------------------------------------------------------
__global__ __launch_bounds__(256) void build_etg(
    const bf16_t* __restrict__ yarb, const bf16_t* __restrict__ xb,
    bf16_t* __restrict__ etg)
{
    const int t0 = blockIdx.x * 64, h = blockIdx.y, b = blockIdx.z;
    const int tid = threadIdx.x;
    const int bh = b * NHH + h;
    __shared__ __align__(16) bf16_t tile[64 * 64];

    #pragma unroll
    for (int it = 0; it < 2; ++it) {
        const int t = it * 32 + (tid >> 3);
        const int cw = tid & 7;
        const int slot = (cw + (t >> 3)) & 7;
        const int tg = t0 + t;
        bf16x8 ev;
        if (tg == 0) {
            #pragma unroll
            for (int u = 0; u < 8; ++u) ev[u] = (bf16_t)0.f;
        } else {
            bf16x8 xv = *(const bf16x8*)(xb   + (size_t)(b*TT + tg)*DDE + h*HDD + cw*8);
            bf16x8 nv = *(const bf16x8*)(yarb + (size_t)(b*TT + tg - 1)*DDE + h*HDD + cw*8);
            #pragma unroll
            for (int u = 0; u < 8; ++u)
                ev[u] = (bf16_t)((float)xv[u] - (float)nv[u]);
        }
        *(bf16x8*)(tile + t*64 + slot*8) = ev;
    }
    __syncthreads();
    #pragma unroll
    for (int it = 0; it < 2; ++it) {
        const int d = it * 32 + (tid >> 3);
        const int co = tid & 7;
        const int slot = ((d >> 3) + co) & 7;
        bf16x8 o;
        #pragma unroll
        for (int j = 0; j < 8; ++j)
            o[j] = tile[(co*8 + j)*64 + slot*8 + (d & 7)];
        *(bf16x8*)(etg + (size_t)(bh*64 + d)*TT + t0 + co*8) = o;
    }
}

// ---------------------------------------------------------------------------
// Fused QKV GEMM, BM=64 x BN=128, BK=64, counted-vmcnt dbuf pipeline.
// Region by column tile:
//   [0,1024):  q -> qkb = q*0.125*log2(e) (exp2 domain), qab = leaky(q*0.125)
//   [1024,2048): k -> qkb raw
//   [2048,3072): k2 -> kcs[t+1] = sigmoid(k2*0.0025)-0.5 (shifted, row0=0)
// ---------------------------------------------------------------------------
__global__ __launch_bounds__(256) void gemm_qkk2(
    const bf16_t* __restrict__ A, const bf16_t* __restrict__ wab,
    const bf16_t* __restrict__ wkb, const float* __restrict__ b_attn,
    const float* __restrict__ b_k2, bf16_t* __restrict__ qkb,
    bf16_t* __restrict__ qab, bf16_t* __restrict__ kcs)
{
    __shared__ __align__(16) unsigned short As[2][64 * 64];
    __shared__ __align__(16) unsigned short Bs[2][128 * 64];
    const int tid  = threadIdx.x;
    const int wave = tid >> 6, lane = tid & 63;
    const int l15  = lane & 15, quad = lane >> 4;
    // XCD swizzle (bijective: 1536 = 8*192): each XCD owns 8 contiguous
    // m-rows x all 24 n-tiles; per-k-step slab (A 64KB + B 384KB) L2-fits.
    const int lid = (int)blockIdx.y * 24 + (int)blockIdx.x;
    const int s   = (lid & 7) * 192 + (lid >> 3);
    const int bm = (s / 24) * 64, bn = (s % 24) * 128;
    const int wm = (wave & 1) * 32, wn = (wave >> 1) * 64;
    const int region = bn >> 10;
    const int K = DDE;
    constexpr int NST = DDE / 64;   // 16 K-steps

    const bf16_t* W = (region < 2) ? wab + (size_t)bn * K
                                   : wkb + (size_t)(bn - 2048) * K;
    const float* bp = (region < 2) ? b_attn + bn : b_k2 + (bn - 2048);
    const bf16_t* Ab = A + (size_t)bm * K;

    f32x4 acc[2][4];
    #pragma unroll
    for (int i = 0; i < 2; ++i)
        #pragma unroll
        for (int j = 0; j < 4; ++j) acc[i][j] = (f32x4)0.f;

    // prologue: stage K-steps 0 and 1 (6 gll16/wave each: 2 A + 4 B)
    stage_tile<64>(Ab, K, As[0], wave, lane);
    stage_tile<128>(W,  K, Bs[0], wave, lane);
    stage_tile<64>(Ab + 64, K, As[1], wave, lane);
    stage_tile<128>(W  + 64, K, Bs[1], wave, lane);

    for (int t = 0; t < NST; ++t) {
        // wait tile t landed; tile t+1's 6 loads stay in flight
        if (t + 1 < NST) WAIT_VM6(); else WAIT_VM0();
        wg_barrier();
        const unsigned short* Ac = As[t & 1];
        const unsigned short* Bc = Bs[t & 1];
        bf16x8 af[2][2], bfr[4][2];
        #pragma unroll
        for (int mt = 0; mt < 2; ++mt)
            #pragma unroll
            for (int kh = 0; kh < 2; ++kh)
                af[mt][kh] = *(const bf16x8*)(Ac + (wm + mt*16 + l15)*64
                                              + (((kh*4 + quad) ^ (l15 & 7))*8));
        #pragma unroll
        for (int nt = 0; nt < 4; ++nt)
            #pragma unroll
            for (int kh = 0; kh < 2; ++kh)
                bfr[nt][kh] = *(const bf16x8*)(Bc + (wn + nt*16 + l15)*64
                                               + (((kh*4 + quad) ^ (l15 & 7))*8));
        __builtin_amdgcn_s_setprio(1);
        #pragma unroll
        for (int mt = 0; mt < 2; ++mt)
            #pragma unroll
            for (int nt = 0; nt < 4; ++nt) {
                acc[mt][nt] = MFMA(af[mt][0], bfr[nt][0], acc[mt][nt]);
                acc[mt][nt] = MFMA(af[mt][1], bfr[nt][1], acc[mt][nt]);
            }
        __builtin_amdgcn_s_setprio(0);
        // all waves done reading buf[t&1] before restaging into it
        WAIT_LGKM0();
        wg_barrier();
        if (t + 2 < NST) {
            stage_tile<64>(Ab + (t+2)*64, K, As[t & 1], wave, lane);
            stage_tile<128>(W  + (t+2)*64, K, Bs[t & 1], wave, lane);
        }
    }

    #pragma unroll
    for (int nt = 0; nt < 4; ++nt) {
        const int cl = wn + nt*16 + l15;
        const float bj = bp[cl];
        const int cg = bn + cl;
        #pragma unroll
        for (int mt = 0; mt < 2; ++mt)
            #pragma unroll
            for (int r = 0; r < 4; ++r) {
                const int row = bm + wm + mt*16 + quad*4 + r;
                const float v = acc[mt][nt][r] + bj;
                if (region == 0) {
                    qkb[(size_t)row * (2*DDE) + cg] = (bf16_t)(v * 0.180336880f);
                    const float z = v * 0.125f;
                    qab[(size_t)row * DDE + cg] = (bf16_t)((v > 0.f) ? 0.02f*z : z);
                } else if (region == 1) {
                    qkb[(size_t)row * (2*DDE) + cg] = (bf16_t)v;
                } else {
                    const int c2 = cg - 2048;
                    const float kc = 1.f/(1.f + __expf(-v*0.0025f)) - 0.5f;
                    if (((row + 1) & (TT - 1)) != 0)
                        kcs[(size_t)(row + 1) * DDE + c2] = (bf16_t)kc;
                    if ((row & (TT - 1)) == 0)
                        kcs[(size_t)row * DDE + c2] = (bf16_t)0.f;
                }
            }
    }
}

// ---------------------------------------------------------------------------
// proj GEMM, BM=64 x BN=64, BK=64, counted-vmcnt dbuf (fp32 out):
// C = A W^T + 2*bias.  1024 blocks (4/CU by grid, 5/CU by LDS=32KB).
// ---------------------------------------------------------------------------
__global__ __launch_bounds__(256) void gemm_proj(
    const bf16_t* __restrict__ A, const bf16_t* __restrict__ W,
    const float* __restrict__ bias, float* __restrict__ C,
    int M, int N, int K, float bmul)
{
    __shared__ __align__(16) unsigned short As[2][64 * 64];
    __shared__ __align__(16) unsigned short Bs[2][64 * 64];
    const int tid  = threadIdx.x;
    const int wave = tid >> 6, lane = tid & 63;
    const int l15  = lane & 15, quad = lane >> 4;
    // XCD swizzle (bijective: 1024 = 8*128)
    const int lid = (int)blockIdx.y * 16 + (int)blockIdx.x;
    const int s   = (lid & 7) * 128 + (lid >> 3);
    const int bm = (s / 16) * 64, bn = (s % 16) * 64;
    const int wm = (wave & 1) * 32, wn = (wave >> 1) * 32;

    const bf16_t* Ab = A + (size_t)bm * K;
    const bf16_t* Wb = W + (size_t)bn * K;
    const int NST = K / 64;

    f32x4 acc[2][2];
    #pragma unroll
    for (int i = 0; i < 2; ++i)
        #pragma unroll
        for (int j = 0; j < 2; ++j) acc[i][j] = (f32x4)0.f;

    stage_tile<64>(Ab, K, As[0], wave, lane);
    stage_tile<64>(Wb, K, Bs[0], wave, lane);
    stage_tile<64>(Ab + 64, K, As[1], wave, lane);
    stage_tile<64>(Wb + 64, K, Bs[1], wave, lane);

    for (int t = 0; t < NST; ++t) {
        if (t + 1 < NST) WAIT_VM4(); else WAIT_VM0();
        wg_barrier();
        const unsigned short* Ac = As[t & 1];
        const unsigned short* Bc = Bs[t & 1];
        bf16x8 af[2][2], bfr[2][2];
        #pragma unroll
        for (int mt = 0; mt < 2; ++mt)
            #pragma unroll
            for (int kh = 0; kh < 2; ++kh)
                af[mt][kh] = *(const bf16x8*)(Ac + (wm + mt*16 + l15)*64
                                              + (((kh*4 + quad) ^ (l15 & 7))*8));
        #pragma unroll
        for (int nt = 0; nt < 2; ++nt)
            #pragma unroll
            for (int kh = 0; kh < 2; ++kh)
                bfr[nt][kh] = *(const bf16x8*)(Bc + (wn + nt*16 + l15)*64
                                               + (((kh*4 + quad) ^ (l15 & 7))*8));
        __builtin_amdgcn_s_setprio(1);
        #pragma unroll
        for (int mt = 0; mt < 2; ++mt)
            #pragma unroll
            for (int nt = 0; nt < 2; ++nt) {
                acc[mt][nt] = MFMA(af[mt][0], bfr[nt][0], acc[mt][nt]);
                acc[mt][nt] = MFMA(af[mt][1], bfr[nt][1], acc[mt][nt]);
            }
        __builtin_amdgcn_s_setprio(0);
        WAIT_LGKM0();
        wg_barrier();
        if (t + 2 < NST) {
            stage_tile<64>(Ab + (t+2)*64, K, As[t & 1], wave, lane);
            stage_tile<64>(Wb + (t+2)*64, K, Bs[t & 1], wave, lane);
        }
    }

    #pragma unroll
    for (int nt = 0; nt < 2; ++nt) {
        const int col = bn + wn + nt*16 + l15;
        const float bj = bias[col] * bmul;
        #pragma unroll
        for (int mt = 0; mt < 2; ++mt)
            #pragma unroll
            for (int r = 0; r < 4; ++r) {
                const int row = bm + wm + mt*16 + quad*4 + r;
                C[(size_t)row * N + col] = acc[mt][nt][r] + bj;
            }
    }
}

// per-unit AR compute on tile (Kc,Vc,s0): QK^T (swapped), softmax-exp,
// permlane repack, ones-MFMA denominator, PV accumulate.
#define AR_UNIT(QF, OO, LSACC, QW0)  do {                                   \
    f32x4 sv[4];                                                            \
    __builtin_amdgcn_s_setprio(1);                                          \
    _Pragma("unroll")                                                       \
    for (int nt = 0; nt < 4; ++nt) {                                        \
        const unsigned short* kr = Kc + (nt*16 + l15)*64;                   \
        bf16x8 kb0 = *(const bf16x8*)(kr + ((quad    ) ^ (l15 & 7))*8);     \
        bf16x8 kb1 = *(const bf16x8*)(kr + ((quad + 4) ^ (l15 & 7))*8);     \
        f32x4 z = (f32x4)0.f;                                               \
        z = MFMA(kb0, QF[0], z);                                            \
        z = MFMA(kb1, QF[1], z);                                            \
        sv[nt] = z;                                                         \
    }                                                                       \
    __builtin_amdgcn_s_setprio(0);                                          \
    const bool domask = (s0 + 63 > (QW0));                                  \
    const int qg = (QW0) + l15;                                             \
    unsigned int pk[4][2];                                                  \
    _Pragma("unroll")                                                       \
    for (int nt = 0; nt < 4; ++nt) {                                        \
        float pv[4];                                                        \
        _Pragma("unroll")                                                   \
        for (int r = 0; r < 4; ++r) {                                       \
            float pe = fexp2(sv[nt][r]);                                    \
            if (domask) {                                                   \
                const int sg = s0 + nt*16 + quad*4 + r;                     \
                if (sg > qg) pe = 0.f;                                      \
            }                                                               \
            pv[r] = pe;                                                     \
        }                                                                   \
        pk[nt][0] = cvtpk(pv[0], pv[1]);                                    \
        pk[nt][1] = cvtpk(pv[2], pv[3]);                                    \
    }                                                                       \
    bf16x8 pa[2];                                                           \
    _Pragma("unroll")                                                       \
    for (int sc = 0; sc < 2; ++sc) {                                        \
        pl16swap(pk[2*sc][0], pk[2*sc+1][0]);                               \
        pl16swap(pk[2*sc][1], pk[2*sc+1][1]);                               \
        union { unsigned int uu[4]; bf16x8 v; } pu;                         \
        pu.uu[0] = pk[2*sc][0];   pu.uu[1] = pk[2*sc][1];                   \
        pu.uu[2] = pk[2*sc+1][0]; pu.uu[3] = pk[2*sc+1][1];                 \
        pa[sc] = pu.v;                                                      \
    }                                                                       \
    __builtin_amdgcn_s_setprio(1);                                          \
    LSACC = MFMA(pa[0], onesb, LSACC);                                      \
    LSACC = MFMA(pa[1], onesb, LSACC);                                      \
    _Pragma("unroll")                                                       \
    for (int nt = 0; nt < 4; ++nt) {                                        \
        const unsigned short* vr = Vc + (nt*16 + l15)*64;                   \
        bf16x8 vb0 = *(const bf16x8*)(vr + ((cq    ) ^ (l15 & 7))*8);       \
        bf16x8 vb1 = *(const bf16x8*)(vr + ((cq + 4) ^ (l15 & 7))*8);       \
        OO[nt] = MFMA(pa[0], vb0, OO[nt]);                                  \
        OO[nt] = MFMA(pa[1], vb1, OO[nt]);                                  \
    }                                                                       \
    __builtin_amdgcn_s_setprio(0);                                          \
} while (0)

// ---------------------------------------------------------------------------
// AR: fixed-max flash attention, work-conserving paired decomposition.
// Block owns q-tiles (p, 31-p).  Per kv-pair iteration, wave takes tile
// myt = 2*jp + (wave>=4) and processes up to TWO units on it: (qtH,myt) and
// (qtL,myt) -> every wave ~16.5 units regardless of p (no idle waves).
// Even/odd-tile partials merge across the ws-pair through LDS at the end.
// ---------------------------------------------------------------------------
__global__ __launch_bounds__(512, 4) void attn_ar_mfma(
    const bf16_t* __restrict__ qkb, const bf16_t* __restrict__ vtg,
    bf16_t* __restrict__ yarb)
{
    const int h = blockIdx.y, b = blockIdx.z;
    const int p = b ? (15 - (int)blockIdx.x) : (int)blockIdx.x;  // co-CU hedge
    const int qtL = p, qtH = 31 - p;
    const int tid = threadIdx.x, wave = tid >> 6, lane = tid & 63;
    const int l15 = lane & 15, quad = lane >> 4;
    const int wl = wave & 3, wsid = wave >> 2;
    const int qw0L = qtL * 64 + wl * 16;
    const int qw0H = qtH * 64 + wl * 16;
    const int bh = b * NHH + h;

    // [pair][half][K=0/V=1][64*64] = 64 KB; reused as f32 merge scratch.
    __shared__ __align__(16) unsigned short Lds[2][2][2][64 * 64];

    const int nit = qtH + 1;          // kv tiles 0 .. qtH  (>= 17)
    const int npair = (nit + 1) >> 1;

    const bf16_t* kg = qkb + (size_t)(b*TT)*(2*DDE) + DDE + h*HDD;
    const bf16_t* vg = vtg + (size_t)(bh*64)*TT;

    // Q fragments for both targets: direct global->reg.
    const bf16_t* qrowL = qkb + (size_t)(b*TT + qw0L + l15)*(2*DDE) + h*HDD;
    const bf16_t* qrowH = qkb + (size_t)(b*TT + qw0H + l15)*(2*DDE) + h*HDD;
    bf16x8 qfL[2], qfH[2];
    qfL[0] = *(const bf16x8*)(qrowL + quad*8);
    qfL[1] = *(const bf16x8*)(qrowL + (quad + 4)*8);
    qfH[0] = *(const bf16x8*)(qrowH + quad*8);
    qfH[1] = *(const bf16x8*)(qrowH + (quad + 4)*8);
    __builtin_amdgcn_sched_barrier(0);   // pin Q-load issue before staging

    // prologue: pairs 0 (tiles 0,1) and 1 (tiles 2,3); 4 loads/wave/pair
    stage_tile<64, 8>(kg, 2*DDE, &Lds[0][0][0][0], wave, lane);
    stage_tile<64, 8>(vg, TT,    &Lds[0][0][1][0], wave, lane);
    stage_tile<64, 8>(kg + (size_t)64*(2*DDE), 2*DDE, &Lds[0][1][0][0], wave, lane);
    stage_tile<64, 8>(vg + 64, TT, &Lds[0][1][1][0], wave, lane);
    stage_tile<64, 8>(kg + (size_t)2*64*(2*DDE), 2*DDE, &Lds[1][0][0][0], wave, lane);
    stage_tile<64, 8>(vg + 2*64, TT, &Lds[1][0][1][0], wave, lane);
    stage_tile<64, 8>(kg + (size_t)3*64*(2*DDE), 2*DDE, &Lds[1][1][0][0], wave, lane);
    stage_tile<64, 8>(vg + 3*64, TT, &Lds[1][1][1][0], wave, lane);
    WAIT_VM4();            // Q + pair0 landed, pair1 in flight
    wg_barrier();

    f32x4 oH[4], oL[4];
    f32x4 lsH = (f32x4)0.f, lsL = (f32x4)0.f;
    #pragma unroll
    for (int nt = 0; nt < 4; ++nt) { oH[nt] = (f32x4)0.f; oL[nt] = (f32x4)0.f; }
    bf16x8 onesb;
    #pragma unroll
    for (int j = 0; j < 8; ++j) onesb[j] = (bf16_t)1.f;

    // after permlane repack, quad q holds key-chunk cq = bitswap(q)
    const int cq = ((quad & 1) << 1) | (quad >> 1);

    for (int jp = 0; jp < npair; ++jp) {
        if (jp > 0) {
            if (jp + 1 < npair) WAIT_VM4(); else WAIT_VM0();
            wg_barrier();
        }
        const int myt = 2*jp + wsid;
        const int s0 = myt * 64;
        const unsigned short* Kc = &Lds[jp & 1][wsid][0][0];
        const unsigned short* Vc = &Lds[jp & 1][wsid][1][0];

        if (myt <= qtH) AR_UNIT(qfH, oH, lsH, qw0H);
        if (myt <= p)   AR_UNIT(qfL, oL, lsL, qw0L);

        WAIT_LGKM0();
        wg_barrier();
        if (jp + 2 < npair) {
            const int t0 = 2*(jp + 2);              // always < nit
            const int t1 = min(t0 + 1, nit - 1);    // clamp (uniform vmcnt)
            stage_tile<64, 8>(kg + (size_t)t0*64*(2*DDE), 2*DDE, &Lds[jp & 1][0][0][0], wave, lane);
            stage_tile<64, 8>(vg + t0*64, TT, &Lds[jp & 1][0][1][0], wave, lane);
            stage_tile<64, 8>(kg + (size_t)t1*64*(2*DDE), 2*DDE, &Lds[jp & 1][1][0][0], wave, lane);
            stage_tile<64, 8>(vg + t1*64, TT, &Lds[jp & 1][1][1][0], wave, lane);
        }
    }
    // here: vmcnt==0 (final iter waited VM0, no further stages); LDS reusable.

    // merge partials across the ws-pair: ws=0 ships H-set, ws=1 ships L-set.
    float* S = (float*)&Lds[0][0][0][0];
    float* my = S + (size_t)(wave*64 + lane)*20;
    {
        const f32x4 (&os)[4] = wsid ? oL : oH;
        const f32x4 &lss     = wsid ? lsL : lsH;
        #pragma unroll
        for (int nt = 0; nt < 4; ++nt)
            #pragma unroll
            for (int r = 0; r < 4; ++r) my[nt*4 + r] = os[nt][r];
        #pragma unroll
        for (int r = 0; r < 4; ++r) my[16 + r] = lss[r];
    }
    WAIT_LGKM0();
    wg_barrier();
    const float* peer = S + (size_t)((wave ^ 4)*64 + lane)*20;
    f32x4 (&ok)[4] = wsid ? oH : oL;   // kept set (the one not shipped)
    f32x4 &lsk     = wsid ? lsH : lsL;
    #pragma unroll
    for (int nt = 0; nt < 4; ++nt)
        #pragma unroll
        for (int r = 0; r < 4; ++r) ok[nt][r] += peer[nt*4 + r];
    #pragma unroll
    for (int r = 0; r < 4; ++r) lsk[r] += peer[16 + r];

    // store: ws=0 -> qtL rows, ws=1 -> qtH rows
    const int qt = wsid ? qtH : qtL;
    float inv[4];
    #pragma unroll
    for (int r = 0; r < 4; ++r) inv[r] = 1.f / lsk[r];
    #pragma unroll
    for (int nt = 0; nt < 4; ++nt)
        #pragma unroll
        for (int r = 0; r < 4; ++r) {
            const int row = qt*64 + wl*16 + quad*4 + r;
            const int col = h*HDD + nt*16 + l15;
            yarb[(size_t)(b*TT + row)*DDE + col] = (bf16_t)(ok[nt][r] * inv[r]);
        }
}

// per-unit MA compute (linear attention variant: p = S + Rr, zero masks).
#define MA_UNIT(QF, OO, RR, QW0)  do {                                      \
    f32x4 sv[4];                                                            \
    __builtin_amdgcn_s_setprio(1);                                          \
    _Pragma("unroll")                                                       \
    for (int nt = 0; nt < 4; ++nt) {                                        \
        const unsigned short* kr = Kc + (nt*16 + l15)*64;                   \
        bf16x8 kb0 = *(const bf16x8*)(kr + ((quad    ) ^ (l15 & 7))*8);     \
        bf16x8 kb1 = *(const bf16x8*)(kr + ((quad + 4) ^ (l15 & 7))*8);     \
        f32x4 z = (f32x4)0.f;                                               \
        z = MFMA(kb0, QF[0], z);                                            \
        z = MFMA(kb1, QF[1], z);                                            \
        sv[nt] = z;                                                         \
    }                                                                       \
    __builtin_amdgcn_s_setprio(0);                                          \
    const bool domask = (s0 + 63 > (QW0));                                  \
    const bool m0 = (myt == 0);                                             \
    const int qg = (QW0) + l15;                                             \
    unsigned int pk[4][2];                                                  \
    _Pragma("unroll")                                                       \
    for (int nt = 0; nt < 4; ++nt) {                                        \
        float pv[4];                                                        \
        _Pragma("unroll")                                                   \
        for (int r = 0; r < 4; ++r) {                                       \
            const int sg = s0 + nt*16 + quad*4 + r;                         \
            float pe = sv[nt][r] + (RR);                                    \
            if (m0 && sg == 0) pe = 0.f;                                    \
            if (domask && sg > qg) pe = 0.f;                                \
            pv[r] = pe;                                                     \
        }                                                                   \
        pk[nt][0] = cvtpk(pv[0], pv[1]);                                    \
        pk[nt][1] = cvtpk(pv[2], pv[3]);                                    \
    }                                                                       \
    bf16x8 pa[2];                                                           \
    _Pragma("unroll")                                                       \
    for (int sc = 0; sc < 2; ++sc) {                                        \
        pl16swap(pk[2*sc][0], pk[2*sc+1][0]);                               \
        pl16swap(pk[2*sc][1], pk[2*sc+1][1]);                               \
        union { unsigned int uu[4]; bf16x8 v; } pu;                         \
        pu.uu[0] = pk[2*sc][0];   pu.uu[1] = pk[2*sc][1];                   \
        pu.uu[2] = pk[2*sc+1][0]; pu.uu[3] = pk[2*sc+1][1];                 \
        pa[sc] = pu.v;                                                      \
    }                                                                       \
    __builtin_amdgcn_s_setprio(1);                                          \
    _Pragma("unroll")                                                       \
    for (int nt = 0; nt < 4; ++nt) {                                        \
        const unsigned short* er = Vc + (nt*16 + l15)*64;                   \
        bf16x8 eb0 = *(const bf16x8*)(er + ((cq    ) ^ (l15 & 7))*8);       \
        bf16x8 eb1 = *(const bf16x8*)(er + ((cq + 4) ^ (l15 & 7))*8);       \
        OO[nt] = MFMA(pa[0], eb0, OO[nt]);                                  \
        OO[nt] = MFMA(pa[1], eb1, OO[nt]);                                  \
    }                                                                       \
    __builtin_amdgcn_s_setprio(0);                                          \
} while (0)

// ---------------------------------------------------------------------------
// MA: linear causal attention, same work-conserving paired structure.
// Q row-sums in-register for both targets; merge across ws-pair; fused
// combine epilogue: ysumb = bf16(yarb + o).
// ---------------------------------------------------------------------------
__global__ __launch_bounds__(512, 4) void attn_ma_mfma(
    const bf16_t* __restrict__ qab, const bf16_t* __restrict__ kcs,
    const bf16_t* __restrict__ etg, const bf16_t* __restrict__ yarb,
    bf16_t* __restrict__ ysumb)
{
    const int h = blockIdx.y, b = blockIdx.z;
    const int p = b ? (15 - (int)blockIdx.x) : (int)blockIdx.x;
    const int qtL = p, qtH = 31 - p;
    const int tid = threadIdx.x, wave = tid >> 6, lane = tid & 63;
    const int l15 = lane & 15, quad = lane >> 4;
    const int wl = wave & 3, wsid = wave >> 2;
    const int qw0L = qtL * 64 + wl * 16;
    const int qw0H = qtH * 64 + wl * 16;
    const int bh = b * NHH + h;

    __shared__ __align__(16) unsigned short Lds[2][2][2][64 * 64];

    const int nit = qtH + 1;
    const int npair = (nit + 1) >> 1;

    const bf16_t* kg = kcs + (size_t)(b*TT)*DDE + h*HDD;
    const bf16_t* eg = etg + (size_t)(bh*64)*TT;

    const bf16_t* qrowL = qab + (size_t)(b*TT + qw0L + l15)*DDE + h*HDD;
    const bf16_t* qrowH = qab + (size_t)(b*TT + qw0H + l15)*DDE + h*HDD;
    bf16x8 qfL[2], qfH[2];
    qfL[0] = *(const bf16x8*)(qrowL + quad*8);
    qfL[1] = *(const bf16x8*)(qrowL + (quad + 4)*8);
    qfH[0] = *(const bf16x8*)(qrowH + quad*8);
    qfH[1] = *(const bf16x8*)(qrowH + (quad + 4)*8);
    __builtin_amdgcn_sched_barrier(0);

    stage_tile<64, 8>(kg, DDE, &Lds[0][0][0][0], wave, lane);
    stage_tile<64, 8>(eg, TT,  &Lds[0][0][1][0], wave, lane);
    stage_tile<64, 8>(kg + (size_t)64*DDE, DDE, &Lds[0][1][0][0], wave, lane);
    stage_tile<64, 8>(eg + 64, TT, &Lds[0][1][1][0], wave, lane);
    stage_tile<64, 8>(kg + (size_t)2*64*DDE, DDE, &Lds[1][0][0][0], wave, lane);
    stage_tile<64, 8>(eg + 2*64, TT, &Lds[1][0][1][0], wave, lane);
    stage_tile<64, 8>(kg + (size_t)3*64*DDE, DDE, &Lds[1][1][0][0], wave, lane);
    stage_tile<64, 8>(eg + 3*64, TT, &Lds[1][1][1][0], wave, lane);
    WAIT_VM4();
    wg_barrier();

    // Q row-sums in-register (quad butterfly yields full 64-col sum per row)
    float rsL = 0.f, rsH = 0.f;
    #pragma unroll
    for (int kc = 0; kc < 2; ++kc)
        #pragma unroll
        for (int u = 0; u < 8; ++u) { rsL += (float)qfL[kc][u]; rsH += (float)qfH[kc][u]; }
    rsL += __shfl_xor(rsL, 16); rsL += __shfl_xor(rsL, 32);
    rsH += __shfl_xor(rsH, 16); rsH += __shfl_xor(rsH, 32);
    const float RrL = 0.5f * rsL;
    const float RrH = 0.5f * rsH;

    f32x4 oH[4], oL[4];
    #pragma unroll
    for (int nt = 0; nt < 4; ++nt) { oH[nt] = (f32x4)0.f; oL[nt] = (f32x4)0.f; }

    const int cq = ((quad & 1) << 1) | (quad >> 1);

    for (int jp = 0; jp < npair; ++jp) {
        if (jp > 0) {
            if (jp + 1 < npair) WAIT_VM4(); else WAIT_VM0();
            wg_barrier();
        }
        const int myt = 2*jp + wsid;
        const int s0 = myt * 64;
        const unsigned short* Kc = &Lds[jp & 1][wsid][0][0];
        const unsigned short* Vc = &Lds[jp & 1][wsid][1][0];

        if (myt <= qtH) MA_UNIT(qfH, oH, RrH, qw0H);
        if (myt <= p)   MA_UNIT(qfL, oL, RrL, qw0L);

        WAIT_LGKM0();
        wg_barrier();
        if (jp + 2 < npair) {
            const int t0 = 2*(jp + 2);
            const int t1 = min(t0 + 1, nit - 1);
            stage_tile<64, 8>(kg + (size_t)t0*64*DDE, DDE, &Lds[jp & 1][0][0][0], wave, lane);
            stage_tile<64, 8>(eg + t0*64, TT, &Lds[jp & 1][0][1][0], wave, lane);
            stage_tile<64, 8>(kg + (size_t)t1*64*DDE, DDE, &Lds[jp & 1][1][0][0], wave, lane);
            stage_tile<64, 8>(eg + t1*64, TT, &Lds[jp & 1][1][1][0], wave, lane);
        }
    }

    // merge partials across the ws-pair: ws=0 ships H-set, ws=1 ships L-set.
    float* S = (float*)&Lds[0][0][0][0];
    float* my = S + (size_t)(wave*64 + lane)*16;
    {
        const f32x4 (&os)[4] = wsid ? oL : oH;
        #pragma unroll
        for (int nt = 0; nt < 4; ++nt)
            #pragma unroll
            for (int r = 0; r < 4; ++r) my[nt*4 + r] = os[nt][r];
    }
    WAIT_LGKM0();
    wg_barrier();
    const float* peer = S + (size_t)((wave ^ 4)*64 + lane)*16;
    f32x4 (&ok)[4] = wsid ? oH : oL;
    #pragma unroll
    for (int nt = 0; nt < 4; ++nt)
        #pragma unroll
        for (int r = 0; r < 4; ++r) ok[nt][r] += peer[nt*4 + r];

    // store with fused combine: ws=0 -> qtL rows, ws=1 -> qtH rows
    const int qt = wsid ? qtH : qtL;
    #pragma unroll
    for (int nt = 0; nt < 4; ++nt)
        #pragma unroll
        for (int r = 0; r < 4; ++r) {
            const int row = qt*64 + wl*16 + quad*4 + r;
            const int col = h*HDD + nt*16 + l15;
            const size_t e = (size_t)(b*TT + row)*DDE + col;
            ysumb[e] = (bf16_t)((float)yarb[e] + ok[nt][r]);
        }
}

// ---------------------------------------------------------------------------
extern "C" void kernel_launch(void* const* d_in, const int* in_sizes, int n_in,
                              void* d_out, int out_size, void* d_ws, size_t ws_size,
                              hipStream_t stream)
{
    const float* x      = (const float*)d_in[0];
    const float* w_attn = (const float*)d_in[1];
    const float* b_attn = (const float*)d_in[2];
    const float* w_k2   = (const float*)d_in[3];
    const float* b_k2   = (const float*)d_in[4];
    const float* w_proj = (const float*)d_in[5];
    const float* b_proj = (const float*)d_in[6];

    const size_t NX  = (size_t)BB*TT*DDE;
    const size_t NWA = (size_t)2*DDE*DDE;
    const size_t NW  = (size_t)DDE*DDE;
    const size_t NQK = (size_t)BB*TT*2*DDE;

    bf16_t* xb   = (bf16_t*)d_ws;
    bf16_t* wab  = xb   + NX;
    bf16_t* wkb  = wab  + NWA;
    bf16_t* wpb  = wkb  + NW;
    bf16_t* qkb  = wpb  + NW;
    bf16_t* qab  = qkb  + NQK;
    bf16_t* kcs  = qab  + NX;
    bf16_t* vtg  = kcs  + NX;          // aliased by etg after attn_ar
    bf16_t* ysumb= vtg  + NX;
    bf16_t* yarb = (bf16_t*)((float*)(vtg + NX) + NX);
    bf16_t* etg  = vtg;

    const size_t NCVT = NX + NWA + NW + NW;
    cvt_all<<<NCVT / 1024, 256, 0, stream>>>(x, w_attn, w_k2, w_proj, xb);

    transpose_head<<<dim3(TT/64, NHH, BB), 256, 0, stream>>>(xb, vtg);

    const int M = BB * TT;
    gemm_qkk2<<<dim3(24, M/64), 256, 0, stream>>>(xb, wab, wkb, b_attn, b_k2,
                                                   qkb, qab, kcs);

    attn_ar_mfma<<<dim3(16, NHH, BB), 512, 0, stream>>>(qkb, vtg, yarb);
    build_etg<<<dim3(TT/64, NHH, BB), 256, 0, stream>>>(yarb, xb, etg);
    attn_ma_mfma<<<dim3(16, NHH, BB), 512, 0, stream>>>(qab, kcs, etg, yarb, ysumb);

    gemm_proj<<<dim3(DDE/64, M/64), 256, 0, stream>>>(ysumb, wpb, b_proj,
                                                      (float*)d_out, M, DDE, DDE, 2.f);
}